// Round 2
// baseline (1750.937 us; speedup 1.0000x reference)
//
#include <hip/hip_runtime.h>

typedef unsigned short ushort_t;

#define B_ 4
#define L_ 1024
#define C_ 768
#define N_ 16
#define DR_ 48
#define HW_ 32
#define M_ (B_*L_)   // 4096 rows

// Workspace budget: 59,252,992 B (~56.5 MiB). Layout (byte offsets):
//   0        IDX   (2*1024 int)
//   8192     FLAG  (int; 1 = inputs are bf16, 0 = fp32)
//   8448     XN    M*C   u16   (aliased later by HBUF)
//   6299904  U     2*M*C u16   (aliased later by DT)
//   18882816 Z     2*M*C u16   (aliased later by FUSED, M*2C u16)
//   31465728 UC    2*M*C u16
//   44048640 DBL   2*M*80 f32
//   46670080 Y     2*M*C u16

__device__ __forceinline__ float bf2f(ushort_t u) {
  union { unsigned int i; float f; } v; v.i = ((unsigned int)u) << 16; return v.f;
}
__device__ __forceinline__ ushort_t f2bf(float f) {
  union { float f; unsigned int i; } v; v.f = f;
  unsigned int x = v.i;
  return (ushort_t)((x + 0x7fffu + ((x >> 16) & 1u)) >> 16);
}
// dual-dtype input loads (flag chooses bf16 vs fp32 interpretation)
__device__ __forceinline__ float ldf(const void* p, size_t i, int bf) {
  return bf ? bf2f(((const ushort_t*)p)[i]) : ((const float*)p)[i];
}
__device__ __forceinline__ float4 ldf4(const void* p, size_t i, int bf) {
  if (bf) {
    ushort4 u = *reinterpret_cast<const ushort4*>((const ushort_t*)p + i);
    return make_float4(bf2f(u.x), bf2f(u.y), bf2f(u.z), bf2f(u.w));
  }
  return *reinterpret_cast<const float4*>((const float*)p + i);
}

// ------------------------------------------------- spiral idx + dtype detect
__global__ void setup_k(const void* x, int* idx_cw, int* idx_ccw, int* flag) {
  int t = threadIdx.x;
  if (t == 0) {
    int top = 0, bottom = HW_-1, left = 0, right = HW_-1, p = 0;
    while (top <= bottom && left <= right) {
      for (int j = left; j <= right; j++) idx_cw[p++] = top*HW_ + j;
      top++;
      for (int i = top; i <= bottom; i++) idx_cw[p++] = i*HW_ + right;
      right--;
      if (top <= bottom) { for (int j = right; j >= left; j--) idx_cw[p++] = bottom*HW_ + j; bottom--; }
      if (left <= right) { for (int i = bottom; i >= top; i--) idx_cw[p++] = i*HW_ + left; left++; }
    }
  } else if (t == 1) {
    int top = 0, bottom = HW_-1, left = 0, right = HW_-1, p = 0;
    while (top <= bottom && left <= right) {
      for (int j = right; j >= left; j--) idx_ccw[p++] = top*HW_ + j;
      top++;
      for (int i = top; i <= bottom; i++) idx_ccw[p++] = i*HW_ + left;
      left++;
      if (top <= bottom) { for (int j = left; j <= right; j++) idx_ccw[p++] = bottom*HW_ + j; bottom--; }
      if (left <= right) { for (int i = bottom; i >= top; i--) idx_ccw[p++] = i*HW_ + right; right--; }
    }
  } else if (t == 2) {
    // If x is really fp32 reinterpreted as u16, the low-half words have
    // uniform-random exponent fields; bf16 N(0,1) data stays in [90,141].
    const ushort_t* u = (const ushort_t*)x;
    int bf = 1;
    for (int i = 0; i < 256; i++) {
      int e = (u[i] >> 7) & 0xFF;
      if (e < 90 || e > 141) { bf = 0; break; }
    }
    *flag = bf;
  }
}

// ---------------------------------------------------------------- layernorm
__global__ __launch_bounds__(256) void layernorm_k(
    const void* __restrict__ x, const void* __restrict__ w,
    const void* __restrict__ bb, ushort_t* __restrict__ xn,
    const int* __restrict__ flagp)
{
  const int inbf = *flagp;
  int row = blockIdx.x;
  int tid = threadIdx.x;
  size_t o0 = (size_t)row * C_;
  float v0 = ldf(x, o0 + tid,       inbf);
  float v1 = ldf(x, o0 + tid + 256, inbf);
  float v2 = ldf(x, o0 + tid + 512, inbf);
  float s = v0 + v1 + v2, s2 = v0*v0 + v1*v1 + v2*v2;
  for (int o = 32; o > 0; o >>= 1) { s += __shfl_down(s, o); s2 += __shfl_down(s2, o); }
  __shared__ float ss[4], ss2[4];
  if ((tid & 63) == 0) { ss[tid >> 6] = s; ss2[tid >> 6] = s2; }
  __syncthreads();
  s  = ss[0] + ss[1] + ss[2] + ss[3];
  s2 = ss2[0] + ss2[1] + ss2[2] + ss2[3];
  float mean = s * (1.f / C_);
  float var  = s2 * (1.f / C_) - mean * mean;
  float inv  = rsqrtf(var + 1e-6f);
  xn[o0 + tid]       = f2bf((v0 - mean) * inv * ldf(w, tid,     inbf) + ldf(bb, tid,     inbf));
  xn[o0 + tid + 256] = f2bf((v1 - mean) * inv * ldf(w, tid+256, inbf) + ldf(bb, tid+256, inbf));
  xn[o0 + tid + 512] = f2bf((v2 - mean) * inv * ldf(w, tid+512, inbf) + ldf(bb, tid+512, inbf));
}

// ---------------------------------------------------------------- generic GEMM
// Out[M,N] = act(A[M,K] @ W[K, wofs:wofs+N] + bias) (+resid); optional A-row
// gather and out-row scatter (per-batch spiral maps).
// a_bf: A dtype (1=bf16 ws, 0=fp32 ws). W/bias/resid dtype follows *flagp.
// out_mode: 0 = bf16 store, 1 = fp32 store, 2 = follow flag (d_out).
__global__ __launch_bounds__(256) void sgemm_k(
    const void* __restrict__ A, int lda, int a_bf, const int* __restrict__ a_map,
    const void* __restrict__ W, int ldw, int wofs,
    const void* __restrict__ bias,
    const void* __restrict__ resid, int ldr,
    void* __restrict__ OutP, int ldo, const int* __restrict__ o_map, int out_mode,
    int M, int N, int K, int act, const int* __restrict__ flagp)
{
  const int inbf = *flagp;
  __shared__ float As[16][68];   // As[k][m]
  __shared__ float Bs[16][68];   // Bs[k][n]
  const int tid  = threadIdx.x;
  const int row0 = blockIdx.y * 64;
  const int col0 = blockIdx.x * 64;

  const int ar = tid >> 2;
  const int ak = (tid & 3) << 2;
  int arow = row0 + ar;
  int asrc = arow;
  if (a_map) { int b = arow / L_, l = arow - b * L_; asrc = b * L_ + a_map[l]; }
  const size_t abase = (size_t)asrc * lda + ak;

  const int wk = tid >> 4;
  const int wc = (tid & 15) << 2;
  const int wcol = col0 + wc;
  const bool wvalid = (wcol < N);
  const size_t wbase = (size_t)wk * ldw + wcol + wofs;

  const int ty = tid >> 4;
  const int tx = tid & 15;

  float acc[4][4];
  #pragma unroll
  for (int i = 0; i < 4; i++)
    #pragma unroll
    for (int j = 0; j < 4; j++) acc[i][j] = 0.f;

  for (int k0 = 0; k0 < K; k0 += 16) {
    float4 av = ldf4(A, abase + k0, a_bf);
    float4 wv = make_float4(0.f, 0.f, 0.f, 0.f);
    if (wvalid) wv = ldf4(W, wbase + (size_t)k0 * ldw, inbf);
    __syncthreads();
    As[ak + 0][ar] = av.x;
    As[ak + 1][ar] = av.y;
    As[ak + 2][ar] = av.z;
    As[ak + 3][ar] = av.w;
    *reinterpret_cast<float4*>(&Bs[wk][wc]) = wv;
    __syncthreads();
    #pragma unroll
    for (int kk = 0; kk < 16; ++kk) {
      float4 a4 = *reinterpret_cast<const float4*>(&As[kk][ty << 2]);
      float4 b4 = *reinterpret_cast<const float4*>(&Bs[kk][tx << 2]);
      float aa[4] = {a4.x, a4.y, a4.z, a4.w};
      float bb[4] = {b4.x, b4.y, b4.z, b4.w};
      #pragma unroll
      for (int i = 0; i < 4; i++)
        #pragma unroll
        for (int j = 0; j < 4; j++)
          acc[i][j] = fmaf(aa[i], bb[j], acc[i][j]);
    }
  }

  const int obf = (out_mode == 2) ? inbf : (out_mode == 0);
  #pragma unroll
  for (int i = 0; i < 4; i++) {
    int r = row0 + (ty << 2) + i;
    int orow = r;
    if (o_map) { int b = r / L_, l = r - b * L_; orow = b * L_ + o_map[l]; }
    #pragma unroll
    for (int j = 0; j < 4; j++) {
      int c = col0 + (tx << 2) + j;
      if (c >= N) continue;
      float v = acc[i][j];
      if (bias) v += ldf(bias, c, inbf);
      if (act == 1) v = (v > 20.f) ? v : log1pf(__expf(v));                       // softplus
      else if (act == 2) v = 0.5f * v * (1.f + erff(v * 0.70710678118654752f));   // exact gelu
      if (resid) v += ldf(resid, (size_t)orow * ldr + c, inbf);
      size_t oi = (size_t)orow * ldo + c;
      if (obf) ((ushort_t*)OutP)[oi] = f2bf(v);
      else     ((float*)OutP)[oi]    = v;
    }
  }
}

// ---------------------------------------------------------------- conv(K=4)+silu
// per-direction launch; u/uc are M x C (stride C_)
__global__ __launch_bounds__(256) void conv_silu_k(
    const ushort_t* __restrict__ u, const void* __restrict__ cw,
    const void* __restrict__ cb, ushort_t* __restrict__ uc,
    const int* __restrict__ flagp)
{
  const int inbf = *flagp;
  int g = blockIdx.x * 256 + threadIdx.x;   // (b,l,c), c fastest
  int c = g % C_;
  int row = g / C_;
  int l = row % L_;
  float w0 = ldf(cw, c*4+0, inbf), w1 = ldf(cw, c*4+1, inbf);
  float w2 = ldf(cw, c*4+2, inbf), w3 = ldf(cw, c*4+3, inbf);
  const ushort_t* up = u + (size_t)(row - l) * C_ + c;   // start of this batch row
  float s = ldf(cb, c, inbf);
  if (l >= 3) s += w0 * bf2f(up[(size_t)(l-3) * C_]);
  if (l >= 2) s += w1 * bf2f(up[(size_t)(l-2) * C_]);
  if (l >= 1) s += w2 * bf2f(up[(size_t)(l-1) * C_]);
  s += w3 * bf2f(up[(size_t)l * C_]);
  s = s / (1.f + __expf(-s));   // silu
  uc[g] = f2bf(s);
}

// ---------------------------------------------------------------- selective scan
// thread = (dir, b, c, n); h recurrence in regs; reduce over n (16 lanes) via shfl
__global__ __launch_bounds__(256) void scan_k(
    const ushort_t* __restrict__ dt, const ushort_t* __restrict__ uc,
    const float* __restrict__ dbl, const ushort_t* __restrict__ z,
    const void* __restrict__ Alog_cw, const void* __restrict__ Alog_ccw,
    const void* __restrict__ D_cw, const void* __restrict__ D_ccw,
    ushort_t* __restrict__ y, const int* __restrict__ flagp)
{
  const int inbf = *flagp;
  const int d = blockIdx.z;
  const int b = blockIdx.y;
  const int tid = threadIdx.x;
  const int n = tid & 15;
  const int c = blockIdx.x * 16 + (tid >> 4);

  const size_t rbase = (size_t)d * M_ * C_ + (size_t)b * L_ * C_ + c;
  const ushort_t* dtp = dt + rbase;
  const ushort_t* ucp = uc + rbase;
  const ushort_t* zp  = z  + rbase;
  ushort_t* yp = y + rbase;
  const float* dblp = dbl + (size_t)d * M_ * 80 + (size_t)b * L_ * 80;

  const void* Alog = d ? Alog_ccw : Alog_cw;
  const void* Dp   = d ? D_ccw   : D_cw;
  const float a   = -__expf(ldf(Alog, c * N_ + n, inbf));
  const float dvc = ldf(Dp, c, inbf);

  float h = 0.f;
  for (int l = 0; l < L_; ++l) {
    float dtv = bf2f(dtp[(size_t)l * C_]);
    float ucv = bf2f(ucp[(size_t)l * C_]);
    float bv  = dblp[(size_t)l * 80 + DR_ + n];
    float cv  = dblp[(size_t)l * 80 + DR_ + N_ + n];
    h = h * __expf(dtv * a) + dtv * bv * ucv;
    float p = h * cv;
    p += __shfl_xor(p, 1);
    p += __shfl_xor(p, 2);
    p += __shfl_xor(p, 4);
    p += __shfl_xor(p, 8);
    if (n == 0) {
      float zv = bf2f(zp[(size_t)l * C_]);
      float yv = p + dvc * ucv;
      yv *= zv / (1.f + __expf(-zv));    // * silu(z)
      yp[(size_t)l * C_] = f2bf(yv);
    }
  }
}

// ---------------------------------------------------------------- launch
extern "C" void kernel_launch(void* const* d_in, const int* in_sizes, int n_in,
                              void* d_out, int out_size, void* d_ws, size_t ws_size,
                              hipStream_t stream)
{
  const void* x      = d_in[0];
  const void* norm_w = d_in[1];
  const void* norm_b = d_in[2];
  const void* in_w[2]    = { d_in[3],  d_in[12] };
  const void* conv_w[2]  = { d_in[4],  d_in[13] };
  const void* conv_b[2]  = { d_in[5],  d_in[14] };
  const void* xproj_w[2] = { d_in[6],  d_in[15] };
  const void* dtp_w[2]   = { d_in[7],  d_in[16] };
  const void* dtp_b[2]   = { d_in[8],  d_in[17] };
  const void* A_log[2]   = { d_in[9],  d_in[18] };
  const void* Dvec[2]    = { d_in[10], d_in[19] };
  const void* out_w[2]   = { d_in[11], d_in[20] };
  const void* fus_w1 = d_in[21];
  const void* fus_b1 = d_in[22];
  const void* fus_w2 = d_in[23];
  const void* fus_b2 = d_in[24];

  char* base = (char*)d_ws;
  int*      IDX  = (int*)base;
  int*      FLAG = (int*)(base + 8192);
  ushort_t* XN   = (ushort_t*)(base + 8448);
  ushort_t* U    = (ushort_t*)(base + 6299904);
  ushort_t* Z    = (ushort_t*)(base + 18882816);
  ushort_t* UC   = (ushort_t*)(base + 31465728);
  float*    DBL  = (float*)(base + 44048640);
  ushort_t* Y    = (ushort_t*)(base + 46670080);
  // aliases (non-overlapping lifetimes, stage-ordered launches below)
  ushort_t* DT    = U;    // dt written after conv consumed U
  ushort_t* FUSED = Z;    // fused written after scan consumed Z
  ushort_t* HBUF  = XN;   // hidden written after in_proj consumed XN

  const size_t SD = (size_t)M_ * C_;   // per-dir activation elems

  hipLaunchKernelGGL(setup_k, dim3(1), dim3(64), 0, stream, x, IDX, IDX + L_, FLAG);
  hipLaunchKernelGGL(layernorm_k, dim3(M_), dim3(256), 0, stream, x, norm_w, norm_b, XN, FLAG);

  // stage 2: in_proj (u half and z half), both dirs   (4x GEMM 4096x768x768)
  for (int d = 0; d < 2; ++d) {
    const int* idx = IDX + d * L_;
    hipLaunchKernelGGL(sgemm_k, dim3(12, 64), dim3(256), 0, stream,
        XN, C_, 1, idx, in_w[d], 2*C_, 0, (const void*)nullptr, (const void*)nullptr, 0,
        (void*)(U + d*SD), C_, (const int*)nullptr, 0, M_, C_, C_, 0, FLAG);
    hipLaunchKernelGGL(sgemm_k, dim3(12, 64), dim3(256), 0, stream,
        XN, C_, 1, idx, in_w[d], 2*C_, C_, (const void*)nullptr, (const void*)nullptr, 0,
        (void*)(Z + d*SD), C_, (const int*)nullptr, 0, M_, C_, C_, 0, FLAG);
  }
  // stage 3: conv + silu
  for (int d = 0; d < 2; ++d)
    hipLaunchKernelGGL(conv_silu_k, dim3(M_*C_/256), dim3(256), 0, stream,
        U + d*SD, conv_w[d], conv_b[d], UC + d*SD, FLAG);
  // stage 4: xproj   (4096x80x768, fp32 out)
  for (int d = 0; d < 2; ++d)
    hipLaunchKernelGGL(sgemm_k, dim3(2, 64), dim3(256), 0, stream,
        UC + d*SD, C_, 1, (const int*)nullptr, xproj_w[d], 80, 0,
        (const void*)nullptr, (const void*)nullptr, 0,
        (void*)(DBL + (size_t)d*M_*80), 80, (const int*)nullptr, 1, M_, 80, C_, 0, FLAG);
  // stage 5: dt = softplus(dtc @ dtp_w + dtp_b)   (4096x768x48) -> DT (=U region)
  for (int d = 0; d < 2; ++d)
    hipLaunchKernelGGL(sgemm_k, dim3(12, 64), dim3(256), 0, stream,
        DBL + (size_t)d*M_*80, 80, 0, (const int*)nullptr, dtp_w[d], C_, 0,
        dtp_b[d], (const void*)nullptr, 0,
        (void*)(DT + d*SD), C_, (const int*)nullptr, 0, M_, C_, DR_, 1, FLAG);
  // stage 6: selective scan (both dirs), z-gated
  hipLaunchKernelGGL(scan_k, dim3(C_/16, B_, 2), dim3(256), 0, stream,
      DT, UC, DBL, Z, A_log[0], A_log[1], Dvec[0], Dvec[1], Y, FLAG);
  // stage 7: out_proj with spiral-inverse scatter -> FUSED (=Z region)
  for (int d = 0; d < 2; ++d)
    hipLaunchKernelGGL(sgemm_k, dim3(12, 64), dim3(256), 0, stream,
        Y + d*SD, C_, 1, (const int*)nullptr, out_w[d], C_, 0,
        (const void*)nullptr, (const void*)nullptr, 0,
        (void*)(FUSED + d*C_), 2*C_, IDX + d*L_, 0, M_, C_, C_, 0, FLAG);
  // stage 8: h = gelu(fused @ fus_w1 + fus_b1)   (4096x768x1536) -> HBUF (=XN region)
  hipLaunchKernelGGL(sgemm_k, dim3(12, 64), dim3(256), 0, stream,
      FUSED, 2*C_, 1, (const int*)nullptr, fus_w1, C_, 0, fus_b1,
      (const void*)nullptr, 0,
      (void*)HBUF, C_, (const int*)nullptr, 0, M_, C_, 2*C_, 2, FLAG);
  // stage 9: out = h @ fus_w2 + fus_b2 + x       (4096x768x768), dtype per flag
  hipLaunchKernelGGL(sgemm_k, dim3(12, 64), dim3(256), 0, stream,
      HBUF, C_, 1, (const int*)nullptr, fus_w2, C_, 0, fus_b2,
      x, C_,
      d_out, C_, (const int*)nullptr, 2, M_, C_, C_, 0, FLAG);
}

// Round 3
// 1257.732 us; speedup vs baseline: 1.3921x; 1.3921x over previous
//
#include <hip/hip_runtime.h>

typedef unsigned short ushort_t;

#define B_ 4
#define L_ 1024
#define C_ 768
#define N_ 16
#define DR_ 48
#define HW_ 32
#define M_ (B_*L_)   // 4096 rows
#define SEG_ 128     // scan segment length
#define NSEG_ 8      // L_/SEG_

// Workspace budget: 59,252,992 B (~56.5 MiB). Layout (byte offsets):
//   0        IDX   (2*1024 int)
//   8192     FLAG  (int; 1 = inputs are bf16, 0 = fp32)
//   8448     XN    M*C u16 (aliased by scan P/Q during scan, by HBUF at stage 8)
//   6299904  U     2*M*C u16   (aliased later by DT)
//   18882816 Z     2*M*C u16   (aliased later by FUSED, M*2C u16)
//   31465728 UC    2*M*C u16
//   44048640 DBL   2*M*80 f32
//   46670080 Y     2*M*C u16

__device__ __forceinline__ float bf2f(ushort_t u) {
  union { unsigned int i; float f; } v; v.i = ((unsigned int)u) << 16; return v.f;
}
__device__ __forceinline__ ushort_t f2bf(float f) {
  union { float f; unsigned int i; } v; v.f = f;
  unsigned int x = v.i;
  return (ushort_t)((x + 0x7fffu + ((x >> 16) & 1u)) >> 16);
}
__device__ __forceinline__ float ldf(const void* p, size_t i, int bf) {
  return bf ? bf2f(((const ushort_t*)p)[i]) : ((const float*)p)[i];
}
__device__ __forceinline__ float4 ldf4(const void* p, size_t i, int bf) {
  if (bf) {
    ushort4 u = *reinterpret_cast<const ushort4*>((const ushort_t*)p + i);
    return make_float4(bf2f(u.x), bf2f(u.y), bf2f(u.z), bf2f(u.w));
  }
  return *reinterpret_cast<const float4*>((const float*)p + i);
}

// ------------------------------------------------- spiral idx + dtype detect
__global__ void setup_k(const void* x, int* idx_cw, int* idx_ccw, int* flag) {
  int t = threadIdx.x;
  if (t == 0) {
    int top = 0, bottom = HW_-1, left = 0, right = HW_-1, p = 0;
    while (top <= bottom && left <= right) {
      for (int j = left; j <= right; j++) idx_cw[p++] = top*HW_ + j;
      top++;
      for (int i = top; i <= bottom; i++) idx_cw[p++] = i*HW_ + right;
      right--;
      if (top <= bottom) { for (int j = right; j >= left; j--) idx_cw[p++] = bottom*HW_ + j; bottom--; }
      if (left <= right) { for (int i = bottom; i >= top; i--) idx_cw[p++] = i*HW_ + left; left++; }
    }
  } else if (t == 1) {
    int top = 0, bottom = HW_-1, left = 0, right = HW_-1, p = 0;
    while (top <= bottom && left <= right) {
      for (int j = right; j >= left; j--) idx_ccw[p++] = top*HW_ + j;
      top++;
      for (int i = top; i <= bottom; i++) idx_ccw[p++] = i*HW_ + left;
      left++;
      if (top <= bottom) { for (int j = left; j <= right; j++) idx_ccw[p++] = bottom*HW_ + j; bottom--; }
      if (left <= right) { for (int i = bottom; i >= top; i--) idx_ccw[p++] = i*HW_ + right; right--; }
    }
  } else if (t == 2) {
    const ushort_t* u = (const ushort_t*)x;
    int bf = 1;
    for (int i = 0; i < 256; i++) {
      int e = (u[i] >> 7) & 0xFF;
      if (e < 90 || e > 141) { bf = 0; break; }
    }
    *flag = bf;
  }
}

// ---------------------------------------------------------------- layernorm
__global__ __launch_bounds__(256) void layernorm_k(
    const void* __restrict__ x, const void* __restrict__ w,
    const void* __restrict__ bb, ushort_t* __restrict__ xn,
    const int* __restrict__ flagp)
{
  const int inbf = *flagp;
  int row = blockIdx.x;
  int tid = threadIdx.x;
  size_t o0 = (size_t)row * C_;
  float v0 = ldf(x, o0 + tid,       inbf);
  float v1 = ldf(x, o0 + tid + 256, inbf);
  float v2 = ldf(x, o0 + tid + 512, inbf);
  float s = v0 + v1 + v2, s2 = v0*v0 + v1*v1 + v2*v2;
  for (int o = 32; o > 0; o >>= 1) { s += __shfl_down(s, o); s2 += __shfl_down(s2, o); }
  __shared__ float ss[4], ss2[4];
  if ((tid & 63) == 0) { ss[tid >> 6] = s; ss2[tid >> 6] = s2; }
  __syncthreads();
  s  = ss[0] + ss[1] + ss[2] + ss[3];
  s2 = ss2[0] + ss2[1] + ss2[2] + ss2[3];
  float mean = s * (1.f / C_);
  float var  = s2 * (1.f / C_) - mean * mean;
  float inv  = rsqrtf(var + 1e-6f);
  xn[o0 + tid]       = f2bf((v0 - mean) * inv * ldf(w, tid,     inbf) + ldf(bb, tid,     inbf));
  xn[o0 + tid + 256] = f2bf((v1 - mean) * inv * ldf(w, tid+256, inbf) + ldf(bb, tid+256, inbf));
  xn[o0 + tid + 512] = f2bf((v2 - mean) * inv * ldf(w, tid+512, inbf) + ldf(bb, tid+512, inbf));
}

// ---------------------------------------------------------------- generic GEMM
__global__ __launch_bounds__(256) void sgemm_k(
    const void* __restrict__ A, int lda, int a_bf, const int* __restrict__ a_map,
    const void* __restrict__ W, int ldw, int wofs,
    const void* __restrict__ bias,
    const void* __restrict__ resid, int ldr,
    void* __restrict__ OutP, int ldo, const int* __restrict__ o_map, int out_mode,
    int M, int N, int K, int act, const int* __restrict__ flagp)
{
  const int inbf = *flagp;
  __shared__ float As[16][68];
  __shared__ float Bs[16][68];
  const int tid  = threadIdx.x;
  const int row0 = blockIdx.y * 64;
  const int col0 = blockIdx.x * 64;

  const int ar = tid >> 2;
  const int ak = (tid & 3) << 2;
  int arow = row0 + ar;
  int asrc = arow;
  if (a_map) { int b = arow / L_, l = arow - b * L_; asrc = b * L_ + a_map[l]; }
  const size_t abase = (size_t)asrc * lda + ak;

  const int wk = tid >> 4;
  const int wc = (tid & 15) << 2;
  const int wcol = col0 + wc;
  const bool wvalid = (wcol < N);
  const size_t wbase = (size_t)wk * ldw + wcol + wofs;

  const int ty = tid >> 4;
  const int tx = tid & 15;

  float acc[4][4];
  #pragma unroll
  for (int i = 0; i < 4; i++)
    #pragma unroll
    for (int j = 0; j < 4; j++) acc[i][j] = 0.f;

  for (int k0 = 0; k0 < K; k0 += 16) {
    float4 av = ldf4(A, abase + k0, a_bf);
    float4 wv = make_float4(0.f, 0.f, 0.f, 0.f);
    if (wvalid) wv = ldf4(W, wbase + (size_t)k0 * ldw, inbf);
    __syncthreads();
    As[ak + 0][ar] = av.x;
    As[ak + 1][ar] = av.y;
    As[ak + 2][ar] = av.z;
    As[ak + 3][ar] = av.w;
    *reinterpret_cast<float4*>(&Bs[wk][wc]) = wv;
    __syncthreads();
    #pragma unroll
    for (int kk = 0; kk < 16; ++kk) {
      float4 a4 = *reinterpret_cast<const float4*>(&As[kk][ty << 2]);
      float4 b4 = *reinterpret_cast<const float4*>(&Bs[kk][tx << 2]);
      float aa[4] = {a4.x, a4.y, a4.z, a4.w};
      float bb[4] = {b4.x, b4.y, b4.z, b4.w};
      #pragma unroll
      for (int i = 0; i < 4; i++)
        #pragma unroll
        for (int j = 0; j < 4; j++)
          acc[i][j] = fmaf(aa[i], bb[j], acc[i][j]);
    }
  }

  const int obf = (out_mode == 2) ? inbf : (out_mode == 0);
  #pragma unroll
  for (int i = 0; i < 4; i++) {
    int r = row0 + (ty << 2) + i;
    int orow = r;
    if (o_map) { int b = r / L_, l = r - b * L_; orow = b * L_ + o_map[l]; }
    #pragma unroll
    for (int j = 0; j < 4; j++) {
      int c = col0 + (tx << 2) + j;
      if (c >= N) continue;
      float v = acc[i][j];
      if (bias) v += ldf(bias, c, inbf);
      if (act == 1) v = (v > 20.f) ? v : log1pf(__expf(v));
      else if (act == 2) v = 0.5f * v * (1.f + erff(v * 0.70710678118654752f));
      if (resid) v += ldf(resid, (size_t)orow * ldr + c, inbf);
      size_t oi = (size_t)orow * ldo + c;
      if (obf) ((ushort_t*)OutP)[oi] = f2bf(v);
      else     ((float*)OutP)[oi]    = v;
    }
  }
}

// ---------------------------------------------------------------- conv(K=4)+silu
__global__ __launch_bounds__(256) void conv_silu_k(
    const ushort_t* __restrict__ u, const void* __restrict__ cw,
    const void* __restrict__ cb, ushort_t* __restrict__ uc,
    const int* __restrict__ flagp)
{
  const int inbf = *flagp;
  int g = blockIdx.x * 256 + threadIdx.x;
  int c = g % C_;
  int row = g / C_;
  int l = row % L_;
  float w0 = ldf(cw, c*4+0, inbf), w1 = ldf(cw, c*4+1, inbf);
  float w2 = ldf(cw, c*4+2, inbf), w3 = ldf(cw, c*4+3, inbf);
  const ushort_t* up = u + (size_t)(row - l) * C_ + c;
  float s = ldf(cb, c, inbf);
  if (l >= 3) s += w0 * bf2f(up[(size_t)(l-3) * C_]);
  if (l >= 2) s += w1 * bf2f(up[(size_t)(l-2) * C_]);
  if (l >= 1) s += w2 * bf2f(up[(size_t)(l-1) * C_]);
  s += w3 * bf2f(up[(size_t)l * C_]);
  s = s / (1.f + __expf(-s));
  uc[g] = f2bf(s);
}

// ---------------------------------------------------------------- segmented scan
// Pass 1: per (d,b,c,n,seg) compute P = prod(dA), Q = local h-scan end (h0=0).
// thread: n = tid&15, c = blockIdx.x*16 + tid>>4 ; seg = blockIdx.y ; db = blockIdx.z
__global__ __launch_bounds__(256) void scan_pass1(
    const ushort_t* __restrict__ dt, const ushort_t* __restrict__ uc,
    const float* __restrict__ dbl,
    const void* __restrict__ Alog_cw, const void* __restrict__ Alog_ccw,
    float* __restrict__ P, float* __restrict__ Q, const int* __restrict__ flagp)
{
  const int inbf = *flagp;
  const int db = blockIdx.z, d = db >> 2, b = db & 3;
  const int s = blockIdx.y;
  const int tid = threadIdx.x;
  const int n = tid & 15;
  const int c = blockIdx.x * 16 + (tid >> 4);
  const int l0 = s * SEG_;

  const size_t rbase = (size_t)d*M_*C_ + (size_t)b*L_*C_ + (size_t)l0*C_ + c;
  const ushort_t* dtp = dt + rbase;
  const ushort_t* ucp = uc + rbase;
  const float* dblp = dbl + ((size_t)d*M_ + (size_t)b*L_ + l0) * 80 + DR_ + n;

  const void* Alog = d ? Alog_ccw : Alog_cw;
  const float a = -__expf(ldf(Alog, c * N_ + n, inbf));

  float h = 0.f, Pa = 1.f;
  #pragma unroll 4
  for (int l = 0; l < SEG_; ++l) {
    float dtv = bf2f(dtp[0]);
    float ucv = bf2f(ucp[0]);
    float bv  = dblp[0];
    float dA  = __expf(dtv * a);
    h  = h * dA + dtv * bv * ucv;
    Pa = Pa * dA;
    dtp += C_; ucp += C_; dblp += 80;
  }
  size_t idx = (((size_t)db * NSEG_ + s) * C_ + c) * N_ + n;
  P[idx] = Pa; Q[idx] = h;
}

// Pass 2: per (d,b,c,n) combine segments sequentially; Q[s] becomes the
// segment-START state H_s (read P/Q before overwrite; same thread owns slots).
__global__ __launch_bounds__(256) void scan_pass2(
    float* __restrict__ P, float* __restrict__ Q)
{
  size_t g = (size_t)blockIdx.x * 256 + threadIdx.x;   // 98304 = 8*12288
  size_t db = g / (C_ * N_);
  size_t cn = g % (C_ * N_);
  float h = 0.f;
  #pragma unroll
  for (int s = 0; s < NSEG_; ++s) {
    size_t off = (db * NSEG_ + s) * (C_ * N_) + cn;
    float p = P[off], q = Q[off];
    Q[off] = h;          // H_s (state entering segment s)
    h = h * p + q;
  }
}

// Pass 3: recompute local scan seeded with H_s; emit z-gated y.
__global__ __launch_bounds__(256) void scan_pass3(
    const ushort_t* __restrict__ dt, const ushort_t* __restrict__ uc,
    const float* __restrict__ dbl, const ushort_t* __restrict__ z,
    const void* __restrict__ Alog_cw, const void* __restrict__ Alog_ccw,
    const void* __restrict__ D_cw, const void* __restrict__ D_ccw,
    const float* __restrict__ Q, ushort_t* __restrict__ y,
    const int* __restrict__ flagp)
{
  const int inbf = *flagp;
  const int db = blockIdx.z, d = db >> 2, b = db & 3;
  const int s = blockIdx.y;
  const int tid = threadIdx.x;
  const int n = tid & 15;
  const int c = blockIdx.x * 16 + (tid >> 4);
  const int l0 = s * SEG_;

  const size_t rbase = (size_t)d*M_*C_ + (size_t)b*L_*C_ + (size_t)l0*C_ + c;
  const ushort_t* dtp = dt + rbase;
  const ushort_t* ucp = uc + rbase;
  const ushort_t* zp  = z  + rbase;
  ushort_t* yp = y + rbase;
  const float* dblp = dbl + ((size_t)d*M_ + (size_t)b*L_ + l0) * 80 + DR_ + n;

  const void* Alog = d ? Alog_ccw : Alog_cw;
  const void* Dp   = d ? D_ccw   : D_cw;
  const float a   = -__expf(ldf(Alog, c * N_ + n, inbf));
  const float dvc = ldf(Dp, c, inbf);

  size_t idx = (((size_t)db * NSEG_ + s) * C_ + c) * N_ + n;
  float h = Q[idx];

  #pragma unroll 2
  for (int l = 0; l < SEG_; ++l) {
    float dtv = bf2f(dtp[0]);
    float ucv = bf2f(ucp[0]);
    float bv  = dblp[0];
    float cv  = dblp[N_];
    float dA  = __expf(dtv * a);
    h = h * dA + dtv * bv * ucv;
    float p = h * cv;
    p += __shfl_xor(p, 1);
    p += __shfl_xor(p, 2);
    p += __shfl_xor(p, 4);
    p += __shfl_xor(p, 8);
    if (n == 0) {
      float zv = bf2f(zp[0]);
      float yv = p + dvc * ucv;
      yv *= zv / (1.f + __expf(-zv));
      yp[0] = f2bf(yv);
    }
    dtp += C_; ucp += C_; zp += C_; yp += C_; dblp += 80;
  }
}

// ---------------------------------------------------------------- launch
extern "C" void kernel_launch(void* const* d_in, const int* in_sizes, int n_in,
                              void* d_out, int out_size, void* d_ws, size_t ws_size,
                              hipStream_t stream)
{
  const void* x      = d_in[0];
  const void* norm_w = d_in[1];
  const void* norm_b = d_in[2];
  const void* in_w[2]    = { d_in[3],  d_in[12] };
  const void* conv_w[2]  = { d_in[4],  d_in[13] };
  const void* conv_b[2]  = { d_in[5],  d_in[14] };
  const void* xproj_w[2] = { d_in[6],  d_in[15] };
  const void* dtp_w[2]   = { d_in[7],  d_in[16] };
  const void* dtp_b[2]   = { d_in[8],  d_in[17] };
  const void* A_log[2]   = { d_in[9],  d_in[18] };
  const void* Dvec[2]    = { d_in[10], d_in[19] };
  const void* out_w[2]   = { d_in[11], d_in[20] };
  const void* fus_w1 = d_in[21];
  const void* fus_b1 = d_in[22];
  const void* fus_w2 = d_in[23];
  const void* fus_b2 = d_in[24];

  char* base = (char*)d_ws;
  int*      IDX  = (int*)base;
  int*      FLAG = (int*)(base + 8192);
  ushort_t* XN   = (ushort_t*)(base + 8448);
  ushort_t* U    = (ushort_t*)(base + 6299904);
  ushort_t* Z    = (ushort_t*)(base + 18882816);
  ushort_t* UC   = (ushort_t*)(base + 31465728);
  float*    DBL  = (float*)(base + 44048640);
  ushort_t* Y    = (ushort_t*)(base + 46670080);
  // aliases (non-overlapping lifetimes, stage-ordered launches below)
  ushort_t* DT    = U;    // dt written after conv consumed U
  ushort_t* FUSED = Z;    // fused written after scan consumed Z
  ushort_t* HBUF  = XN;   // hidden written after in_proj consumed XN
  // scan P/Q alias the XN region (dead between stage 2 and stage 8):
  // 786432 floats each; P+Q = 6291456 B = exactly XN's extent.
  float* SP = (float*)(base + 8448);
  float* SQ = SP + (size_t)2 * 4 * NSEG_ * C_ * N_;   // +786432 floats

  const size_t SD = (size_t)M_ * C_;

  hipLaunchKernelGGL(setup_k, dim3(1), dim3(64), 0, stream, x, IDX, IDX + L_, FLAG);
  hipLaunchKernelGGL(layernorm_k, dim3(M_), dim3(256), 0, stream, x, norm_w, norm_b, XN, FLAG);

  // stage 2: in_proj (u half and z half), both dirs
  for (int d = 0; d < 2; ++d) {
    const int* idx = IDX + d * L_;
    hipLaunchKernelGGL(sgemm_k, dim3(12, 64), dim3(256), 0, stream,
        XN, C_, 1, idx, in_w[d], 2*C_, 0, (const void*)nullptr, (const void*)nullptr, 0,
        (void*)(U + d*SD), C_, (const int*)nullptr, 0, M_, C_, C_, 0, FLAG);
    hipLaunchKernelGGL(sgemm_k, dim3(12, 64), dim3(256), 0, stream,
        XN, C_, 1, idx, in_w[d], 2*C_, C_, (const void*)nullptr, (const void*)nullptr, 0,
        (void*)(Z + d*SD), C_, (const int*)nullptr, 0, M_, C_, C_, 0, FLAG);
  }
  // stage 3: conv + silu
  for (int d = 0; d < 2; ++d)
    hipLaunchKernelGGL(conv_silu_k, dim3(M_*C_/256), dim3(256), 0, stream,
        U + d*SD, conv_w[d], conv_b[d], UC + d*SD, FLAG);
  // stage 4: xproj (fp32 out)
  for (int d = 0; d < 2; ++d)
    hipLaunchKernelGGL(sgemm_k, dim3(2, 64), dim3(256), 0, stream,
        UC + d*SD, C_, 1, (const int*)nullptr, xproj_w[d], 80, 0,
        (const void*)nullptr, (const void*)nullptr, 0,
        (void*)(DBL + (size_t)d*M_*80), 80, (const int*)nullptr, 1, M_, 80, C_, 0, FLAG);
  // stage 5: dt = softplus(dtc @ dtp_w + dtp_b) -> DT (=U region)
  for (int d = 0; d < 2; ++d)
    hipLaunchKernelGGL(sgemm_k, dim3(12, 64), dim3(256), 0, stream,
        DBL + (size_t)d*M_*80, 80, 0, (const int*)nullptr, dtp_w[d], C_, 0,
        dtp_b[d], (const void*)nullptr, 0,
        (void*)(DT + d*SD), C_, (const int*)nullptr, 0, M_, C_, DR_, 1, FLAG);
  // stage 6: segmented selective scan (both dirs), z-gated
  hipLaunchKernelGGL(scan_pass1, dim3(C_/16, NSEG_, 8), dim3(256), 0, stream,
      DT, UC, DBL, A_log[0], A_log[1], SP, SQ, FLAG);
  hipLaunchKernelGGL(scan_pass2, dim3(8 * C_ * N_ / 256), dim3(256), 0, stream, SP, SQ);
  hipLaunchKernelGGL(scan_pass3, dim3(C_/16, NSEG_, 8), dim3(256), 0, stream,
      DT, UC, DBL, Z, A_log[0], A_log[1], Dvec[0], Dvec[1], SQ, Y, FLAG);
  // stage 7: out_proj with spiral-inverse scatter -> FUSED (=Z region)
  for (int d = 0; d < 2; ++d)
    hipLaunchKernelGGL(sgemm_k, dim3(12, 64), dim3(256), 0, stream,
        Y + d*SD, C_, 1, (const int*)nullptr, out_w[d], C_, 0,
        (const void*)nullptr, (const void*)nullptr, 0,
        (void*)(FUSED + d*C_), 2*C_, IDX + d*L_, 0, M_, C_, C_, 0, FLAG);
  // stage 8: h = gelu(fused @ fus_w1 + fus_b1) -> HBUF (=XN region)
  hipLaunchKernelGGL(sgemm_k, dim3(12, 64), dim3(256), 0, stream,
      FUSED, 2*C_, 1, (const int*)nullptr, fus_w1, C_, 0, fus_b1,
      (const void*)nullptr, 0,
      (void*)HBUF, C_, (const int*)nullptr, 0, M_, C_, 2*C_, 2, FLAG);
  // stage 9: out = h @ fus_w2 + fus_b2 + x
  hipLaunchKernelGGL(sgemm_k, dim3(12, 64), dim3(256), 0, stream,
      HBUF, C_, 1, (const int*)nullptr, fus_w2, C_, 0, fus_b2,
      x, C_,
      d_out, C_, (const int*)nullptr, 2, M_, C_, C_, 0, FLAG);
}

// Round 4
// 1199.825 us; speedup vs baseline: 1.4593x; 1.0483x over previous
//
#include <hip/hip_runtime.h>

typedef unsigned short ushort_t;
typedef __attribute__((ext_vector_type(8))) short short8;
typedef __attribute__((ext_vector_type(4))) float f32x4;

#define B_ 4
#define L_ 1024
#define C_ 768
#define N_ 16
#define DR_ 48
#define HW_ 32
#define M_ (B_*L_)   // 4096 rows
#define SEG_ 128     // scan segment length
#define NSEG_ 8      // L_/SEG_

// Workspace budget: 59,252,992 B (~56.5 MiB). Layout (byte offsets):
//   0        IDX   (2*1024 int)
//   8192     FLAG  (int; 1 = inputs are bf16, 0 = fp32)
//   8448     XN    M*C u16 (aliased by scan P/Q during scan, by HBUF at stage 8)
//   6299904  U     2*M*C u16   (aliased later by DT)
//   18882816 Z     2*M*C u16   (aliased later by FUSED, M*2C u16)
//   31465728 UC    2*M*C u16
//   44048640 DBL   2*M*80 f32
//   46670080 Y     2*M*C u16

__device__ __forceinline__ float bf2f(ushort_t u) {
  union { unsigned int i; float f; } v; v.i = ((unsigned int)u) << 16; return v.f;
}
__device__ __forceinline__ ushort_t f2bf(float f) {
  union { float f; unsigned int i; } v; v.f = f;
  unsigned int x = v.i;
  return (ushort_t)((x + 0x7fffu + ((x >> 16) & 1u)) >> 16);
}
__device__ __forceinline__ float ldf(const void* p, size_t i, int bf) {
  return bf ? bf2f(((const ushort_t*)p)[i]) : ((const float*)p)[i];
}

// ------------------------------------------------- spiral idx + dtype detect
__global__ void setup_k(const void* x, int* idx_cw, int* idx_ccw, int* flag) {
  int t = threadIdx.x;
  if (t == 0) {
    int top = 0, bottom = HW_-1, left = 0, right = HW_-1, p = 0;
    while (top <= bottom && left <= right) {
      for (int j = left; j <= right; j++) idx_cw[p++] = top*HW_ + j;
      top++;
      for (int i = top; i <= bottom; i++) idx_cw[p++] = i*HW_ + right;
      right--;
      if (top <= bottom) { for (int j = right; j >= left; j--) idx_cw[p++] = bottom*HW_ + j; bottom--; }
      if (left <= right) { for (int i = bottom; i >= top; i--) idx_cw[p++] = i*HW_ + left; left++; }
    }
  } else if (t == 1) {
    int top = 0, bottom = HW_-1, left = 0, right = HW_-1, p = 0;
    while (top <= bottom && left <= right) {
      for (int j = right; j >= left; j--) idx_ccw[p++] = top*HW_ + j;
      top++;
      for (int i = top; i <= bottom; i++) idx_ccw[p++] = i*HW_ + left;
      left++;
      if (top <= bottom) { for (int j = left; j <= right; j++) idx_ccw[p++] = bottom*HW_ + j; bottom--; }
      if (left <= right) { for (int i = bottom; i >= top; i--) idx_ccw[p++] = i*HW_ + right; right--; }
    }
  } else if (t == 2) {
    const ushort_t* u = (const ushort_t*)x;
    int bf = 1;
    for (int i = 0; i < 256; i++) {
      int e = (u[i] >> 7) & 0xFF;
      if (e < 90 || e > 141) { bf = 0; break; }
    }
    *flag = bf;
  }
}

// ---------------------------------------------------------------- layernorm
__global__ __launch_bounds__(256) void layernorm_k(
    const void* __restrict__ x, const void* __restrict__ w,
    const void* __restrict__ bb, ushort_t* __restrict__ xn,
    const int* __restrict__ flagp)
{
  const int inbf = *flagp;
  int row = blockIdx.x;
  int tid = threadIdx.x;
  size_t o0 = (size_t)row * C_;
  float v0 = ldf(x, o0 + tid,       inbf);
  float v1 = ldf(x, o0 + tid + 256, inbf);
  float v2 = ldf(x, o0 + tid + 512, inbf);
  float s = v0 + v1 + v2, s2 = v0*v0 + v1*v1 + v2*v2;
  for (int o = 32; o > 0; o >>= 1) { s += __shfl_down(s, o); s2 += __shfl_down(s2, o); }
  __shared__ float ss[4], ss2[4];
  if ((tid & 63) == 0) { ss[tid >> 6] = s; ss2[tid >> 6] = s2; }
  __syncthreads();
  s  = ss[0] + ss[1] + ss[2] + ss[3];
  s2 = ss2[0] + ss2[1] + ss2[2] + ss2[3];
  float mean = s * (1.f / C_);
  float var  = s2 * (1.f / C_) - mean * mean;
  float inv  = rsqrtf(var + 1e-6f);
  xn[o0 + tid]       = f2bf((v0 - mean) * inv * ldf(w, tid,     inbf) + ldf(bb, tid,     inbf));
  xn[o0 + tid + 256] = f2bf((v1 - mean) * inv * ldf(w, tid+256, inbf) + ldf(bb, tid+256, inbf));
  xn[o0 + tid + 512] = f2bf((v2 - mean) * inv * ldf(w, tid+512, inbf) + ldf(bb, tid+512, inbf));
}

// ---------------------------------------------------------------- MFMA GEMM
// Out[M, Nn] = act(A[M,K] @ W[K, wofs+0..Nn] + bias) (+resid)
// Batched over blockIdx.z (per-z pointers in GB). A is bf16 ws (or fp32 when
// a_f32). W/bias/resid follow *flagp dtype. Tile: 128(M) x 64(N) x 32(K),
// 2 waves, each wave 64x64 via 4x4 mfma_f32_16x16x32_bf16 fragments.
// Lane maps (verified per guide): A-frag A[m=lane&15][k=quad*8+j];
// B-frag B[k=quad*8+j][n=lane&15]; D col=lane&15, row=quad*4+reg.
struct GB {
  const void* A[4]; const int* amap[4];
  const void* W[4]; int wofs[4];
  const void* bias[4];
  void* out[4]; const int* omap[4];
};

__global__ __launch_bounds__(128) void mgemm_k(
    GB gb, int lda, int a_f32, int ldw, int Nn, int K, int ldo,
    int act, int out_mode, const void* resid, int ldr, const int* __restrict__ flagp)
{
  const int inbf = *flagp;
  const int z = blockIdx.z;
  const void* A    = gb.A[z];
  const int* amap  = gb.amap[z];
  const void* W    = gb.W[z];
  const int  wofs  = gb.wofs[z];
  const void* bias = gb.bias[z];
  void* Out        = gb.out[z];
  const int* omap  = gb.omap[z];

  __shared__ __align__(16) ushort_t As[128 * 40];   // [m][k], stride 40
  __shared__ __align__(16) ushort_t Bs[64 * 40];    // [n][k], stride 40

  const int tid  = threadIdx.x;
  const int wm   = tid >> 6;       // wave id -> m offset 0/64
  const int lane = tid & 63;
  const int quad = lane >> 4;
  const int l15  = lane & 15;
  const int row0 = blockIdx.y * 128;
  const int col0 = blockIdx.x * 64;

  // A staging addresses (4 iters of 8 bf16): idx = tid + i*128
  size_t abase[4];
  #pragma unroll
  for (int i = 0; i < 4; ++i) {
    int idx = tid + i * 128;
    int r = idx >> 2;
    int arow = row0 + r;
    int asrc = arow;
    if (amap) { int b = arow >> 10, l = arow & 1023; asrc = (b << 10) + amap[l]; }
    abase[i] = (size_t)asrc * lda + ((idx & 3) << 3);
  }
  // B staging: thread covers n-pair (bn, bn+1) x 8 k's
  const int bn   = (tid & 31) * 2;
  const int bkb  = (tid >> 5) * 8;
  const int wcol = col0 + bn;
  const bool bvalid = (wcol + 1) < Nn;   // Nn is even

  f32x4 acc[4][4];
  #pragma unroll
  for (int mi = 0; mi < 4; ++mi)
    #pragma unroll
    for (int ni = 0; ni < 4; ++ni)
      acc[mi][ni] = (f32x4){0.f, 0.f, 0.f, 0.f};

  for (int k0 = 0; k0 < K; k0 += 32) {
    __syncthreads();   // previous iteration's frag reads done before overwrite
    // ---- stage A tile 128x32 -> LDS [m][k]
    #pragma unroll
    for (int i = 0; i < 4; ++i) {
      int idx = tid + i * 128;
      int r  = idx >> 2;
      int kq = (idx & 3) << 3;
      short8 av;
      if (a_f32) {
        const float* ap = (const float*)A + abase[i] + k0;
        f32x4 f0 = *(const f32x4*)(ap);
        f32x4 f1 = *(const f32x4*)(ap + 4);
        #pragma unroll
        for (int j = 0; j < 4; ++j) av[j]   = (short)f2bf(f0[j]);
        #pragma unroll
        for (int j = 0; j < 4; ++j) av[4+j] = (short)f2bf(f1[j]);
      } else {
        av = *(const short8*)((const ushort_t*)A + abase[i] + k0);
      }
      *(short8*)&As[r * 40 + kq] = av;
    }
    // ---- stage B tile 32x64 -> LDS [n][k] (transposed)
    {
      short8 lov, hiv;
      #pragma unroll
      for (int j = 0; j < 8; ++j) {
        int kk = k0 + bkb + j;
        unsigned int w32 = 0;
        if (bvalid && kk < K) {
          if (inbf) {
            w32 = *(const unsigned int*)((const ushort_t*)W + (size_t)kk * ldw + wofs + wcol);
          } else {
            const float* wp = (const float*)W + (size_t)kk * ldw + wofs + wcol;
            w32 = (unsigned int)f2bf(wp[0]) | ((unsigned int)f2bf(wp[1]) << 16);
          }
        }
        lov[j] = (short)(w32 & 0xffffu);
        hiv[j] = (short)(w32 >> 16);
      }
      *(short8*)&Bs[bn * 40 + bkb]       = lov;
      *(short8*)&Bs[(bn + 1) * 40 + bkb] = hiv;
    }
    __syncthreads();
    // ---- fragments + MFMA
    short8 aF[4], bF[4];
    #pragma unroll
    for (int mi = 0; mi < 4; ++mi)
      aF[mi] = *(const short8*)&As[(wm * 64 + mi * 16 + l15) * 40 + quad * 8];
    #pragma unroll
    for (int ni = 0; ni < 4; ++ni)
      bF[ni] = *(const short8*)&Bs[(ni * 16 + l15) * 40 + quad * 8];
    #pragma unroll
    for (int mi = 0; mi < 4; ++mi)
      #pragma unroll
      for (int ni = 0; ni < 4; ++ni)
        acc[mi][ni] = __builtin_amdgcn_mfma_f32_16x16x32_bf16(aF[mi], bF[ni], acc[mi][ni], 0, 0, 0);
  }

  // ---- epilogue
  const int obf = (out_mode == 2) ? inbf : (out_mode == 0);
  #pragma unroll
  for (int ni = 0; ni < 4; ++ni) {
    int colg = col0 + ni * 16 + l15;
    if (colg >= Nn) continue;
    float bv = bias ? ldf(bias, colg, inbf) : 0.f;
    #pragma unroll
    for (int mi = 0; mi < 4; ++mi) {
      #pragma unroll
      for (int r = 0; r < 4; ++r) {
        int rowg = row0 + wm * 64 + mi * 16 + quad * 4 + r;
        int orow = rowg;
        if (omap) { int b = rowg >> 10, l = rowg & 1023; orow = (b << 10) + omap[l]; }
        float v = acc[mi][ni][r] + bv;
        if (act == 1)      v = (v > 20.f) ? v : log1pf(__expf(v));                       // softplus
        else if (act == 2) v = 0.5f * v * (1.f + erff(v * 0.70710678118654752f));        // gelu
        if (resid) v += ldf(resid, (size_t)orow * ldr + colg, inbf);
        size_t oi = (size_t)orow * ldo + colg;
        if (obf) ((ushort_t*)Out)[oi] = f2bf(v);
        else     ((float*)Out)[oi]    = v;
      }
    }
  }
}

// ---------------------------------------------------------------- conv(K=4)+silu
__global__ __launch_bounds__(256) void conv_silu_k(
    const ushort_t* __restrict__ u, const void* __restrict__ cw,
    const void* __restrict__ cb, ushort_t* __restrict__ uc,
    const int* __restrict__ flagp)
{
  const int inbf = *flagp;
  int g = blockIdx.x * 256 + threadIdx.x;
  int c = g % C_;
  int row = g / C_;
  int l = row % L_;
  float w0 = ldf(cw, c*4+0, inbf), w1 = ldf(cw, c*4+1, inbf);
  float w2 = ldf(cw, c*4+2, inbf), w3 = ldf(cw, c*4+3, inbf);
  const ushort_t* up = u + (size_t)(row - l) * C_ + c;
  float s = ldf(cb, c, inbf);
  if (l >= 3) s += w0 * bf2f(up[(size_t)(l-3) * C_]);
  if (l >= 2) s += w1 * bf2f(up[(size_t)(l-2) * C_]);
  if (l >= 1) s += w2 * bf2f(up[(size_t)(l-1) * C_]);
  s += w3 * bf2f(up[(size_t)l * C_]);
  s = s / (1.f + __expf(-s));
  uc[g] = f2bf(s);
}

// ---------------------------------------------------------------- segmented scan
__global__ __launch_bounds__(256) void scan_pass1(
    const ushort_t* __restrict__ dt, const ushort_t* __restrict__ uc,
    const float* __restrict__ dbl,
    const void* __restrict__ Alog_cw, const void* __restrict__ Alog_ccw,
    float* __restrict__ P, float* __restrict__ Q, const int* __restrict__ flagp)
{
  const int inbf = *flagp;
  const int db = blockIdx.z, d = db >> 2, b = db & 3;
  const int s = blockIdx.y;
  const int tid = threadIdx.x;
  const int n = tid & 15;
  const int c = blockIdx.x * 16 + (tid >> 4);
  const int l0 = s * SEG_;

  const size_t rbase = (size_t)d*M_*C_ + (size_t)b*L_*C_ + (size_t)l0*C_ + c;
  const ushort_t* dtp = dt + rbase;
  const ushort_t* ucp = uc + rbase;
  const float* dblp = dbl + ((size_t)d*M_ + (size_t)b*L_ + l0) * 80 + DR_ + n;

  const void* Alog = d ? Alog_ccw : Alog_cw;
  const float a = -__expf(ldf(Alog, c * N_ + n, inbf));

  float h = 0.f, Pa = 1.f;
  #pragma unroll 4
  for (int l = 0; l < SEG_; ++l) {
    float dtv = bf2f(dtp[0]);
    float ucv = bf2f(ucp[0]);
    float bv  = dblp[0];
    float dA  = __expf(dtv * a);
    h  = h * dA + dtv * bv * ucv;
    Pa = Pa * dA;
    dtp += C_; ucp += C_; dblp += 80;
  }
  size_t idx = (((size_t)db * NSEG_ + s) * C_ + c) * N_ + n;
  P[idx] = Pa; Q[idx] = h;
}

__global__ __launch_bounds__(256) void scan_pass2(
    float* __restrict__ P, float* __restrict__ Q)
{
  size_t g = (size_t)blockIdx.x * 256 + threadIdx.x;
  size_t db = g / (C_ * N_);
  size_t cn = g % (C_ * N_);
  float h = 0.f;
  #pragma unroll
  for (int s = 0; s < NSEG_; ++s) {
    size_t off = (db * NSEG_ + s) * (C_ * N_) + cn;
    float p = P[off], q = Q[off];
    Q[off] = h;
    h = h * p + q;
  }
}

__global__ __launch_bounds__(256) void scan_pass3(
    const ushort_t* __restrict__ dt, const ushort_t* __restrict__ uc,
    const float* __restrict__ dbl, const ushort_t* __restrict__ z,
    const void* __restrict__ Alog_cw, const void* __restrict__ Alog_ccw,
    const void* __restrict__ D_cw, const void* __restrict__ D_ccw,
    const float* __restrict__ Q, ushort_t* __restrict__ y,
    const int* __restrict__ flagp)
{
  const int inbf = *flagp;
  const int db = blockIdx.z, d = db >> 2, b = db & 3;
  const int s = blockIdx.y;
  const int tid = threadIdx.x;
  const int n = tid & 15;
  const int c = blockIdx.x * 16 + (tid >> 4);
  const int l0 = s * SEG_;

  const size_t rbase = (size_t)d*M_*C_ + (size_t)b*L_*C_ + (size_t)l0*C_ + c;
  const ushort_t* dtp = dt + rbase;
  const ushort_t* ucp = uc + rbase;
  const ushort_t* zp  = z  + rbase;
  ushort_t* yp = y + rbase;
  const float* dblp = dbl + ((size_t)d*M_ + (size_t)b*L_ + l0) * 80 + DR_ + n;

  const void* Alog = d ? Alog_ccw : Alog_cw;
  const void* Dp   = d ? D_ccw   : D_cw;
  const float a   = -__expf(ldf(Alog, c * N_ + n, inbf));
  const float dvc = ldf(Dp, c, inbf);

  size_t idx = (((size_t)db * NSEG_ + s) * C_ + c) * N_ + n;
  float h = Q[idx];

  #pragma unroll 2
  for (int l = 0; l < SEG_; ++l) {
    float dtv = bf2f(dtp[0]);
    float ucv = bf2f(ucp[0]);
    float bv  = dblp[0];
    float cv  = dblp[N_];
    float dA  = __expf(dtv * a);
    h = h * dA + dtv * bv * ucv;
    float p = h * cv;
    p += __shfl_xor(p, 1);
    p += __shfl_xor(p, 2);
    p += __shfl_xor(p, 4);
    p += __shfl_xor(p, 8);
    if (n == 0) {
      float zv = bf2f(zp[0]);
      float yv = p + dvc * ucv;
      yv *= zv / (1.f + __expf(-zv));
      yp[0] = f2bf(yv);
    }
    dtp += C_; ucp += C_; zp += C_; yp += C_; dblp += 80;
  }
}

// ---------------------------------------------------------------- launch
extern "C" void kernel_launch(void* const* d_in, const int* in_sizes, int n_in,
                              void* d_out, int out_size, void* d_ws, size_t ws_size,
                              hipStream_t stream)
{
  const void* x      = d_in[0];
  const void* norm_w = d_in[1];
  const void* norm_b = d_in[2];
  const void* in_w[2]    = { d_in[3],  d_in[12] };
  const void* conv_w[2]  = { d_in[4],  d_in[13] };
  const void* conv_b[2]  = { d_in[5],  d_in[14] };
  const void* xproj_w[2] = { d_in[6],  d_in[15] };
  const void* dtp_w[2]   = { d_in[7],  d_in[16] };
  const void* dtp_b[2]   = { d_in[8],  d_in[17] };
  const void* A_log[2]   = { d_in[9],  d_in[18] };
  const void* Dvec[2]    = { d_in[10], d_in[19] };
  const void* out_w[2]   = { d_in[11], d_in[20] };
  const void* fus_w1 = d_in[21];
  const void* fus_b1 = d_in[22];
  const void* fus_w2 = d_in[23];
  const void* fus_b2 = d_in[24];

  char* base = (char*)d_ws;
  int*      IDX  = (int*)base;
  int*      FLAG = (int*)(base + 8192);
  ushort_t* XN   = (ushort_t*)(base + 8448);
  ushort_t* U    = (ushort_t*)(base + 6299904);
  ushort_t* Z    = (ushort_t*)(base + 18882816);
  ushort_t* UC   = (ushort_t*)(base + 31465728);
  float*    DBL  = (float*)(base + 44048640);
  ushort_t* Y    = (ushort_t*)(base + 46670080);
  ushort_t* DT    = U;    // dt written after conv consumed U
  ushort_t* FUSED = Z;    // fused written after scan consumed Z
  ushort_t* HBUF  = XN;   // hidden written after in_proj consumed XN
  float* SP = (float*)(base + 8448);
  float* SQ = SP + (size_t)2 * 4 * NSEG_ * C_ * N_;

  const size_t SD = (size_t)M_ * C_;

  hipLaunchKernelGGL(setup_k, dim3(1), dim3(64), 0, stream, x, IDX, IDX + L_, FLAG);
  hipLaunchKernelGGL(layernorm_k, dim3(M_), dim3(256), 0, stream, x, norm_w, norm_b, XN, FLAG);

  GB gb;
  // ---- stage 2: in_proj, batched (d, u/z half): 4 GEMMs 4096x768x768
  for (int zz = 0; zz < 4; ++zz) {
    int d = zz >> 1, half = zz & 1;
    gb.A[zz] = XN; gb.amap[zz] = IDX + d * L_;
    gb.W[zz] = in_w[d]; gb.wofs[zz] = half * C_;
    gb.bias[zz] = nullptr;
    gb.out[zz] = (void*)((half ? Z : U) + d * SD); gb.omap[zz] = nullptr;
  }
  hipLaunchKernelGGL(mgemm_k, dim3(12, 32, 4), dim3(128), 0, stream,
      gb, C_, 0, 2*C_, C_, C_, C_, 0, 0, (const void*)nullptr, 0, FLAG);

  // ---- stage 3: conv + silu
  for (int d = 0; d < 2; ++d)
    hipLaunchKernelGGL(conv_silu_k, dim3(M_*C_/256), dim3(256), 0, stream,
        U + d*SD, conv_w[d], conv_b[d], UC + d*SD, FLAG);

  // ---- stage 4: xproj 4096x80x768 (fp32 out), batched over d
  for (int zz = 0; zz < 2; ++zz) {
    gb.A[zz] = UC + zz * SD; gb.amap[zz] = nullptr;
    gb.W[zz] = xproj_w[zz]; gb.wofs[zz] = 0;
    gb.bias[zz] = nullptr;
    gb.out[zz] = (void*)(DBL + (size_t)zz * M_ * 80); gb.omap[zz] = nullptr;
  }
  hipLaunchKernelGGL(mgemm_k, dim3(2, 32, 2), dim3(128), 0, stream,
      gb, C_, 0, 80, 80, C_, 80, 0, 1, (const void*)nullptr, 0, FLAG);

  // ---- stage 5: dt = softplus(dtc @ dtp_w + dtp_b), A = DBL fp32, K=48
  for (int zz = 0; zz < 2; ++zz) {
    gb.A[zz] = DBL + (size_t)zz * M_ * 80; gb.amap[zz] = nullptr;
    gb.W[zz] = dtp_w[zz]; gb.wofs[zz] = 0;
    gb.bias[zz] = dtp_b[zz];
    gb.out[zz] = (void*)(DT + zz * SD); gb.omap[zz] = nullptr;
  }
  hipLaunchKernelGGL(mgemm_k, dim3(12, 32, 2), dim3(128), 0, stream,
      gb, 80, 1, C_, C_, DR_, C_, 1, 0, (const void*)nullptr, 0, FLAG);

  // ---- stage 6: segmented selective scan
  hipLaunchKernelGGL(scan_pass1, dim3(C_/16, NSEG_, 8), dim3(256), 0, stream,
      DT, UC, DBL, A_log[0], A_log[1], SP, SQ, FLAG);
  hipLaunchKernelGGL(scan_pass2, dim3(8 * C_ * N_ / 256), dim3(256), 0, stream, SP, SQ);
  hipLaunchKernelGGL(scan_pass3, dim3(C_/16, NSEG_, 8), dim3(256), 0, stream,
      DT, UC, DBL, Z, A_log[0], A_log[1], Dvec[0], Dvec[1], SQ, Y, FLAG);

  // ---- stage 7: out_proj with spiral-inverse scatter, batched over d
  for (int zz = 0; zz < 2; ++zz) {
    gb.A[zz] = Y + zz * SD; gb.amap[zz] = nullptr;
    gb.W[zz] = out_w[zz]; gb.wofs[zz] = 0;
    gb.bias[zz] = nullptr;
    gb.out[zz] = (void*)(FUSED + zz * C_); gb.omap[zz] = IDX + zz * L_;
  }
  hipLaunchKernelGGL(mgemm_k, dim3(12, 32, 2), dim3(128), 0, stream,
      gb, C_, 0, C_, C_, C_, 2*C_, 0, 0, (const void*)nullptr, 0, FLAG);

  // ---- stage 8: h = gelu(fused @ fus_w1 + fus_b1), K=1536
  gb.A[0] = FUSED; gb.amap[0] = nullptr;
  gb.W[0] = fus_w1; gb.wofs[0] = 0;
  gb.bias[0] = fus_b1;
  gb.out[0] = (void*)HBUF; gb.omap[0] = nullptr;
  hipLaunchKernelGGL(mgemm_k, dim3(12, 32, 1), dim3(128), 0, stream,
      gb, 2*C_, 0, C_, C_, 2*C_, C_, 2, 0, (const void*)nullptr, 0, FLAG);

  // ---- stage 9: out = h @ fus_w2 + fus_b2 + x
  gb.A[0] = HBUF; gb.amap[0] = nullptr;
  gb.W[0] = fus_w2; gb.wofs[0] = 0;
  gb.bias[0] = fus_b2;
  gb.out[0] = d_out; gb.omap[0] = nullptr;
  hipLaunchKernelGGL(mgemm_k, dim3(12, 32, 1), dim3(128), 0, stream,
      gb, C_, 0, C_, C_, C_, C_, 0, 2, x, C_, FLAG);
}

// Round 5
// 753.249 us; speedup vs baseline: 2.3245x; 1.5929x over previous
//
#include <hip/hip_runtime.h>

typedef unsigned short ushort_t;
typedef __attribute__((ext_vector_type(8))) short short8;
typedef __attribute__((ext_vector_type(4))) float f32x4;

#define B_ 4
#define L_ 1024
#define C_ 768
#define N_ 16
#define DR_ 48
#define HW_ 32
#define M_ (B_*L_)   // 4096 rows
#define SEG_ 128     // scan segment length
#define NSEG_ 8      // L_/SEG_

// Workspace layout (byte offsets), total 59,252,992 B — same as round 3/4:
//   0        IDX   (2*1024 int)
//   8192     FLAG
//   8448     XN region (6,291,456 B): XN -> {DTC, dtp^T} -> {SP,SQ} -> HBUF
//   6299904  U region (12,582,912 B): U -> xproj^T -> DT -> {fus_w1^T, fus_w2^T}
//   18882816 Z region: Z -> FUSED
//   31465728 UC region: in_w^T -> UC -> out_w^T
//   44048640 DBL 2*M*80 f32
//   46670080 Y 2*M*C u16

__device__ __forceinline__ float bf2f(ushort_t u) {
  union { unsigned int i; float f; } v; v.i = ((unsigned int)u) << 16; return v.f;
}
__device__ __forceinline__ ushort_t f2bf(float f) {
  union { float f; unsigned int i; } v; v.f = f;
  unsigned int x = v.i;
  return (ushort_t)((x + 0x7fffu + ((x >> 16) & 1u)) >> 16);
}
__device__ __forceinline__ float ldf(const void* p, size_t i, int bf) {
  return bf ? bf2f(((const ushort_t*)p)[i]) : ((const float*)p)[i];
}
// async global->LDS, 16 B per lane; lds dest = wave-uniform base + lane*16
__device__ __forceinline__ void gload_lds16(const void* g, void* lds) {
  __builtin_amdgcn_global_load_lds(
      (const __attribute__((address_space(1))) unsigned int*)g,
      (__attribute__((address_space(3))) unsigned int*)lds, 16, 0, 0);
}

// ------------------------------------------------- spiral idx + dtype detect
__global__ void setup_k(const void* x, int* idx_cw, int* idx_ccw, int* flag) {
  int t = threadIdx.x;
  if (t == 0) {
    int top = 0, bottom = HW_-1, left = 0, right = HW_-1, p = 0;
    while (top <= bottom && left <= right) {
      for (int j = left; j <= right; j++) idx_cw[p++] = top*HW_ + j;
      top++;
      for (int i = top; i <= bottom; i++) idx_cw[p++] = i*HW_ + right;
      right--;
      if (top <= bottom) { for (int j = right; j >= left; j--) idx_cw[p++] = bottom*HW_ + j; bottom--; }
      if (left <= right) { for (int i = bottom; i >= top; i--) idx_cw[p++] = i*HW_ + left; left++; }
    }
  } else if (t == 1) {
    int top = 0, bottom = HW_-1, left = 0, right = HW_-1, p = 0;
    while (top <= bottom && left <= right) {
      for (int j = right; j >= left; j--) idx_ccw[p++] = top*HW_ + j;
      top++;
      for (int i = top; i <= bottom; i++) idx_ccw[p++] = i*HW_ + left;
      left++;
      if (top <= bottom) { for (int j = left; j <= right; j++) idx_ccw[p++] = bottom*HW_ + j; bottom--; }
      if (left <= right) { for (int i = bottom; i >= top; i--) idx_ccw[p++] = i*HW_ + right; right--; }
    }
  } else if (t == 2) {
    const ushort_t* u = (const ushort_t*)x;
    int bf = 1;
    for (int i = 0; i < 256; i++) {
      int e = (u[i] >> 7) & 0xFF;
      if (e < 90 || e > 141) { bf = 0; break; }
    }
    *flag = bf;
  }
}

// ---------------------------------------------------------------- layernorm
__global__ __launch_bounds__(256) void layernorm_k(
    const void* __restrict__ x, const void* __restrict__ w,
    const void* __restrict__ bb, ushort_t* __restrict__ xn,
    const int* __restrict__ flagp)
{
  const int inbf = *flagp;
  int row = blockIdx.x;
  int tid = threadIdx.x;
  size_t o0 = (size_t)row * C_;
  float v0 = ldf(x, o0 + tid,       inbf);
  float v1 = ldf(x, o0 + tid + 256, inbf);
  float v2 = ldf(x, o0 + tid + 512, inbf);
  float s = v0 + v1 + v2, s2 = v0*v0 + v1*v1 + v2*v2;
  for (int o = 32; o > 0; o >>= 1) { s += __shfl_down(s, o); s2 += __shfl_down(s2, o); }
  __shared__ float ss[4], ss2[4];
  if ((tid & 63) == 0) { ss[tid >> 6] = s; ss2[tid >> 6] = s2; }
  __syncthreads();
  s  = ss[0] + ss[1] + ss[2] + ss[3];
  s2 = ss2[0] + ss2[1] + ss2[2] + ss2[3];
  float mean = s * (1.f / C_);
  float var  = s2 * (1.f / C_) - mean * mean;
  float inv  = rsqrtf(var + 1e-6f);
  xn[o0 + tid]       = f2bf((v0 - mean) * inv * ldf(w, tid,     inbf) + ldf(bb, tid,     inbf));
  xn[o0 + tid + 256] = f2bf((v1 - mean) * inv * ldf(w, tid+256, inbf) + ldf(bb, tid+256, inbf));
  xn[o0 + tid + 512] = f2bf((v2 - mean) * inv * ldf(w, tid+512, inbf) + ldf(bb, tid+512, inbf));
}

// ---------------------------------------------------------------- transpose
// dst[c][r] = src[r][c]; src [R][Cc] dtype per flag; dst bf16 [Cc][ldD].
// OOB tile entries written as 0 so k-padding (ldD > R) is zero-filled.
__global__ __launch_bounds__(256) void transpose_k(
    const void* __restrict__ src, int R, int Cc, int ldD,
    ushort_t* __restrict__ dst, const int* __restrict__ flagp)
{
  const int inbf = *flagp;
  __shared__ ushort_t tile[32][33];
  int bx = blockIdx.x * 32;  // c
  int by = blockIdx.y * 32;  // r
  int tx = threadIdx.x & 31, ty = threadIdx.x >> 5;
  #pragma unroll
  for (int i = 0; i < 4; ++i) {
    int r = by + ty + i*8, c = bx + tx;
    ushort_t v = 0;
    if (r < R && c < Cc) v = f2bf(ldf(src, (size_t)r * Cc + c, inbf));
    tile[ty + i*8][tx] = v;
  }
  __syncthreads();
  #pragma unroll
  for (int i = 0; i < 4; ++i) {
    int dr = bx + ty + i*8, dc = by + tx;
    if (dr < Cc && dc < ldD)
      dst[(size_t)dr * ldD + dc] = tile[tx][ty + i*8];
  }
}

// ---------------------------------------------------------------- dtc pack
// DBL [2*M][80] f32 -> DTC [2*M][64] bf16, cols 48..63 = 0
__global__ __launch_bounds__(256) void dtc_pack_k(
    const float* __restrict__ dbl, ushort_t* __restrict__ dtc)
{
  int g = blockIdx.x * 256 + threadIdx.x;
  int col = g & 63, row = g >> 6;
  float v = (col < DR_) ? dbl[(size_t)row * 80 + col] : 0.f;
  dtc[g] = f2bf(v);
}

// ---------------------------------------------------------------- MFMA GEMM
// Out[M, Nn] = act(A[M,K] @ WT[N,K]^T + bias) (+resid). A bf16 [M][lda],
// WT bf16 [N][ldb] (pre-transposed weights). Tile 128x128xBK64, 256 thr,
// 4 waves each computing a 64x64 quadrant. Staging via global_load_lds w=16
// into unpadded LDS [row][k] with XOR chunk swizzle c' = c ^ (row&7).
struct GB {
  const ushort_t* A[4]; const int* amap[4];
  const ushort_t* WT[4];
  const void* bias[4];
  void* out[4]; const int* omap[4];
};

__global__ __launch_bounds__(256) void mgemm_k(
    GB gb, int lda, int ldb, int Nn, int K, int ldo,
    int act, int out_mode, const void* resid, int ldr, const int* __restrict__ flagp)
{
  const int inbf = *flagp;
  const int z = blockIdx.z;
  const ushort_t* A  = gb.A[z];
  const int* amap    = gb.amap[z];
  const ushort_t* Bw = gb.WT[z];
  const void* bias   = gb.bias[z];
  void* Out          = gb.out[z];
  const int* omap    = gb.omap[z];

  __shared__ __align__(16) ushort_t As[128 * 64];  // [m][k], 16 KB
  __shared__ __align__(16) ushort_t Bs[128 * 64];  // [n][k], 16 KB

  const int tid  = threadIdx.x;
  const int w    = tid >> 6;
  const int lane = tid & 63;
  const int quad = lane >> 4;
  const int l15  = lane & 15;
  const int wm   = w >> 1, wn = w & 1;
  const int row0 = blockIdx.y * 128;
  const int col0 = blockIdx.x * 128;

  // staging descriptors: 4 A-chunks + 4 B-chunks per thread (16 B each)
  int agb[4], bgb[4], aldso[4], bldso[4];
  #pragma unroll
  for (int i = 0; i < 4; ++i) {
    int t  = i * 256 + w * 64 + lane;   // chunk id 0..1023
    int r  = t >> 3;
    int c  = (t & 7) ^ (r & 7);         // global k-chunk (swizzle involution)
    int grow = row0 + r;
    if (amap) { int b = grow >> 10, l = grow & 1023; grow = (b << 10) + amap[l]; }
    agb[i] = grow * lda + c * 8;        // element offset; +k0 later
    bgb[i] = (col0 + r) * ldb + c * 8;
    aldso[i] = (i * 256 + w * 64) * 16; // wave-uniform LDS byte base
    bldso[i] = aldso[i];
  }

  f32x4 acc[4][4];
  #pragma unroll
  for (int mi = 0; mi < 4; ++mi)
    #pragma unroll
    for (int ni = 0; ni < 4; ++ni)
      acc[mi][ni] = (f32x4){0.f, 0.f, 0.f, 0.f};

  const int sA = (l15 & 7);   // read-side swizzle key (row&7; mi*16 doesn't affect low3)

  for (int k0 = 0; k0 < K; k0 += 64) {
    #pragma unroll
    for (int i = 0; i < 4; ++i)
      gload_lds16(A + agb[i] + k0, (char*)As + aldso[i]);
    #pragma unroll
    for (int i = 0; i < 4; ++i)
      gload_lds16(Bw + bgb[i] + k0, (char*)Bs + bldso[i]);
    __syncthreads();   // drains vmcnt -> LDS visible

    #pragma unroll
    for (int ks = 0; ks < 2; ++ks) {
      short8 aF[4], bF[4];
      #pragma unroll
      for (int mi = 0; mi < 4; ++mi)
        aF[mi] = *(const short8*)&As[(wm*64 + mi*16 + l15) * 64 + (((quad + 4*ks) ^ sA) * 8)];
      #pragma unroll
      for (int ni = 0; ni < 4; ++ni)
        bF[ni] = *(const short8*)&Bs[(wn*64 + ni*16 + l15) * 64 + (((quad + 4*ks) ^ sA) * 8)];
      #pragma unroll
      for (int mi = 0; mi < 4; ++mi)
        #pragma unroll
        for (int ni = 0; ni < 4; ++ni)
          acc[mi][ni] = __builtin_amdgcn_mfma_f32_16x16x32_bf16(aF[mi], bF[ni], acc[mi][ni], 0, 0, 0);
    }
    __syncthreads();   // frag reads done before next overwrite
  }

  // ---- epilogue
  const int obf = (out_mode == 2) ? inbf : (out_mode == 0);
  #pragma unroll
  for (int ni = 0; ni < 4; ++ni) {
    int colg = col0 + wn*64 + ni*16 + l15;
    if (colg >= Nn) continue;
    float bv = bias ? ldf(bias, colg, inbf) : 0.f;
    #pragma unroll
    for (int mi = 0; mi < 4; ++mi) {
      #pragma unroll
      for (int r = 0; r < 4; ++r) {
        int rowg = row0 + wm*64 + mi*16 + quad*4 + r;
        int orow = rowg;
        if (omap) { int b = rowg >> 10, l = rowg & 1023; orow = (b << 10) + omap[l]; }
        float v = acc[mi][ni][r] + bv;
        if (act == 1)      v = (v > 20.f) ? v : log1pf(__expf(v));                  // softplus
        else if (act == 2) v = 0.5f * v * (1.f + erff(v * 0.70710678118654752f));   // gelu
        if (resid) v += ldf(resid, (size_t)orow * ldr + colg, inbf);
        size_t oi = (size_t)orow * ldo + colg;
        if (obf) ((ushort_t*)Out)[oi] = f2bf(v);
        else     ((float*)Out)[oi]    = v;
      }
    }
  }
}

// ---------------------------------------------------------------- conv(K=4)+silu
__global__ __launch_bounds__(256) void conv_silu_k(
    const ushort_t* __restrict__ u, const void* __restrict__ cw,
    const void* __restrict__ cb, ushort_t* __restrict__ uc,
    const int* __restrict__ flagp)
{
  const int inbf = *flagp;
  int g = blockIdx.x * 256 + threadIdx.x;
  int c = g % C_;
  int row = g / C_;
  int l = row % L_;
  float w0 = ldf(cw, c*4+0, inbf), w1 = ldf(cw, c*4+1, inbf);
  float w2 = ldf(cw, c*4+2, inbf), w3 = ldf(cw, c*4+3, inbf);
  const ushort_t* up = u + (size_t)(row - l) * C_ + c;
  float s = ldf(cb, c, inbf);
  if (l >= 3) s += w0 * bf2f(up[(size_t)(l-3) * C_]);
  if (l >= 2) s += w1 * bf2f(up[(size_t)(l-2) * C_]);
  if (l >= 1) s += w2 * bf2f(up[(size_t)(l-1) * C_]);
  s += w3 * bf2f(up[(size_t)l * C_]);
  s = s / (1.f + __expf(-s));
  uc[g] = f2bf(s);
}

// ---------------------------------------------------------------- segmented scan
__global__ __launch_bounds__(256) void scan_pass1(
    const ushort_t* __restrict__ dt, const ushort_t* __restrict__ uc,
    const float* __restrict__ dbl,
    const void* __restrict__ Alog_cw, const void* __restrict__ Alog_ccw,
    float* __restrict__ P, float* __restrict__ Q, const int* __restrict__ flagp)
{
  const int inbf = *flagp;
  const int db = blockIdx.z, d = db >> 2, b = db & 3;
  const int s = blockIdx.y;
  const int tid = threadIdx.x;
  const int n = tid & 15;
  const int c = blockIdx.x * 16 + (tid >> 4);
  const int l0 = s * SEG_;

  const size_t rbase = (size_t)d*M_*C_ + (size_t)b*L_*C_ + (size_t)l0*C_ + c;
  const ushort_t* dtp = dt + rbase;
  const ushort_t* ucp = uc + rbase;
  const float* dblp = dbl + ((size_t)d*M_ + (size_t)b*L_ + l0) * 80 + DR_ + n;

  const void* Alog = d ? Alog_ccw : Alog_cw;
  const float a = -__expf(ldf(Alog, c * N_ + n, inbf));

  float h = 0.f, Pa = 1.f;
  #pragma unroll 4
  for (int l = 0; l < SEG_; ++l) {
    float dtv = bf2f(dtp[0]);
    float ucv = bf2f(ucp[0]);
    float bv  = dblp[0];
    float dA  = __expf(dtv * a);
    h  = h * dA + dtv * bv * ucv;
    Pa = Pa * dA;
    dtp += C_; ucp += C_; dblp += 80;
  }
  size_t idx = (((size_t)db * NSEG_ + s) * C_ + c) * N_ + n;
  P[idx] = Pa; Q[idx] = h;
}

__global__ __launch_bounds__(256) void scan_pass2(
    float* __restrict__ P, float* __restrict__ Q)
{
  size_t g = (size_t)blockIdx.x * 256 + threadIdx.x;
  size_t db = g / (C_ * N_);
  size_t cn = g % (C_ * N_);
  float h = 0.f;
  #pragma unroll
  for (int s = 0; s < NSEG_; ++s) {
    size_t off = (db * NSEG_ + s) * (C_ * N_) + cn;
    float p = P[off], q = Q[off];
    Q[off] = h;
    h = h * p + q;
  }
}

__global__ __launch_bounds__(256) void scan_pass3(
    const ushort_t* __restrict__ dt, const ushort_t* __restrict__ uc,
    const float* __restrict__ dbl, const ushort_t* __restrict__ z,
    const void* __restrict__ Alog_cw, const void* __restrict__ Alog_ccw,
    const void* __restrict__ D_cw, const void* __restrict__ D_ccw,
    const float* __restrict__ Q, ushort_t* __restrict__ y,
    const int* __restrict__ flagp)
{
  const int inbf = *flagp;
  const int db = blockIdx.z, d = db >> 2, b = db & 3;
  const int s = blockIdx.y;
  const int tid = threadIdx.x;
  const int n = tid & 15;
  const int c = blockIdx.x * 16 + (tid >> 4);
  const int l0 = s * SEG_;

  const size_t rbase = (size_t)d*M_*C_ + (size_t)b*L_*C_ + (size_t)l0*C_ + c;
  const ushort_t* dtp = dt + rbase;
  const ushort_t* ucp = uc + rbase;
  const ushort_t* zp  = z  + rbase;
  ushort_t* yp = y + rbase;
  const float* dblp = dbl + ((size_t)d*M_ + (size_t)b*L_ + l0) * 80 + DR_ + n;

  const void* Alog = d ? Alog_ccw : Alog_cw;
  const void* Dp   = d ? D_ccw   : D_cw;
  const float a   = -__expf(ldf(Alog, c * N_ + n, inbf));
  const float dvc = ldf(Dp, c, inbf);

  size_t idx = (((size_t)db * NSEG_ + s) * C_ + c) * N_ + n;
  float h = Q[idx];

  #pragma unroll 2
  for (int l = 0; l < SEG_; ++l) {
    float dtv = bf2f(dtp[0]);
    float ucv = bf2f(ucp[0]);
    float bv  = dblp[0];
    float cv  = dblp[N_];
    float dA  = __expf(dtv * a);
    h = h * dA + dtv * bv * ucv;
    float p = h * cv;
    p += __shfl_xor(p, 1);
    p += __shfl_xor(p, 2);
    p += __shfl_xor(p, 4);
    p += __shfl_xor(p, 8);
    if (n == 0) {
      float zv = bf2f(zp[0]);
      float yv = p + dvc * ucv;
      yv *= zv / (1.f + __expf(-zv));
      yp[0] = f2bf(yv);
    }
    dtp += C_; ucp += C_; zp += C_; yp += C_; dblp += 80;
  }
}

// ---------------------------------------------------------------- launch
extern "C" void kernel_launch(void* const* d_in, const int* in_sizes, int n_in,
                              void* d_out, int out_size, void* d_ws, size_t ws_size,
                              hipStream_t stream)
{
  const void* x      = d_in[0];
  const void* norm_w = d_in[1];
  const void* norm_b = d_in[2];
  const void* in_w[2]    = { d_in[3],  d_in[12] };
  const void* conv_w[2]  = { d_in[4],  d_in[13] };
  const void* conv_b[2]  = { d_in[5],  d_in[14] };
  const void* xproj_w[2] = { d_in[6],  d_in[15] };
  const void* dtp_w[2]   = { d_in[7],  d_in[16] };
  const void* dtp_b[2]   = { d_in[8],  d_in[17] };
  const void* A_log[2]   = { d_in[9],  d_in[18] };
  const void* Dvec[2]    = { d_in[10], d_in[19] };
  const void* out_w[2]   = { d_in[11], d_in[20] };
  const void* fus_w1 = d_in[21];
  const void* fus_b1 = d_in[22];
  const void* fus_w2 = d_in[23];
  const void* fus_b2 = d_in[24];

  char* base = (char*)d_ws;
  int*      IDX  = (int*)base;
  int*      FLAG = (int*)(base + 8192);
  ushort_t* XN   = (ushort_t*)(base + 8448);
  ushort_t* U    = (ushort_t*)(base + 6299904);
  ushort_t* Z    = (ushort_t*)(base + 18882816);
  ushort_t* UC   = (ushort_t*)(base + 31465728);
  float*    DBL  = (float*)(base + 44048640);
  ushort_t* Y    = (ushort_t*)(base + 46670080);
  // lifetime aliases
  ushort_t* DT    = U;                                    // S5 out, S6 in
  ushort_t* FUSED = Z;                                    // S7 out, S8 in
  ushort_t* HBUF  = XN;                                   // S8 out, S9 in
  float* SP = (float*)(base + 8448);                      // S6 only
  float* SQ = SP + (size_t)2 * 4 * NSEG_ * C_ * N_;
  // JIT weight transposes (bf16), placed in regions dead at their use time:
  ushort_t* INWT = UC;                                    // [2][1536][768], used S2
  ushort_t* XPJT = U;                                     // [2][128pad][768], used S4
  ushort_t* DTC  = XN;                                    // [2*M][64], S4.5 -> S5
  ushort_t* DTPT = (ushort_t*)(base + 8448 + 1048576);    // [2][768][64], used S5
  ushort_t* OWT  = UC;                                    // [2][768][768], used S7
  ushort_t* FW1T = U;                                     // [768][1536], used S8
  ushort_t* FW2T = U + (size_t)768 * 1536;                // [768][768], used S9

  const size_t SD = (size_t)M_ * C_;

  hipLaunchKernelGGL(setup_k, dim3(1), dim3(64), 0, stream, x, IDX, IDX + L_, FLAG);
  hipLaunchKernelGGL(layernorm_k, dim3(M_), dim3(256), 0, stream, x, norm_w, norm_b, XN, FLAG);

  GB gb;
  // ---- T(in_w): [768][1536] -> [1536][768]
  for (int d = 0; d < 2; ++d)
    hipLaunchKernelGGL(transpose_k, dim3(48, 24), dim3(256), 0, stream,
        in_w[d], C_, 2*C_, C_, INWT + (size_t)d*1536*768, FLAG);
  // ---- S2: in_proj, z = (d, u/z half)
  for (int zz = 0; zz < 4; ++zz) {
    int d = zz >> 1, half = zz & 1;
    gb.A[zz] = XN; gb.amap[zz] = IDX + d * L_;
    gb.WT[zz] = INWT + (size_t)d*1536*768 + (size_t)half*768*768;
    gb.bias[zz] = nullptr;
    gb.out[zz] = (void*)((half ? Z : U) + d * SD); gb.omap[zz] = nullptr;
  }
  hipLaunchKernelGGL(mgemm_k, dim3(6, 32, 4), dim3(256), 0, stream,
      gb, C_, C_, C_, C_, C_, 0, 0, (const void*)nullptr, 0, FLAG);

  // ---- S3: conv + silu
  for (int d = 0; d < 2; ++d)
    hipLaunchKernelGGL(conv_silu_k, dim3(M_*C_/256), dim3(256), 0, stream,
        U + d*SD, conv_w[d], conv_b[d], UC + d*SD, FLAG);

  // ---- T(xproj): [768][80] -> [80][768] (alloc 128 rows; extra rows unused)
  for (int d = 0; d < 2; ++d)
    hipLaunchKernelGGL(transpose_k, dim3(3, 24), dim3(256), 0, stream,
        xproj_w[d], C_, 80, C_, XPJT + (size_t)d*128*768, FLAG);
  // ---- S4: xproj -> DBL fp32, Nn=80
  for (int zz = 0; zz < 2; ++zz) {
    gb.A[zz] = UC + zz * SD; gb.amap[zz] = nullptr;
    gb.WT[zz] = XPJT + (size_t)zz*128*768;
    gb.bias[zz] = nullptr;
    gb.out[zz] = (void*)(DBL + (size_t)zz * M_ * 80); gb.omap[zz] = nullptr;
  }
  hipLaunchKernelGGL(mgemm_k, dim3(1, 32, 2), dim3(256), 0, stream,
      gb, C_, C_, 80, C_, 80, 0, 1, (const void*)nullptr, 0, FLAG);

  // ---- pack dtc (zero-padded K=64) + T(dtp): [48][768] -> [768][64]
  hipLaunchKernelGGL(dtc_pack_k, dim3(2*M_*64/256), dim3(256), 0, stream, DBL, DTC);
  for (int d = 0; d < 2; ++d)
    hipLaunchKernelGGL(transpose_k, dim3(24, 2), dim3(256), 0, stream,
        dtp_w[d], DR_, C_, 64, DTPT + (size_t)d*768*64, FLAG);
  // ---- S5: dt = softplus(dtc @ dtp_w + dtp_b), K=64
  for (int zz = 0; zz < 2; ++zz) {
    gb.A[zz] = DTC + (size_t)zz * M_ * 64; gb.amap[zz] = nullptr;
    gb.WT[zz] = DTPT + (size_t)zz*768*64;
    gb.bias[zz] = dtp_b[zz];
    gb.out[zz] = (void*)(DT + zz * SD); gb.omap[zz] = nullptr;
  }
  hipLaunchKernelGGL(mgemm_k, dim3(6, 32, 2), dim3(256), 0, stream,
      gb, 64, 64, C_, 64, C_, 1, 0, (const void*)nullptr, 0, FLAG);

  // ---- S6: segmented selective scan
  hipLaunchKernelGGL(scan_pass1, dim3(C_/16, NSEG_, 8), dim3(256), 0, stream,
      DT, UC, DBL, A_log[0], A_log[1], SP, SQ, FLAG);
  hipLaunchKernelGGL(scan_pass2, dim3(8 * C_ * N_ / 256), dim3(256), 0, stream, SP, SQ);
  hipLaunchKernelGGL(scan_pass3, dim3(C_/16, NSEG_, 8), dim3(256), 0, stream,
      DT, UC, DBL, Z, A_log[0], A_log[1], Dvec[0], Dvec[1], SQ, Y, FLAG);

  // ---- T(out_w) + S7: out_proj with spiral-inverse scatter
  for (int d = 0; d < 2; ++d)
    hipLaunchKernelGGL(transpose_k, dim3(24, 24), dim3(256), 0, stream,
        out_w[d], C_, C_, C_, OWT + (size_t)d*768*768, FLAG);
  for (int zz = 0; zz < 2; ++zz) {
    gb.A[zz] = Y + zz * SD; gb.amap[zz] = nullptr;
    gb.WT[zz] = OWT + (size_t)zz*768*768;
    gb.bias[zz] = nullptr;
    gb.out[zz] = (void*)(FUSED + zz * C_); gb.omap[zz] = IDX + zz * L_;
  }
  hipLaunchKernelGGL(mgemm_k, dim3(6, 32, 2), dim3(256), 0, stream,
      gb, C_, C_, C_, C_, 2*C_, 0, 0, (const void*)nullptr, 0, FLAG);

  // ---- T(fus_w1) + S8: h = gelu(fused @ fus_w1 + fus_b1), K=1536
  hipLaunchKernelGGL(transpose_k, dim3(24, 48), dim3(256), 0, stream,
      fus_w1, 2*C_, C_, 2*C_, FW1T, FLAG);
  gb.A[0] = FUSED; gb.amap[0] = nullptr;
  gb.WT[0] = FW1T; gb.bias[0] = fus_b1;
  gb.out[0] = (void*)HBUF; gb.omap[0] = nullptr;
  hipLaunchKernelGGL(mgemm_k, dim3(6, 32, 1), dim3(256), 0, stream,
      gb, 2*C_, 2*C_, C_, 2*C_, C_, 2, 0, (const void*)nullptr, 0, FLAG);

  // ---- T(fus_w2) + S9: out = h @ fus_w2 + fus_b2 + x
  hipLaunchKernelGGL(transpose_k, dim3(24, 24), dim3(256), 0, stream,
      fus_w2, C_, C_, C_, FW2T, FLAG);
  gb.A[0] = HBUF; gb.amap[0] = nullptr;
  gb.WT[0] = FW2T; gb.bias[0] = fus_b2;
  gb.out[0] = d_out; gb.omap[0] = nullptr;
  hipLaunchKernelGGL(mgemm_k, dim3(6, 32, 1), dim3(256), 0, stream,
      gb, C_, C_, C_, C_, C_, 0, 2, x, C_, FLAG);
}

// Round 6
// 621.389 us; speedup vs baseline: 2.8178x; 1.2122x over previous
//
#include <hip/hip_runtime.h>

typedef unsigned short ushort_t;
typedef __attribute__((ext_vector_type(8))) short short8;
typedef __attribute__((ext_vector_type(4))) float f32x4;

#define B_ 4
#define L_ 1024
#define C_ 768
#define N_ 16
#define DR_ 48
#define HW_ 32
#define M_ (B_*L_)   // 4096 rows
#define SEG_ 64      // scan segment length
#define NSEG_ 16     // L_/SEG_

// Workspace layout (byte offsets), total 59,252,992 B:
//   0        IDX   (2*1024 int)
//   8192     FLAG
//   8448     XN region (6,291,456 B): XN -> {DTC, dtp^T} -> {SP,SQ bf16} -> HBUF
//   6299904  U region (12,582,912 B): U -> xproj^T -> DT -> {fus_w1^T, fus_w2^T}
//   18882816 Z region: Z -> FUSED
//   31465728 UC region: in_w^T -> UC -> out_w^T
//   44048640 DBL 2*M*80 f32
//   46670080 Y 2*M*C u16

__device__ __forceinline__ float bf2f(ushort_t u) {
  union { unsigned int i; float f; } v; v.i = ((unsigned int)u) << 16; return v.f;
}
__device__ __forceinline__ ushort_t f2bf(float f) {
  union { float f; unsigned int i; } v; v.f = f;
  unsigned int x = v.i;
  return (ushort_t)((x + 0x7fffu + ((x >> 16) & 1u)) >> 16);
}
__device__ __forceinline__ float ldf(const void* p, size_t i, int bf) {
  return bf ? bf2f(((const ushort_t*)p)[i]) : ((const float*)p)[i];
}
// async global->LDS, 16 B per lane; lds dest = wave-uniform base + lane*16
__device__ __forceinline__ void gload_lds16(const void* g, void* lds) {
  __builtin_amdgcn_global_load_lds(
      (const __attribute__((address_space(1))) unsigned int*)g,
      (__attribute__((address_space(3))) unsigned int*)lds, 16, 0, 0);
}

// ------------------------------------------------- spiral idx + dtype detect
__global__ void setup_k(const void* x, int* idx_cw, int* idx_ccw, int* flag) {
  int t = threadIdx.x;
  if (t == 0) {
    int top = 0, bottom = HW_-1, left = 0, right = HW_-1, p = 0;
    while (top <= bottom && left <= right) {
      for (int j = left; j <= right; j++) idx_cw[p++] = top*HW_ + j;
      top++;
      for (int i = top; i <= bottom; i++) idx_cw[p++] = i*HW_ + right;
      right--;
      if (top <= bottom) { for (int j = right; j >= left; j--) idx_cw[p++] = bottom*HW_ + j; bottom--; }
      if (left <= right) { for (int i = bottom; i >= top; i--) idx_cw[p++] = i*HW_ + left; left++; }
    }
  } else if (t == 1) {
    int top = 0, bottom = HW_-1, left = 0, right = HW_-1, p = 0;
    while (top <= bottom && left <= right) {
      for (int j = right; j >= left; j--) idx_ccw[p++] = top*HW_ + j;
      top++;
      for (int i = top; i <= bottom; i++) idx_ccw[p++] = i*HW_ + left;
      left++;
      if (top <= bottom) { for (int j = left; j <= right; j++) idx_ccw[p++] = bottom*HW_ + j; bottom--; }
      if (left <= right) { for (int i = bottom; i >= top; i--) idx_ccw[p++] = i*HW_ + right; right--; }
    }
  } else if (t == 2) {
    const ushort_t* u = (const ushort_t*)x;
    int bf = 1;
    for (int i = 0; i < 256; i++) {
      int e = (u[i] >> 7) & 0xFF;
      if (e < 90 || e > 141) { bf = 0; break; }
    }
    *flag = bf;
  }
}

// ---------------------------------------------------------------- layernorm
__global__ __launch_bounds__(256) void layernorm_k(
    const void* __restrict__ x, const void* __restrict__ w,
    const void* __restrict__ bb, ushort_t* __restrict__ xn,
    const int* __restrict__ flagp)
{
  const int inbf = *flagp;
  int row = blockIdx.x;
  int tid = threadIdx.x;
  size_t o0 = (size_t)row * C_;
  float v0 = ldf(x, o0 + tid,       inbf);
  float v1 = ldf(x, o0 + tid + 256, inbf);
  float v2 = ldf(x, o0 + tid + 512, inbf);
  float s = v0 + v1 + v2, s2 = v0*v0 + v1*v1 + v2*v2;
  for (int o = 32; o > 0; o >>= 1) { s += __shfl_down(s, o); s2 += __shfl_down(s2, o); }
  __shared__ float ss[4], ss2[4];
  if ((tid & 63) == 0) { ss[tid >> 6] = s; ss2[tid >> 6] = s2; }
  __syncthreads();
  s  = ss[0] + ss[1] + ss[2] + ss[3];
  s2 = ss2[0] + ss2[1] + ss2[2] + ss2[3];
  float mean = s * (1.f / C_);
  float var  = s2 * (1.f / C_) - mean * mean;
  float inv  = rsqrtf(var + 1e-6f);
  xn[o0 + tid]       = f2bf((v0 - mean) * inv * ldf(w, tid,     inbf) + ldf(bb, tid,     inbf));
  xn[o0 + tid + 256] = f2bf((v1 - mean) * inv * ldf(w, tid+256, inbf) + ldf(bb, tid+256, inbf));
  xn[o0 + tid + 512] = f2bf((v2 - mean) * inv * ldf(w, tid+512, inbf) + ldf(bb, tid+512, inbf));
}

// ---------------------------------------------------------------- transpose
__global__ __launch_bounds__(256) void transpose_k(
    const void* __restrict__ src, int R, int Cc, int ldD,
    ushort_t* __restrict__ dst, const int* __restrict__ flagp)
{
  const int inbf = *flagp;
  __shared__ ushort_t tile[32][33];
  int bx = blockIdx.x * 32;  // c
  int by = blockIdx.y * 32;  // r
  int tx = threadIdx.x & 31, ty = threadIdx.x >> 5;
  #pragma unroll
  for (int i = 0; i < 4; ++i) {
    int r = by + ty + i*8, c = bx + tx;
    ushort_t v = 0;
    if (r < R && c < Cc) v = f2bf(ldf(src, (size_t)r * Cc + c, inbf));
    tile[ty + i*8][tx] = v;
  }
  __syncthreads();
  #pragma unroll
  for (int i = 0; i < 4; ++i) {
    int dr = bx + ty + i*8, dc = by + tx;
    if (dr < Cc && dc < ldD)
      dst[(size_t)dr * ldD + dc] = tile[tx][ty + i*8];
  }
}

// ---------------------------------------------------------------- dtc pack
__global__ __launch_bounds__(256) void dtc_pack_k(
    const float* __restrict__ dbl, ushort_t* __restrict__ dtc)
{
  int g = blockIdx.x * 256 + threadIdx.x;
  int col = g & 63, row = g >> 6;
  float v = (col < DR_) ? dbl[(size_t)row * 80 + col] : 0.f;
  dtc[g] = f2bf(v);
}

// ---------------------------------------------------------------- MFMA GEMM
struct GB {
  const ushort_t* A[4]; const int* amap[4];
  const ushort_t* WT[4];
  const void* bias[4];
  void* out[4]; const int* omap[4];
};

__global__ __launch_bounds__(256) void mgemm_k(
    GB gb, int lda, int ldb, int Nn, int K, int ldo,
    int act, int out_mode, const void* resid, int ldr, const int* __restrict__ flagp)
{
  const int inbf = *flagp;
  const int z = blockIdx.z;
  const ushort_t* A  = gb.A[z];
  const int* amap    = gb.amap[z];
  const ushort_t* Bw = gb.WT[z];
  const void* bias   = gb.bias[z];
  void* Out          = gb.out[z];
  const int* omap    = gb.omap[z];

  __shared__ __align__(16) ushort_t As[128 * 64];  // [m][k], 16 KB
  __shared__ __align__(16) ushort_t Bs[128 * 64];  // [n][k], 16 KB

  const int tid  = threadIdx.x;
  const int w    = tid >> 6;
  const int lane = tid & 63;
  const int quad = lane >> 4;
  const int l15  = lane & 15;
  const int wm   = w >> 1, wn = w & 1;
  const int row0 = blockIdx.y * 128;
  const int col0 = blockIdx.x * 128;

  int agb[4], bgb[4], aldso[4], bldso[4];
  #pragma unroll
  for (int i = 0; i < 4; ++i) {
    int t  = i * 256 + w * 64 + lane;   // chunk id 0..1023
    int r  = t >> 3;
    int c  = (t & 7) ^ (r & 7);         // swizzle involution
    int grow = row0 + r;
    if (amap) { int b = grow >> 10, l = grow & 1023; grow = (b << 10) + amap[l]; }
    agb[i] = grow * lda + c * 8;
    bgb[i] = (col0 + r) * ldb + c * 8;
    aldso[i] = (i * 256 + w * 64) * 16;
    bldso[i] = aldso[i];
  }

  f32x4 acc[4][4];
  #pragma unroll
  for (int mi = 0; mi < 4; ++mi)
    #pragma unroll
    for (int ni = 0; ni < 4; ++ni)
      acc[mi][ni] = (f32x4){0.f, 0.f, 0.f, 0.f};

  const int sA = (l15 & 7);

  for (int k0 = 0; k0 < K; k0 += 64) {
    #pragma unroll
    for (int i = 0; i < 4; ++i)
      gload_lds16(A + agb[i] + k0, (char*)As + aldso[i]);
    #pragma unroll
    for (int i = 0; i < 4; ++i)
      gload_lds16(Bw + bgb[i] + k0, (char*)Bs + bldso[i]);
    __syncthreads();

    #pragma unroll
    for (int ks = 0; ks < 2; ++ks) {
      short8 aF[4], bF[4];
      #pragma unroll
      for (int mi = 0; mi < 4; ++mi)
        aF[mi] = *(const short8*)&As[(wm*64 + mi*16 + l15) * 64 + (((quad + 4*ks) ^ sA) * 8)];
      #pragma unroll
      for (int ni = 0; ni < 4; ++ni)
        bF[ni] = *(const short8*)&Bs[(wn*64 + ni*16 + l15) * 64 + (((quad + 4*ks) ^ sA) * 8)];
      #pragma unroll
      for (int mi = 0; mi < 4; ++mi)
        #pragma unroll
        for (int ni = 0; ni < 4; ++ni)
          acc[mi][ni] = __builtin_amdgcn_mfma_f32_16x16x32_bf16(aF[mi], bF[ni], acc[mi][ni], 0, 0, 0);
    }
    __syncthreads();
  }

  const int obf = (out_mode == 2) ? inbf : (out_mode == 0);
  #pragma unroll
  for (int ni = 0; ni < 4; ++ni) {
    int colg = col0 + wn*64 + ni*16 + l15;
    if (colg >= Nn) continue;
    float bv = bias ? ldf(bias, colg, inbf) : 0.f;
    #pragma unroll
    for (int mi = 0; mi < 4; ++mi) {
      #pragma unroll
      for (int r = 0; r < 4; ++r) {
        int rowg = row0 + wm*64 + mi*16 + quad*4 + r;
        int orow = rowg;
        if (omap) { int b = rowg >> 10, l = rowg & 1023; orow = (b << 10) + omap[l]; }
        float v = acc[mi][ni][r] + bv;
        if (act == 1)      v = (v > 20.f) ? v : log1pf(__expf(v));                  // softplus
        else if (act == 2) v = 0.5f * v * (1.f + erff(v * 0.70710678118654752f));   // gelu
        if (resid) v += ldf(resid, (size_t)orow * ldr + colg, inbf);
        size_t oi = (size_t)orow * ldo + colg;
        if (obf) ((ushort_t*)Out)[oi] = f2bf(v);
        else     ((float*)Out)[oi]    = v;
      }
    }
  }
}

// ---------------------------------------------------------------- conv(K=4)+silu
__global__ __launch_bounds__(256) void conv_silu_k(
    const ushort_t* __restrict__ u, const void* __restrict__ cw,
    const void* __restrict__ cb, ushort_t* __restrict__ uc,
    const int* __restrict__ flagp)
{
  const int inbf = *flagp;
  int g = blockIdx.x * 256 + threadIdx.x;
  int c = g % C_;
  int row = g / C_;
  int l = row % L_;
  float w0 = ldf(cw, c*4+0, inbf), w1 = ldf(cw, c*4+1, inbf);
  float w2 = ldf(cw, c*4+2, inbf), w3 = ldf(cw, c*4+3, inbf);
  const ushort_t* up = u + (size_t)(row - l) * C_ + c;
  float s = ldf(cb, c, inbf);
  if (l >= 3) s += w0 * bf2f(up[(size_t)(l-3) * C_]);
  if (l >= 2) s += w1 * bf2f(up[(size_t)(l-2) * C_]);
  if (l >= 1) s += w2 * bf2f(up[(size_t)(l-1) * C_]);
  s += w3 * bf2f(up[(size_t)l * C_]);
  s = s / (1.f + __expf(-s));
  uc[g] = f2bf(s);
}

// ---------------------------------------------------------------- segmented scan
// thread = c (16 n-states in registers). grid (3, NSEG, 8=db).
// Pass 1: P = exp(a*sum(dt)) per seg (bf16), Q = local h end (bf16, h0=0).
__global__ __launch_bounds__(256) void scan_pass1(
    const ushort_t* __restrict__ dt, const ushort_t* __restrict__ uc,
    const float* __restrict__ dbl,
    const void* __restrict__ Alog_cw, const void* __restrict__ Alog_ccw,
    ushort_t* __restrict__ P, ushort_t* __restrict__ Q,
    const int* __restrict__ flagp)
{
  const int inbf = *flagp;
  const int db = blockIdx.z, d = db >> 2;
  const int s = blockIdx.y;
  const int tid = threadIdx.x;
  const int c = blockIdx.x * 256 + tid;
  const int l0 = s * SEG_;

  __shared__ __align__(16) float Bs[SEG_][32];
  {
    const float* src = dbl + ((size_t)db * L_ + l0) * 80 + DR_;
    #pragma unroll
    for (int i = 0; i < 2; ++i) {
      int idx = tid * 4 + i * 1024;
      int st = idx >> 5, col = idx & 31;
      *(f32x4*)&Bs[st][col] = *(const f32x4*)(src + (size_t)st * 80 + col);
    }
  }
  __syncthreads();

  const void* Alog = d ? Alog_ccw : Alog_cw;
  float a[16];
  #pragma unroll
  for (int n = 0; n < 16; ++n) a[n] = -__expf(ldf(Alog, c * N_ + n, inbf));

  const size_t rbase = ((size_t)db * L_ + l0) * C_ + c;
  const ushort_t* dtp = dt + rbase;
  const ushort_t* ucp = uc + rbase;

  float h[16];
  #pragma unroll
  for (int n = 0; n < 16; ++n) h[n] = 0.f;
  float S = 0.f;

  #pragma unroll 4
  for (int l = 0; l < SEG_; ++l) {
    float dtv = bf2f(dtp[(size_t)l * C_]);
    float ucv = bf2f(ucp[(size_t)l * C_]);
    float dtu = dtv * ucv;
    S += dtv;
    f32x4 bq0 = *(const f32x4*)&Bs[l][0];
    f32x4 bq1 = *(const f32x4*)&Bs[l][4];
    f32x4 bq2 = *(const f32x4*)&Bs[l][8];
    f32x4 bq3 = *(const f32x4*)&Bs[l][12];
    #pragma unroll
    for (int j = 0; j < 4; ++j) { float dA = __expf(dtv*a[j]);    h[j]    = h[j]   *dA + dtu*bq0[j]; }
    #pragma unroll
    for (int j = 0; j < 4; ++j) { float dA = __expf(dtv*a[4+j]);  h[4+j]  = h[4+j] *dA + dtu*bq1[j]; }
    #pragma unroll
    for (int j = 0; j < 4; ++j) { float dA = __expf(dtv*a[8+j]);  h[8+j]  = h[8+j] *dA + dtu*bq2[j]; }
    #pragma unroll
    for (int j = 0; j < 4; ++j) { float dA = __expf(dtv*a[12+j]); h[12+j] = h[12+j]*dA + dtu*bq3[j]; }
  }
  size_t idx = (((size_t)db * NSEG_ + s) * C_ + c) * N_;
  #pragma unroll
  for (int n = 0; n < 16; ++n) {
    P[idx + n] = f2bf(__expf(a[n] * S));
    Q[idx + n] = f2bf(h[n]);
  }
}

// Pass 2: per (db,c,n) combine segments; Q[s] becomes segment-START seed.
__global__ __launch_bounds__(256) void scan_pass2(
    ushort_t* __restrict__ P, ushort_t* __restrict__ Q)
{
  size_t g = (size_t)blockIdx.x * 256 + threadIdx.x;   // 8*768*16 = 98304
  size_t db = g / (C_ * N_);
  size_t cn = g % (C_ * N_);
  float h = 0.f;
  #pragma unroll
  for (int s = 0; s < NSEG_; ++s) {
    size_t off = (db * NSEG_ + s) * (C_ * N_) + cn;
    float p = bf2f(P[off]), q = bf2f(Q[off]);
    Q[off] = f2bf(h);
    h = h * p + q;
  }
}

// Pass 3: recompute local scan seeded with Q; y = sum_n h*C + D*uc, z-gated.
__global__ __launch_bounds__(256) void scan_pass3(
    const ushort_t* __restrict__ dt, const ushort_t* __restrict__ uc,
    const float* __restrict__ dbl, const ushort_t* __restrict__ z,
    const void* __restrict__ Alog_cw, const void* __restrict__ Alog_ccw,
    const void* __restrict__ D_cw, const void* __restrict__ D_ccw,
    const ushort_t* __restrict__ Q, ushort_t* __restrict__ y,
    const int* __restrict__ flagp)
{
  const int inbf = *flagp;
  const int db = blockIdx.z, d = db >> 2;
  const int s = blockIdx.y;
  const int tid = threadIdx.x;
  const int c = blockIdx.x * 256 + tid;
  const int l0 = s * SEG_;

  __shared__ __align__(16) float Bs[SEG_][32];   // cols 0..15 = B, 16..31 = C
  {
    const float* src = dbl + ((size_t)db * L_ + l0) * 80 + DR_;
    #pragma unroll
    for (int i = 0; i < 2; ++i) {
      int idx = tid * 4 + i * 1024;
      int st = idx >> 5, col = idx & 31;
      *(f32x4*)&Bs[st][col] = *(const f32x4*)(src + (size_t)st * 80 + col);
    }
  }
  __syncthreads();

  const void* Alog = d ? Alog_ccw : Alog_cw;
  const void* Dp   = d ? D_ccw   : D_cw;
  float a[16];
  #pragma unroll
  for (int n = 0; n < 16; ++n) a[n] = -__expf(ldf(Alog, c * N_ + n, inbf));
  const float dvc = ldf(Dp, c, inbf);

  const size_t rbase = ((size_t)db * L_ + l0) * C_ + c;
  const ushort_t* dtp = dt + rbase;
  const ushort_t* ucp = uc + rbase;
  const ushort_t* zp  = z  + rbase;
  ushort_t* yp = y + rbase;

  size_t idx = (((size_t)db * NSEG_ + s) * C_ + c) * N_;
  float h[16];
  #pragma unroll
  for (int n = 0; n < 16; ++n) h[n] = bf2f(Q[idx + n]);

  #pragma unroll 2
  for (int l = 0; l < SEG_; ++l) {
    float dtv = bf2f(dtp[(size_t)l * C_]);
    float ucv = bf2f(ucp[(size_t)l * C_]);
    float zv  = bf2f(zp[(size_t)l * C_]);
    float dtu = dtv * ucv;
    f32x4 bq0 = *(const f32x4*)&Bs[l][0];
    f32x4 bq1 = *(const f32x4*)&Bs[l][4];
    f32x4 bq2 = *(const f32x4*)&Bs[l][8];
    f32x4 bq3 = *(const f32x4*)&Bs[l][12];
    f32x4 cq0 = *(const f32x4*)&Bs[l][16];
    f32x4 cq1 = *(const f32x4*)&Bs[l][20];
    f32x4 cq2 = *(const f32x4*)&Bs[l][24];
    f32x4 cq3 = *(const f32x4*)&Bs[l][28];
    float yv = dvc * ucv;
    #pragma unroll
    for (int j = 0; j < 4; ++j) { float dA = __expf(dtv*a[j]);    h[j]    = h[j]   *dA + dtu*bq0[j]; yv += h[j]   *cq0[j]; }
    #pragma unroll
    for (int j = 0; j < 4; ++j) { float dA = __expf(dtv*a[4+j]);  h[4+j]  = h[4+j] *dA + dtu*bq1[j]; yv += h[4+j] *cq1[j]; }
    #pragma unroll
    for (int j = 0; j < 4; ++j) { float dA = __expf(dtv*a[8+j]);  h[8+j]  = h[8+j] *dA + dtu*bq2[j]; yv += h[8+j] *cq2[j]; }
    #pragma unroll
    for (int j = 0; j < 4; ++j) { float dA = __expf(dtv*a[12+j]); h[12+j] = h[12+j]*dA + dtu*bq3[j]; yv += h[12+j]*cq3[j]; }
    yv *= zv / (1.f + __expf(-zv));   // * silu(z)
    yp[(size_t)l * C_] = f2bf(yv);
  }
}

// ---------------------------------------------------------------- launch
extern "C" void kernel_launch(void* const* d_in, const int* in_sizes, int n_in,
                              void* d_out, int out_size, void* d_ws, size_t ws_size,
                              hipStream_t stream)
{
  const void* x      = d_in[0];
  const void* norm_w = d_in[1];
  const void* norm_b = d_in[2];
  const void* in_w[2]    = { d_in[3],  d_in[12] };
  const void* conv_w[2]  = { d_in[4],  d_in[13] };
  const void* conv_b[2]  = { d_in[5],  d_in[14] };
  const void* xproj_w[2] = { d_in[6],  d_in[15] };
  const void* dtp_w[2]   = { d_in[7],  d_in[16] };
  const void* dtp_b[2]   = { d_in[8],  d_in[17] };
  const void* A_log[2]   = { d_in[9],  d_in[18] };
  const void* Dvec[2]    = { d_in[10], d_in[19] };
  const void* out_w[2]   = { d_in[11], d_in[20] };
  const void* fus_w1 = d_in[21];
  const void* fus_b1 = d_in[22];
  const void* fus_w2 = d_in[23];
  const void* fus_b2 = d_in[24];

  char* base = (char*)d_ws;
  int*      IDX  = (int*)base;
  int*      FLAG = (int*)(base + 8192);
  ushort_t* XN   = (ushort_t*)(base + 8448);
  ushort_t* U    = (ushort_t*)(base + 6299904);
  ushort_t* Z    = (ushort_t*)(base + 18882816);
  ushort_t* UC   = (ushort_t*)(base + 31465728);
  float*    DBL  = (float*)(base + 44048640);
  ushort_t* Y    = (ushort_t*)(base + 46670080);
  // lifetime aliases
  ushort_t* DT    = U;                                    // S5 out, S6 in
  ushort_t* FUSED = Z;                                    // S7 out, S8 in
  ushort_t* HBUF  = XN;                                   // S8 out, S9 in
  ushort_t* SP = (ushort_t*)(base + 8448);                // S6 only (bf16)
  ushort_t* SQ = SP + (size_t)2 * 4 * NSEG_ * C_ * N_;    // +1,572,864 elems
  // JIT weight transposes (bf16), in regions dead at use time:
  ushort_t* INWT = UC;                                    // [2][1536][768], S2
  ushort_t* XPJT = U;                                     // [2][128pad][768], S4
  ushort_t* DTC  = XN;                                    // [2*M][64], S4.5 -> S5
  ushort_t* DTPT = (ushort_t*)(base + 8448 + 1048576);    // [2][768][64], S5
  ushort_t* OWT  = UC;                                    // [2][768][768], S7
  ushort_t* FW1T = U;                                     // [768][1536], S8
  ushort_t* FW2T = U + (size_t)768 * 1536;                // [768][768], S9

  const size_t SD = (size_t)M_ * C_;

  hipLaunchKernelGGL(setup_k, dim3(1), dim3(64), 0, stream, x, IDX, IDX + L_, FLAG);
  hipLaunchKernelGGL(layernorm_k, dim3(M_), dim3(256), 0, stream, x, norm_w, norm_b, XN, FLAG);

  GB gb;
  // ---- T(in_w): [768][1536] -> [1536][768]
  for (int d = 0; d < 2; ++d)
    hipLaunchKernelGGL(transpose_k, dim3(48, 24), dim3(256), 0, stream,
        in_w[d], C_, 2*C_, C_, INWT + (size_t)d*1536*768, FLAG);
  // ---- S2: in_proj, z = (d, u/z half)
  for (int zz = 0; zz < 4; ++zz) {
    int d = zz >> 1, half = zz & 1;
    gb.A[zz] = XN; gb.amap[zz] = IDX + d * L_;
    gb.WT[zz] = INWT + (size_t)d*1536*768 + (size_t)half*768*768;
    gb.bias[zz] = nullptr;
    gb.out[zz] = (void*)((half ? Z : U) + d * SD); gb.omap[zz] = nullptr;
  }
  hipLaunchKernelGGL(mgemm_k, dim3(6, 32, 4), dim3(256), 0, stream,
      gb, C_, C_, C_, C_, C_, 0, 0, (const void*)nullptr, 0, FLAG);

  // ---- S3: conv + silu
  for (int d = 0; d < 2; ++d)
    hipLaunchKernelGGL(conv_silu_k, dim3(M_*C_/256), dim3(256), 0, stream,
        U + d*SD, conv_w[d], conv_b[d], UC + d*SD, FLAG);

  // ---- T(xproj): [768][80] -> [80][768]
  for (int d = 0; d < 2; ++d)
    hipLaunchKernelGGL(transpose_k, dim3(3, 24), dim3(256), 0, stream,
        xproj_w[d], C_, 80, C_, XPJT + (size_t)d*128*768, FLAG);
  // ---- S4: xproj -> DBL fp32, Nn=80
  for (int zz = 0; zz < 2; ++zz) {
    gb.A[zz] = UC + zz * SD; gb.amap[zz] = nullptr;
    gb.WT[zz] = XPJT + (size_t)zz*128*768;
    gb.bias[zz] = nullptr;
    gb.out[zz] = (void*)(DBL + (size_t)zz * M_ * 80); gb.omap[zz] = nullptr;
  }
  hipLaunchKernelGGL(mgemm_k, dim3(1, 32, 2), dim3(256), 0, stream,
      gb, C_, C_, 80, C_, 80, 0, 1, (const void*)nullptr, 0, FLAG);

  // ---- pack dtc (zero-padded K=64) + T(dtp): [48][768] -> [768][64]
  hipLaunchKernelGGL(dtc_pack_k, dim3(2*M_*64/256), dim3(256), 0, stream, DBL, DTC);
  for (int d = 0; d < 2; ++d)
    hipLaunchKernelGGL(transpose_k, dim3(24, 2), dim3(256), 0, stream,
        dtp_w[d], DR_, C_, 64, DTPT + (size_t)d*768*64, FLAG);
  // ---- S5: dt = softplus(dtc @ dtp_w + dtp_b), K=64
  for (int zz = 0; zz < 2; ++zz) {
    gb.A[zz] = DTC + (size_t)zz * M_ * 64; gb.amap[zz] = nullptr;
    gb.WT[zz] = DTPT + (size_t)zz*768*64;
    gb.bias[zz] = dtp_b[zz];
    gb.out[zz] = (void*)(DT + zz * SD); gb.omap[zz] = nullptr;
  }
  hipLaunchKernelGGL(mgemm_k, dim3(6, 32, 2), dim3(256), 0, stream,
      gb, 64, 64, C_, 64, C_, 1, 0, (const void*)nullptr, 0, FLAG);

  // ---- S6: segmented selective scan (register-resident n-states)
  hipLaunchKernelGGL(scan_pass1, dim3(3, NSEG_, 8), dim3(256), 0, stream,
      DT, UC, DBL, A_log[0], A_log[1], SP, SQ, FLAG);
  hipLaunchKernelGGL(scan_pass2, dim3(8 * C_ * N_ / 256), dim3(256), 0, stream, SP, SQ);
  hipLaunchKernelGGL(scan_pass3, dim3(3, NSEG_, 8), dim3(256), 0, stream,
      DT, UC, DBL, Z, A_log[0], A_log[1], Dvec[0], Dvec[1], SQ, Y, FLAG);

  // ---- T(out_w) + S7: out_proj with spiral-inverse scatter
  for (int d = 0; d < 2; ++d)
    hipLaunchKernelGGL(transpose_k, dim3(24, 24), dim3(256), 0, stream,
        out_w[d], C_, C_, C_, OWT + (size_t)d*768*768, FLAG);
  for (int zz = 0; zz < 2; ++zz) {
    gb.A[zz] = Y + zz * SD; gb.amap[zz] = nullptr;
    gb.WT[zz] = OWT + (size_t)zz*768*768;
    gb.bias[zz] = nullptr;
    gb.out[zz] = (void*)(FUSED + zz * C_); gb.omap[zz] = IDX + zz * L_;
  }
  hipLaunchKernelGGL(mgemm_k, dim3(6, 32, 2), dim3(256), 0, stream,
      gb, C_, C_, C_, C_, 2*C_, 0, 0, (const void*)nullptr, 0, FLAG);

  // ---- T(fus_w1) + S8: h = gelu(fused @ fus_w1 + fus_b1), K=1536
  hipLaunchKernelGGL(transpose_k, dim3(24, 48), dim3(256), 0, stream,
      fus_w1, 2*C_, C_, 2*C_, FW1T, FLAG);
  gb.A[0] = FUSED; gb.amap[0] = nullptr;
  gb.WT[0] = FW1T; gb.bias[0] = fus_b1;
  gb.out[0] = (void*)HBUF; gb.omap[0] = nullptr;
  hipLaunchKernelGGL(mgemm_k, dim3(6, 32, 1), dim3(256), 0, stream,
      gb, 2*C_, 2*C_, C_, 2*C_, C_, 2, 0, (const void*)nullptr, 0, FLAG);

  // ---- T(fus_w2) + S9: out = h @ fus_w2 + fus_b2 + x
  hipLaunchKernelGGL(transpose_k, dim3(24, 24), dim3(256), 0, stream,
      fus_w2, C_, C_, C_, FW2T, FLAG);
  gb.A[0] = HBUF; gb.amap[0] = nullptr;
  gb.WT[0] = FW2T; gb.bias[0] = fus_b2;
  gb.out[0] = d_out; gb.omap[0] = nullptr;
  hipLaunchKernelGGL(mgemm_k, dim3(6, 32, 1), dim3(256), 0, stream,
      gb, C_, C_, C_, C_, C_, 0, 2, x, C_, FLAG);
}

// Round 7
// 552.634 us; speedup vs baseline: 3.1683x; 1.1244x over previous
//
#include <hip/hip_runtime.h>

typedef unsigned short ushort_t;
typedef __attribute__((ext_vector_type(8))) short short8;
typedef __attribute__((ext_vector_type(4))) float f32x4;

#define B_ 4
#define L_ 1024
#define C_ 768
#define N_ 16
#define DR_ 48
#define HW_ 32
#define M_ (B_*L_)   // 4096 rows
#define SEG_ 64      // scan segment length
#define NSEG_ 16     // L_/SEG_

// Workspace layout (byte offsets), total 59,252,992 B:
//   0        IDX   (2*1024 int)
//   8192     FLAG
//   8448     XN region: XN -> DTC -> {SP,SQ bf16} -> HBUF
//   6299904  U region: U -> DT -> {fus_w1^T, fus_w2^T}
//   18882816 Z region: Z -> FUSED
//   31465728 UC region: in_w^T -> UC
//   44048640 DBL 2*M*80 f32
//   46670080 Y 2*M*C u16
// d_out doubles as scratch for {xproj^T, dtp^T, out_w^T} until S7 (dead til S9).

__device__ __forceinline__ float bf2f(ushort_t u) {
  union { unsigned int i; float f; } v; v.i = ((unsigned int)u) << 16; return v.f;
}
__device__ __forceinline__ ushort_t f2bf(float f) {
  union { float f; unsigned int i; } v; v.f = f;
  unsigned int x = v.i;
  return (ushort_t)((x + 0x7fffu + ((x >> 16) & 1u)) >> 16);
}
__device__ __forceinline__ float ldf(const void* p, size_t i, int bf) {
  return bf ? bf2f(((const ushort_t*)p)[i]) : ((const float*)p)[i];
}
// async global->LDS, 16 B per lane; lds dest = wave-uniform base + lane*16
__device__ __forceinline__ void gload_lds16(const void* g, void* lds) {
  __builtin_amdgcn_global_load_lds(
      (const __attribute__((address_space(1))) unsigned int*)g,
      (__attribute__((address_space(3))) unsigned int*)lds, 16, 0, 0);
}

// ------------------------------------------------- spiral idx + dtype detect
__global__ void setup_k(const void* x, int* idx_cw, int* idx_ccw, int* flag) {
  int t = threadIdx.x;
  if (t == 0) {
    int top = 0, bottom = HW_-1, left = 0, right = HW_-1, p = 0;
    while (top <= bottom && left <= right) {
      for (int j = left; j <= right; j++) idx_cw[p++] = top*HW_ + j;
      top++;
      for (int i = top; i <= bottom; i++) idx_cw[p++] = i*HW_ + right;
      right--;
      if (top <= bottom) { for (int j = right; j >= left; j--) idx_cw[p++] = bottom*HW_ + j; bottom--; }
      if (left <= right) { for (int i = bottom; i >= top; i--) idx_cw[p++] = i*HW_ + left; left++; }
    }
  } else if (t == 1) {
    int top = 0, bottom = HW_-1, left = 0, right = HW_-1, p = 0;
    while (top <= bottom && left <= right) {
      for (int j = right; j >= left; j--) idx_ccw[p++] = top*HW_ + j;
      top++;
      for (int i = top; i <= bottom; i++) idx_ccw[p++] = i*HW_ + left;
      left++;
      if (top <= bottom) { for (int j = left; j <= right; j++) idx_ccw[p++] = bottom*HW_ + j; bottom--; }
      if (left <= right) { for (int i = bottom; i >= top; i--) idx_ccw[p++] = i*HW_ + right; right--; }
    }
  } else if (t == 2) {
    const ushort_t* u = (const ushort_t*)x;
    int bf = 1;
    for (int i = 0; i < 256; i++) {
      int e = (u[i] >> 7) & 0xFF;
      if (e < 90 || e > 141) { bf = 0; break; }
    }
    *flag = bf;
  }
}

// ---------------------------------------------------------------- layernorm
__global__ __launch_bounds__(256) void layernorm_k(
    const void* __restrict__ x, const void* __restrict__ w,
    const void* __restrict__ bb, ushort_t* __restrict__ xn,
    const int* __restrict__ flagp)
{
  const int inbf = *flagp;
  int row = blockIdx.x;
  int tid = threadIdx.x;
  size_t o0 = (size_t)row * C_;
  float v0 = ldf(x, o0 + tid,       inbf);
  float v1 = ldf(x, o0 + tid + 256, inbf);
  float v2 = ldf(x, o0 + tid + 512, inbf);
  float s = v0 + v1 + v2, s2 = v0*v0 + v1*v1 + v2*v2;
  for (int o = 32; o > 0; o >>= 1) { s += __shfl_down(s, o); s2 += __shfl_down(s2, o); }
  __shared__ float ss[4], ss2[4];
  if ((tid & 63) == 0) { ss[tid >> 6] = s; ss2[tid >> 6] = s2; }
  __syncthreads();
  s  = ss[0] + ss[1] + ss[2] + ss[3];
  s2 = ss2[0] + ss2[1] + ss2[2] + ss2[3];
  float mean = s * (1.f / C_);
  float var  = s2 * (1.f / C_) - mean * mean;
  float inv  = rsqrtf(var + 1e-6f);
  xn[o0 + tid]       = f2bf((v0 - mean) * inv * ldf(w, tid,     inbf) + ldf(bb, tid,     inbf));
  xn[o0 + tid + 256] = f2bf((v1 - mean) * inv * ldf(w, tid+256, inbf) + ldf(bb, tid+256, inbf));
  xn[o0 + tid + 512] = f2bf((v2 - mean) * inv * ldf(w, tid+512, inbf) + ldf(bb, tid+512, inbf));
}

// ---------------------------------------------------------------- batched transpose
// Job j: dst[c][r] = src[r][c], src [R][Cc] (dtype per flag), dst bf16 [RD][ldD],
// OOB source entries -> 0 (zero-padding for RD > Cc or ldD > R).
struct TJ {
  const void* src[8]; ushort_t* dst[8];
  int R[8], Cc[8], RD[8], ldD[8];
  int off[9]; int njobs;
};

__global__ __launch_bounds__(256) void tbatch_k(TJ tj, const int* __restrict__ flagp) {
  const int inbf = *flagp;
  int bid = blockIdx.x;
  int j = 0;
  while (bid >= tj.off[j+1]) ++j;
  const void* src = tj.src[j];
  ushort_t* dst = tj.dst[j];
  const int R = tj.R[j], Cc = tj.Cc[j], RD = tj.RD[j], ldD = tj.ldD[j];
  int cb_span = (Cc > RD ? Cc : RD);
  int txt = (cb_span + 31) >> 5;
  int t = bid - tj.off[j];
  int bx = (t % txt) * 32;             // src col / dst row
  int by = (t / txt) * 32;             // src row / dst col
  __shared__ ushort_t tile[32][33];
  int tx = threadIdx.x & 31, ty = threadIdx.x >> 5;
  #pragma unroll
  for (int i = 0; i < 4; ++i) {
    int r = by + ty + i*8, c = bx + tx;
    ushort_t v = 0;
    if (r < R && c < Cc) v = f2bf(ldf(src, (size_t)r * Cc + c, inbf));
    tile[ty + i*8][tx] = v;
  }
  __syncthreads();
  #pragma unroll
  for (int i = 0; i < 4; ++i) {
    int dr = bx + ty + i*8, dc = by + tx;
    if (dr < RD && dc < ldD)
      dst[(size_t)dr * ldD + dc] = tile[tx][ty + i*8];
  }
}

// ---------------------------------------------------------------- MFMA GEMM
// Out[M, Nn] = act(A[M,K] @ WT[N,K]^T + bias) (+resid). Tile 128 x BN x BK32,
// 256 thr / 4 waves (2x2), wave = 64 x BN/2 quadrant of 16x16x32 frags.
// Staging: global_load_lds w=16, LDS [row][k] 64 B rows, XOR chunk swizzle
// c' = c ^ (r&3). out2 (optional): bf16 copy of cols<48 zero-padded to 64
// (dtc extraction fused into xproj GEMM).
struct GB {
  const ushort_t* A[4]; const int* amap[4];
  const ushort_t* WT[4];
  const void* bias[4];
  void* out[4]; ushort_t* out2[4]; const int* omap[4];
};

template<int BN>
__global__ __launch_bounds__(256) void mgemm_k(
    GB gb, int lda, int ldb, int Nn, int K, int ldo,
    int act, int out_mode, const void* resid, int ldr, const int* __restrict__ flagp)
{
  constexpr int FN = BN / 32;    // n-frags per wave
  constexpr int NB = BN / 64;    // B staging chunks per thread
  const int inbf = *flagp;
  const int z = blockIdx.z;
  const ushort_t* A  = gb.A[z];
  const int* amap    = gb.amap[z];
  const ushort_t* Bw = gb.WT[z];
  const void* bias   = gb.bias[z];
  void* Out          = gb.out[z];
  ushort_t* out2     = gb.out2[z];
  const int* omap    = gb.omap[z];

  __shared__ __align__(16) ushort_t As[128 * 32];  // 8 KB
  __shared__ __align__(16) ushort_t Bs[BN * 32];   // 8 or 4 KB

  const int tid  = threadIdx.x;
  const int w    = tid >> 6;
  const int lane = tid & 63;
  const int quad = lane >> 4;
  const int l15  = lane & 15;
  const int wm   = w >> 1, wn = w & 1;
  const int row0 = blockIdx.y * 128;
  const int col0 = blockIdx.x * BN;

  int agb[2], bgb[NB], aldso[2], bldso[NB];
  #pragma unroll
  for (int i = 0; i < 2; ++i) {
    int t = i*256 + tid;
    int r = t >> 2;
    int c = (t & 3) ^ (r & 3);
    int grow = row0 + r;
    if (amap) { int b = grow >> 10, l = grow & 1023; grow = (b << 10) + amap[l]; }
    agb[i] = grow * lda + c * 8;
    aldso[i] = (i*256 + w*64) * 16;
  }
  #pragma unroll
  for (int i = 0; i < NB; ++i) {
    int t = i*256 + tid;
    int r = t >> 2;
    int c = (t & 3) ^ (r & 3);
    bgb[i] = (col0 + r) * ldb + c * 8;
    bldso[i] = (i*256 + w*64) * 16;
  }

  f32x4 acc[4][FN];
  #pragma unroll
  for (int mi = 0; mi < 4; ++mi)
    #pragma unroll
    for (int ni = 0; ni < FN; ++ni)
      acc[mi][ni] = (f32x4){0.f, 0.f, 0.f, 0.f};

  const int sw = l15 & 3;

  for (int k0 = 0; k0 < K; k0 += 32) {
    #pragma unroll
    for (int i = 0; i < 2; ++i)
      gload_lds16(A + agb[i] + k0, (char*)As + aldso[i]);
    #pragma unroll
    for (int i = 0; i < NB; ++i)
      gload_lds16(Bw + bgb[i] + k0, (char*)Bs + bldso[i]);
    __syncthreads();

    short8 aF[4], bF[FN];
    #pragma unroll
    for (int mi = 0; mi < 4; ++mi)
      aF[mi] = *(const short8*)&As[(wm*64 + mi*16 + l15) * 32 + ((quad ^ sw) * 8)];
    #pragma unroll
    for (int ni = 0; ni < FN; ++ni)
      bF[ni] = *(const short8*)&Bs[(wn*(BN/2) + ni*16 + l15) * 32 + ((quad ^ sw) * 8)];
    #pragma unroll
    for (int mi = 0; mi < 4; ++mi)
      #pragma unroll
      for (int ni = 0; ni < FN; ++ni)
        acc[mi][ni] = __builtin_amdgcn_mfma_f32_16x16x32_bf16(aF[mi], bF[ni], acc[mi][ni], 0, 0, 0);
    __syncthreads();
  }

  const int obf = (out_mode == 2) ? inbf : (out_mode == 0);
  #pragma unroll
  for (int ni = 0; ni < FN; ++ni) {
    int colg = col0 + wn*(BN/2) + ni*16 + l15;
    if (colg >= Nn) continue;
    float bv = bias ? ldf(bias, colg, inbf) : 0.f;
    #pragma unroll
    for (int mi = 0; mi < 4; ++mi) {
      #pragma unroll
      for (int r = 0; r < 4; ++r) {
        int rowg = row0 + wm*64 + mi*16 + quad*4 + r;
        int orow = rowg;
        if (omap) { int b = rowg >> 10, l = rowg & 1023; orow = (b << 10) + omap[l]; }
        float v = acc[mi][ni][r] + bv;
        if (out2 && colg < 64)
          out2[(size_t)orow * 64 + colg] = f2bf(colg < DR_ ? v : 0.f);
        if (act == 1)      v = (v > 20.f) ? v : log1pf(__expf(v));                  // softplus
        else if (act == 2) v = 0.5f * v * (1.f + erff(v * 0.70710678118654752f));   // gelu
        if (resid) v += ldf(resid, (size_t)orow * ldr + colg, inbf);
        size_t oi = (size_t)orow * ldo + colg;
        if (obf) ((ushort_t*)Out)[oi] = f2bf(v);
        else     ((float*)Out)[oi]    = v;
      }
    }
  }
}

// ---------------------------------------------------------------- conv(K=4)+silu
// merged both dirs: u is [2*M][C]; d = row >> 12
__global__ __launch_bounds__(256) void conv_silu_k(
    const ushort_t* __restrict__ u,
    const void* __restrict__ cw0, const void* __restrict__ cw1,
    const void* __restrict__ cb0, const void* __restrict__ cb1,
    ushort_t* __restrict__ uc, const int* __restrict__ flagp)
{
  const int inbf = *flagp;
  int g = blockIdx.x * 256 + threadIdx.x;
  int c = g % C_;
  int row = g / C_;
  int l = row & 1023;
  const void* cw = (row >> 12) ? cw1 : cw0;
  const void* cb = (row >> 12) ? cb1 : cb0;
  float w0 = ldf(cw, c*4+0, inbf), w1 = ldf(cw, c*4+1, inbf);
  float w2 = ldf(cw, c*4+2, inbf), w3 = ldf(cw, c*4+3, inbf);
  const ushort_t* up = u + (size_t)(row - l) * C_ + c;
  float s = ldf(cb, c, inbf);
  if (l >= 3) s += w0 * bf2f(up[(size_t)(l-3) * C_]);
  if (l >= 2) s += w1 * bf2f(up[(size_t)(l-2) * C_]);
  if (l >= 1) s += w2 * bf2f(up[(size_t)(l-1) * C_]);
  s += w3 * bf2f(up[(size_t)l * C_]);
  s = s / (1.f + __expf(-s));
  uc[g] = f2bf(s);
}

// ---------------------------------------------------------------- segmented scan
// thread = c (16 n-states in registers). grid (3, NSEG, 8=db).
__global__ __launch_bounds__(256) void scan_pass1(
    const ushort_t* __restrict__ dt, const ushort_t* __restrict__ uc,
    const float* __restrict__ dbl,
    const void* __restrict__ Alog_cw, const void* __restrict__ Alog_ccw,
    ushort_t* __restrict__ P, ushort_t* __restrict__ Q,
    const int* __restrict__ flagp)
{
  const int inbf = *flagp;
  const int db = blockIdx.z, d = db >> 2;
  const int s = blockIdx.y;
  const int tid = threadIdx.x;
  const int c = blockIdx.x * 256 + tid;
  const int l0 = s * SEG_;

  __shared__ __align__(16) float Bs[SEG_][32];
  {
    const float* src = dbl + ((size_t)db * L_ + l0) * 80 + DR_;
    #pragma unroll
    for (int i = 0; i < 2; ++i) {
      int idx = tid * 4 + i * 1024;
      int st = idx >> 5, col = idx & 31;
      *(f32x4*)&Bs[st][col] = *(const f32x4*)(src + (size_t)st * 80 + col);
    }
  }
  __syncthreads();

  const void* Alog = d ? Alog_ccw : Alog_cw;
  float a[16];
  #pragma unroll
  for (int n = 0; n < 16; ++n) a[n] = -__expf(ldf(Alog, c * N_ + n, inbf));

  const size_t rbase = ((size_t)db * L_ + l0) * C_ + c;
  const ushort_t* dtp = dt + rbase;
  const ushort_t* ucp = uc + rbase;

  float h[16];
  #pragma unroll
  for (int n = 0; n < 16; ++n) h[n] = 0.f;
  float S = 0.f;

  #pragma unroll 4
  for (int l = 0; l < SEG_; ++l) {
    float dtv = bf2f(dtp[(size_t)l * C_]);
    float ucv = bf2f(ucp[(size_t)l * C_]);
    float dtu = dtv * ucv;
    S += dtv;
    f32x4 bq0 = *(const f32x4*)&Bs[l][0];
    f32x4 bq1 = *(const f32x4*)&Bs[l][4];
    f32x4 bq2 = *(const f32x4*)&Bs[l][8];
    f32x4 bq3 = *(const f32x4*)&Bs[l][12];
    #pragma unroll
    for (int j = 0; j < 4; ++j) { float dA = __expf(dtv*a[j]);    h[j]    = h[j]   *dA + dtu*bq0[j]; }
    #pragma unroll
    for (int j = 0; j < 4; ++j) { float dA = __expf(dtv*a[4+j]);  h[4+j]  = h[4+j] *dA + dtu*bq1[j]; }
    #pragma unroll
    for (int j = 0; j < 4; ++j) { float dA = __expf(dtv*a[8+j]);  h[8+j]  = h[8+j] *dA + dtu*bq2[j]; }
    #pragma unroll
    for (int j = 0; j < 4; ++j) { float dA = __expf(dtv*a[12+j]); h[12+j] = h[12+j]*dA + dtu*bq3[j]; }
  }
  size_t idx = (((size_t)db * NSEG_ + s) * C_ + c) * N_;
  #pragma unroll
  for (int n = 0; n < 16; ++n) {
    P[idx + n] = f2bf(__expf(a[n] * S));
    Q[idx + n] = f2bf(h[n]);
  }
}

__global__ __launch_bounds__(256) void scan_pass2(
    ushort_t* __restrict__ P, ushort_t* __restrict__ Q)
{
  size_t g = (size_t)blockIdx.x * 256 + threadIdx.x;
  size_t db = g / (C_ * N_);
  size_t cn = g % (C_ * N_);
  float h = 0.f;
  #pragma unroll
  for (int s = 0; s < NSEG_; ++s) {
    size_t off = (db * NSEG_ + s) * (C_ * N_) + cn;
    float p = bf2f(P[off]), q = bf2f(Q[off]);
    Q[off] = f2bf(h);
    h = h * p + q;
  }
}

__global__ __launch_bounds__(256) void scan_pass3(
    const ushort_t* __restrict__ dt, const ushort_t* __restrict__ uc,
    const float* __restrict__ dbl, const ushort_t* __restrict__ z,
    const void* __restrict__ Alog_cw, const void* __restrict__ Alog_ccw,
    const void* __restrict__ D_cw, const void* __restrict__ D_ccw,
    const ushort_t* __restrict__ Q, ushort_t* __restrict__ y,
    const int* __restrict__ flagp)
{
  const int inbf = *flagp;
  const int db = blockIdx.z, d = db >> 2;
  const int s = blockIdx.y;
  const int tid = threadIdx.x;
  const int c = blockIdx.x * 256 + tid;
  const int l0 = s * SEG_;

  __shared__ __align__(16) float Bs[SEG_][32];   // cols 0..15 = B, 16..31 = C
  {
    const float* src = dbl + ((size_t)db * L_ + l0) * 80 + DR_;
    #pragma unroll
    for (int i = 0; i < 2; ++i) {
      int idx = tid * 4 + i * 1024;
      int st = idx >> 5, col = idx & 31;
      *(f32x4*)&Bs[st][col] = *(const f32x4*)(src + (size_t)st * 80 + col);
    }
  }
  __syncthreads();

  const void* Alog = d ? Alog_ccw : Alog_cw;
  const void* Dp   = d ? D_ccw   : D_cw;
  float a[16];
  #pragma unroll
  for (int n = 0; n < 16; ++n) a[n] = -__expf(ldf(Alog, c * N_ + n, inbf));
  const float dvc = ldf(Dp, c, inbf);

  const size_t rbase = ((size_t)db * L_ + l0) * C_ + c;
  const ushort_t* dtp = dt + rbase;
  const ushort_t* ucp = uc + rbase;
  const ushort_t* zp  = z  + rbase;
  ushort_t* yp = y + rbase;

  size_t idx = (((size_t)db * NSEG_ + s) * C_ + c) * N_;
  float h[16];
  #pragma unroll
  for (int n = 0; n < 16; ++n) h[n] = bf2f(Q[idx + n]);

  #pragma unroll 2
  for (int l = 0; l < SEG_; ++l) {
    float dtv = bf2f(dtp[(size_t)l * C_]);
    float ucv = bf2f(ucp[(size_t)l * C_]);
    float zv  = bf2f(zp[(size_t)l * C_]);
    float dtu = dtv * ucv;
    f32x4 bq0 = *(const f32x4*)&Bs[l][0];
    f32x4 bq1 = *(const f32x4*)&Bs[l][4];
    f32x4 bq2 = *(const f32x4*)&Bs[l][8];
    f32x4 bq3 = *(const f32x4*)&Bs[l][12];
    f32x4 cq0 = *(const f32x4*)&Bs[l][16];
    f32x4 cq1 = *(const f32x4*)&Bs[l][20];
    f32x4 cq2 = *(const f32x4*)&Bs[l][24];
    f32x4 cq3 = *(const f32x4*)&Bs[l][28];
    float yv = dvc * ucv;
    #pragma unroll
    for (int j = 0; j < 4; ++j) { float dA = __expf(dtv*a[j]);    h[j]    = h[j]   *dA + dtu*bq0[j]; yv += h[j]   *cq0[j]; }
    #pragma unroll
    for (int j = 0; j < 4; ++j) { float dA = __expf(dtv*a[4+j]);  h[4+j]  = h[4+j] *dA + dtu*bq1[j]; yv += h[4+j] *cq1[j]; }
    #pragma unroll
    for (int j = 0; j < 4; ++j) { float dA = __expf(dtv*a[8+j]);  h[8+j]  = h[8+j] *dA + dtu*bq2[j]; yv += h[8+j] *cq2[j]; }
    #pragma unroll
    for (int j = 0; j < 4; ++j) { float dA = __expf(dtv*a[12+j]); h[12+j] = h[12+j]*dA + dtu*bq3[j]; yv += h[12+j]*cq3[j]; }
    yv *= zv / (1.f + __expf(-zv));   // * silu(z)
    yp[(size_t)l * C_] = f2bf(yv);
  }
}

// ---------------------------------------------------------------- launch
extern "C" void kernel_launch(void* const* d_in, const int* in_sizes, int n_in,
                              void* d_out, int out_size, void* d_ws, size_t ws_size,
                              hipStream_t stream)
{
  const void* x      = d_in[0];
  const void* norm_w = d_in[1];
  const void* norm_b = d_in[2];
  const void* in_w[2]    = { d_in[3],  d_in[12] };
  const void* conv_w[2]  = { d_in[4],  d_in[13] };
  const void* conv_b[2]  = { d_in[5],  d_in[14] };
  const void* xproj_w[2] = { d_in[6],  d_in[15] };
  const void* dtp_w[2]   = { d_in[7],  d_in[16] };
  const void* dtp_b[2]   = { d_in[8],  d_in[17] };
  const void* A_log[2]   = { d_in[9],  d_in[18] };
  const void* Dvec[2]    = { d_in[10], d_in[19] };
  const void* out_w[2]   = { d_in[11], d_in[20] };
  const void* fus_w1 = d_in[21];
  const void* fus_b1 = d_in[22];
  const void* fus_w2 = d_in[23];
  const void* fus_b2 = d_in[24];

  char* base = (char*)d_ws;
  int*      IDX  = (int*)base;
  int*      FLAG = (int*)(base + 8192);
  ushort_t* XN   = (ushort_t*)(base + 8448);
  ushort_t* U    = (ushort_t*)(base + 6299904);
  ushort_t* Z    = (ushort_t*)(base + 18882816);
  ushort_t* UC   = (ushort_t*)(base + 31465728);
  float*    DBL  = (float*)(base + 44048640);
  ushort_t* Y    = (ushort_t*)(base + 46670080);
  // lifetime aliases
  ushort_t* DT    = U;                                  // S5 out, scan in
  ushort_t* FUSED = Z;                                  // S7 out, S8 in
  ushort_t* HBUF  = XN;                                 // S8 out, S9 in
  ushort_t* SP = (ushort_t*)(base + 8448);              // scan only (bf16)
  ushort_t* SQ = SP + (size_t)2 * 4 * NSEG_ * C_ * N_;
  ushort_t* DTC = XN;                                   // S4 out2, S5 in (dead before SP/SQ)
  // weight transposes: batch-1 into UC + d_out scratch; batch-2 into U
  ushort_t* INWT = UC;                                  // [2][1536][768], S2
  ushort_t* uout = (ushort_t*)d_out;
  ushort_t* XPJT = uout;                                // [2][128][768], S4
  ushort_t* DTPT = uout + 196608;                       // [2][768][64],  S5
  ushort_t* OWT  = uout + 294912;                       // [2][768][768], S7
  ushort_t* FW1T = U;                                   // [768][1536], S8
  ushort_t* FW2T = U + (size_t)768 * 1536;              // [768][768],  S9

  const size_t SD = (size_t)M_ * C_;

  hipLaunchKernelGGL(setup_k, dim3(1), dim3(64), 0, stream, x, IDX, IDX + L_, FLAG);

  // ---- batched transposes #1 (weights needed S2..S7)
  {
    TJ tj; tj.njobs = 8; int o = 0;
    for (int d = 0; d < 2; ++d) { // in_w: 768x1536 -> 1536x768
      int j = d;
      tj.src[j]=in_w[d]; tj.dst[j]=INWT+(size_t)d*1536*768;
      tj.R[j]=768; tj.Cc[j]=1536; tj.RD[j]=1536; tj.ldD[j]=768;
    }
    for (int d = 0; d < 2; ++d) { // xproj: 768x80 -> 128(pad)x768
      int j = 2+d;
      tj.src[j]=xproj_w[d]; tj.dst[j]=XPJT+(size_t)d*128*768;
      tj.R[j]=768; tj.Cc[j]=80; tj.RD[j]=128; tj.ldD[j]=768;
    }
    for (int d = 0; d < 2; ++d) { // dtp: 48x768 -> 768x64(pad)
      int j = 4+d;
      tj.src[j]=dtp_w[d]; tj.dst[j]=DTPT+(size_t)d*768*64;
      tj.R[j]=48; tj.Cc[j]=768; tj.RD[j]=768; tj.ldD[j]=64;
    }
    for (int d = 0; d < 2; ++d) { // out_w: 768x768 -> 768x768
      int j = 6+d;
      tj.src[j]=out_w[d]; tj.dst[j]=OWT+(size_t)d*768*768;
      tj.R[j]=768; tj.Cc[j]=768; tj.RD[j]=768; tj.ldD[j]=768;
    }
    tj.off[0] = 0;
    for (int j = 0; j < 8; ++j) {
      int cspan = tj.Cc[j] > tj.RD[j] ? tj.Cc[j] : tj.RD[j];
      int rspan = tj.R[j] > tj.ldD[j] ? tj.R[j] : tj.ldD[j];
      tj.off[j+1] = tj.off[j] + ((cspan+31)>>5) * ((rspan+31)>>5);
      o = tj.off[j+1];
    }
    hipLaunchKernelGGL(tbatch_k, dim3(o), dim3(256), 0, stream, tj, FLAG);
  }

  hipLaunchKernelGGL(layernorm_k, dim3(M_), dim3(256), 0, stream, x, norm_w, norm_b, XN, FLAG);

  GB gb;
  for (int i = 0; i < 4; ++i) { gb.out2[i] = nullptr; gb.omap[i] = nullptr; gb.amap[i] = nullptr; gb.bias[i] = nullptr; }

  // ---- S2: in_proj, z = (d, u/z half), BN=128
  for (int zz = 0; zz < 4; ++zz) {
    int d = zz >> 1, half = zz & 1;
    gb.A[zz] = XN; gb.amap[zz] = IDX + d * L_;
    gb.WT[zz] = INWT + (size_t)d*1536*768 + (size_t)half*768*768;
    gb.bias[zz] = nullptr;
    gb.out[zz] = (void*)((half ? Z : U) + d * SD); gb.out2[zz] = nullptr; gb.omap[zz] = nullptr;
  }
  hipLaunchKernelGGL(mgemm_k<128>, dim3(6, 32, 4), dim3(256), 0, stream,
      gb, C_, C_, C_, C_, C_, 0, 0, (const void*)nullptr, 0, FLAG);

  // ---- S3: conv + silu (both dirs, one dispatch)
  hipLaunchKernelGGL(conv_silu_k, dim3(2*M_*C_/256), dim3(256), 0, stream,
      U, conv_w[0], conv_w[1], conv_b[0], conv_b[1], UC, FLAG);

  // ---- S4: xproj -> DBL fp32 (+fused dtc extraction), BN=64, Nn=80
  for (int zz = 0; zz < 2; ++zz) {
    gb.A[zz] = UC + zz * SD; gb.amap[zz] = nullptr;
    gb.WT[zz] = XPJT + (size_t)zz*128*768;
    gb.bias[zz] = nullptr;
    gb.out[zz] = (void*)(DBL + (size_t)zz * M_ * 80);
    gb.out2[zz] = DTC + (size_t)zz * M_ * 64;
    gb.omap[zz] = nullptr;
  }
  hipLaunchKernelGGL(mgemm_k<64>, dim3(2, 32, 2), dim3(256), 0, stream,
      gb, C_, C_, 80, C_, 80, 0, 1, (const void*)nullptr, 0, FLAG);

  // ---- S5: dt = softplus(dtc @ dtp_w + dtp_b), K=64, BN=64
  for (int zz = 0; zz < 2; ++zz) {
    gb.A[zz] = DTC + (size_t)zz * M_ * 64; gb.amap[zz] = nullptr;
    gb.WT[zz] = DTPT + (size_t)zz*768*64;
    gb.bias[zz] = dtp_b[zz];
    gb.out[zz] = (void*)(DT + zz * SD); gb.out2[zz] = nullptr; gb.omap[zz] = nullptr;
  }
  hipLaunchKernelGGL(mgemm_k<64>, dim3(12, 32, 2), dim3(256), 0, stream,
      gb, 64, 64, C_, 64, C_, 1, 0, (const void*)nullptr, 0, FLAG);

  // ---- S6: segmented selective scan
  hipLaunchKernelGGL(scan_pass1, dim3(3, NSEG_, 8), dim3(256), 0, stream,
      DT, UC, DBL, A_log[0], A_log[1], SP, SQ, FLAG);
  hipLaunchKernelGGL(scan_pass2, dim3(8 * C_ * N_ / 256), dim3(256), 0, stream, SP, SQ);
  hipLaunchKernelGGL(scan_pass3, dim3(3, NSEG_, 8), dim3(256), 0, stream,
      DT, UC, DBL, Z, A_log[0], A_log[1], Dvec[0], Dvec[1], SQ, Y, FLAG);

  // ---- batched transposes #2 (fus weights; U region free after scan)
  {
    TJ tj; tj.njobs = 2;
    tj.src[0]=fus_w1; tj.dst[0]=FW1T; tj.R[0]=1536; tj.Cc[0]=768; tj.RD[0]=768; tj.ldD[0]=1536;
    tj.src[1]=fus_w2; tj.dst[1]=FW2T; tj.R[1]=768;  tj.Cc[1]=768; tj.RD[1]=768; tj.ldD[1]=768;
    tj.off[0] = 0;
    for (int j = 0; j < 2; ++j) {
      int cspan = tj.Cc[j] > tj.RD[j] ? tj.Cc[j] : tj.RD[j];
      int rspan = tj.R[j] > tj.ldD[j] ? tj.R[j] : tj.ldD[j];
      tj.off[j+1] = tj.off[j] + ((cspan+31)>>5) * ((rspan+31)>>5);
    }
    hipLaunchKernelGGL(tbatch_k, dim3(tj.off[2]), dim3(256), 0, stream, tj, FLAG);
  }

  // ---- S7: out_proj with spiral-inverse scatter, BN=128
  for (int zz = 0; zz < 2; ++zz) {
    gb.A[zz] = Y + zz * SD; gb.amap[zz] = nullptr;
    gb.WT[zz] = OWT + (size_t)zz*768*768;
    gb.bias[zz] = nullptr;
    gb.out[zz] = (void*)(FUSED + zz * C_); gb.out2[zz] = nullptr; gb.omap[zz] = IDX + zz * L_;
  }
  hipLaunchKernelGGL(mgemm_k<128>, dim3(6, 32, 2), dim3(256), 0, stream,
      gb, C_, C_, C_, C_, 2*C_, 0, 0, (const void*)nullptr, 0, FLAG);

  // ---- S8: h = gelu(fused @ fus_w1 + fus_b1), K=1536, BN=64
  gb.A[0] = FUSED; gb.amap[0] = nullptr;
  gb.WT[0] = FW1T; gb.bias[0] = fus_b1;
  gb.out[0] = (void*)HBUF; gb.out2[0] = nullptr; gb.omap[0] = nullptr;
  hipLaunchKernelGGL(mgemm_k<64>, dim3(12, 32, 1), dim3(256), 0, stream,
      gb, 2*C_, 2*C_, C_, 2*C_, C_, 2, 0, (const void*)nullptr, 0, FLAG);

  // ---- S9: out = h @ fus_w2 + fus_b2 + x, BN=64
  gb.A[0] = HBUF; gb.amap[0] = nullptr;
  gb.WT[0] = FW2T; gb.bias[0] = fus_b2;
  gb.out[0] = d_out; gb.out2[0] = nullptr; gb.omap[0] = nullptr;
  hipLaunchKernelGGL(mgemm_k<64>, dim3(12, 32, 1), dim3(256), 0, stream,
      gb, C_, C_, C_, C_, C_, 0, 2, x, C_, FLAG);
}

// Round 9
// 508.653 us; speedup vs baseline: 3.4423x; 1.0865x over previous
//
#include <hip/hip_runtime.h>

typedef unsigned short ushort_t;
typedef __attribute__((ext_vector_type(8))) short short8;
typedef __attribute__((ext_vector_type(4))) float f32x4;

#define B_ 4
#define L_ 1024
#define C_ 768
#define N_ 16
#define DR_ 48
#define HW_ 32
#define M_ (B_*L_)   // 4096 rows
#define SEG_ 64      // scan segment length
#define NSEG_ 16     // L_/SEG_

// Workspace layout (byte offsets), total 59,252,992 B:
//   0        IDX   (2*1024 int)
//   8192     FLAG
//   8448     XN region: XN -> DTC -> {SP,SQ bf16} -> HBUF
//   6299904  U region: U -> DT -> {fus_w1^T, fus_w2^T}
//   18882816 Z region: Z -> FUSED
//   31465728 UC region: in_w^T -> UC
//   44048640 DBL 2*M*80 f32
//   46670080 Y 2*M*C u16
// d_out doubles as scratch for {xproj^T, dtp^T, out_w^T} until S7 (dead til S9).

__device__ __forceinline__ float bf2f(ushort_t u) {
  union { unsigned int i; float f; } v; v.i = ((unsigned int)u) << 16; return v.f;
}
__device__ __forceinline__ ushort_t f2bf(float f) {
  union { float f; unsigned int i; } v; v.f = f;
  unsigned int x = v.i;
  return (ushort_t)((x + 0x7fffu + ((x >> 16) & 1u)) >> 16);
}
__device__ __forceinline__ float ldf(const void* p, size_t i, int bf) {
  return bf ? bf2f(((const ushort_t*)p)[i]) : ((const float*)p)[i];
}
// async global->LDS, 16 B per lane; lds dest = wave-uniform base + lane*16
__device__ __forceinline__ void gload_lds16(const void* g, void* lds) {
  __builtin_amdgcn_global_load_lds(
      (const __attribute__((address_space(1))) unsigned int*)g,
      (__attribute__((address_space(3))) unsigned int*)lds, 16, 0, 0);
}

// ------------------------------------------------- spiral idx + dtype detect
__global__ void setup_k(const void* x, int* idx_cw, int* idx_ccw, int* flag) {
  int t = threadIdx.x;
  if (t == 0) {
    int top = 0, bottom = HW_-1, left = 0, right = HW_-1, p = 0;
    while (top <= bottom && left <= right) {
      for (int j = left; j <= right; j++) idx_cw[p++] = top*HW_ + j;
      top++;
      for (int i = top; i <= bottom; i++) idx_cw[p++] = i*HW_ + right;
      right--;
      if (top <= bottom) { for (int j = right; j >= left; j--) idx_cw[p++] = bottom*HW_ + j; bottom--; }
      if (left <= right) { for (int i = bottom; i >= top; i--) idx_cw[p++] = i*HW_ + left; left++; }
    }
  } else if (t == 1) {
    int top = 0, bottom = HW_-1, left = 0, right = HW_-1, p = 0;
    while (top <= bottom && left <= right) {
      for (int j = right; j >= left; j--) idx_ccw[p++] = top*HW_ + j;
      top++;
      for (int i = top; i <= bottom; i++) idx_ccw[p++] = i*HW_ + left;
      left++;
      if (top <= bottom) { for (int j = left; j <= right; j++) idx_ccw[p++] = bottom*HW_ + j; bottom--; }
      if (left <= right) { for (int i = bottom; i >= top; i--) idx_ccw[p++] = i*HW_ + right; right--; }
    }
  } else if (t == 2) {
    const ushort_t* u = (const ushort_t*)x;
    int bf = 1;
    for (int i = 0; i < 256; i++) {
      int e = (u[i] >> 7) & 0xFF;
      if (e < 90 || e > 141) { bf = 0; break; }
    }
    *flag = bf;
  }
}

// ---------------------------------------------------------------- layernorm
__global__ __launch_bounds__(256) void layernorm_k(
    const void* __restrict__ x, const void* __restrict__ w,
    const void* __restrict__ bb, ushort_t* __restrict__ xn,
    const int* __restrict__ flagp)
{
  const int inbf = *flagp;
  int row = blockIdx.x;
  int tid = threadIdx.x;
  size_t o0 = (size_t)row * C_;
  float v0 = ldf(x, o0 + tid,       inbf);
  float v1 = ldf(x, o0 + tid + 256, inbf);
  float v2 = ldf(x, o0 + tid + 512, inbf);
  float s = v0 + v1 + v2, s2 = v0*v0 + v1*v1 + v2*v2;
  for (int o = 32; o > 0; o >>= 1) { s += __shfl_down(s, o); s2 += __shfl_down(s2, o); }
  __shared__ float ss[4], ss2[4];
  if ((tid & 63) == 0) { ss[tid >> 6] = s; ss2[tid >> 6] = s2; }
  __syncthreads();
  s  = ss[0] + ss[1] + ss[2] + ss[3];
  s2 = ss2[0] + ss2[1] + ss2[2] + ss2[3];
  float mean = s * (1.f / C_);
  float var  = s2 * (1.f / C_) - mean * mean;
  float inv  = rsqrtf(var + 1e-6f);
  xn[o0 + tid]       = f2bf((v0 - mean) * inv * ldf(w, tid,     inbf) + ldf(bb, tid,     inbf));
  xn[o0 + tid + 256] = f2bf((v1 - mean) * inv * ldf(w, tid+256, inbf) + ldf(bb, tid+256, inbf));
  xn[o0 + tid + 512] = f2bf((v2 - mean) * inv * ldf(w, tid+512, inbf) + ldf(bb, tid+512, inbf));
}

// ---------------------------------------------------------------- batched transpose
struct TJ {
  const void* src[8]; ushort_t* dst[8];
  int R[8], Cc[8], RD[8], ldD[8];
  int off[9]; int njobs;
};

__global__ __launch_bounds__(256) void tbatch_k(TJ tj, const int* __restrict__ flagp) {
  const int inbf = *flagp;
  int bid = blockIdx.x;
  int j = 0;
  while (bid >= tj.off[j+1]) ++j;
  const void* src = tj.src[j];
  ushort_t* dst = tj.dst[j];
  const int R = tj.R[j], Cc = tj.Cc[j], RD = tj.RD[j], ldD = tj.ldD[j];
  int cb_span = (Cc > RD ? Cc : RD);
  int txt = (cb_span + 31) >> 5;
  int t = bid - tj.off[j];
  int bx = (t % txt) * 32;             // src col / dst row
  int by = (t / txt) * 32;             // src row / dst col
  __shared__ ushort_t tile[32][33];
  int tx = threadIdx.x & 31, ty = threadIdx.x >> 5;
  #pragma unroll
  for (int i = 0; i < 4; ++i) {
    int r = by + ty + i*8, c = bx + tx;
    ushort_t v = 0;
    if (r < R && c < Cc) v = f2bf(ldf(src, (size_t)r * Cc + c, inbf));
    tile[ty + i*8][tx] = v;
  }
  __syncthreads();
  #pragma unroll
  for (int i = 0; i < 4; ++i) {
    int dr = bx + ty + i*8, dc = by + tx;
    if (dr < RD && dc < ldD)
      dst[(size_t)dr * ldD + dc] = tile[tx][ty + i*8];
  }
}

// ---------------------------------------------------------------- MFMA GEMM
// Out[M, Nn] = act(A[M,K] @ WT[N,K]^T + bias) (+resid). Tile 128 x BN x BK64,
// 256 thr / 4 waves (2x2). Staging: global_load_lds w=16, LDS [row][k] 128 B
// rows, XOR chunk swizzle c' = c ^ (r&7) (measured 0 conflicts, round 6).
// 1D grid with XCD-locality swizzle: xcd = bid%8 owns one z (weight set) and a
// y-cluster so per-XCD L2 working set stays < 4 MB.
struct GB {
  const ushort_t* A[4]; const int* amap[4];
  const ushort_t* WT[4];
  const void* bias[4];
  void* out[4]; ushort_t* out2[4]; const int* omap[4];
};

template<int BN>
__global__ __launch_bounds__(256) void mgemm_k(
    GB gb, int lda, int ldb, int Nn, int K, int ldo,
    int act, int out_mode, const void* resid, int ldr,
    int gx, int gz, const int* __restrict__ flagp)
{
  constexpr int FN = BN / 32;    // n-frags per wave
  constexpr int NB = BN / 32;    // B staging chunks per thread (BN*64*2/16/256)
  const int inbf = *flagp;

  // XCD/L2 block swizzle (gy = 32 fixed)
  const int ZW  = 8 / gz;
  const int bid = blockIdx.x;
  const int xcd = bid & 7;
  const int sl  = bid >> 3;
  const int z   = xcd / ZW;
  const int xb  = sl % gx;
  const int yb  = (sl / gx) * ZW + (xcd % ZW);

  const ushort_t* A  = gb.A[z];
  const int* amap    = gb.amap[z];
  const ushort_t* Bw = gb.WT[z];
  const void* bias   = gb.bias[z];
  void* Out          = gb.out[z];
  ushort_t* out2     = gb.out2[z];
  const int* omap    = gb.omap[z];

  __shared__ __align__(16) ushort_t As[128 * 64];  // 16 KB
  __shared__ __align__(16) ushort_t Bs[BN * 64];   // 16 or 8 KB

  const int tid  = threadIdx.x;
  const int w    = tid >> 6;
  const int lane = tid & 63;
  const int quad = lane >> 4;
  const int l15  = lane & 15;
  const int wm   = w >> 1, wn = w & 1;
  const int row0 = yb * 128;
  const int col0 = xb * BN;

  int agb[4], bgb[NB], aldso[4], bldso[NB];
  #pragma unroll
  for (int i = 0; i < 4; ++i) {
    int t = i*256 + tid;                // chunk 0..1023
    int r = t >> 3;
    int c = (t & 7) ^ (r & 7);          // swizzle involution
    int grow = row0 + r;
    if (amap) { int b = grow >> 10, l = grow & 1023; grow = (b << 10) + amap[l]; }
    agb[i] = grow * lda + c * 8;
    aldso[i] = (i*256 + w*64) * 16;
  }
  #pragma unroll
  for (int i = 0; i < NB; ++i) {
    int t = i*256 + tid;
    int r = t >> 3;
    int c = (t & 7) ^ (r & 7);
    bgb[i] = (col0 + r) * ldb + c * 8;
    bldso[i] = (i*256 + w*64) * 16;
  }

  f32x4 acc[4][FN];
  #pragma unroll
  for (int mi = 0; mi < 4; ++mi)
    #pragma unroll
    for (int ni = 0; ni < FN; ++ni)
      acc[mi][ni] = (f32x4){0.f, 0.f, 0.f, 0.f};

  const int sw = l15 & 7;

  for (int k0 = 0; k0 < K; k0 += 64) {
    #pragma unroll
    for (int i = 0; i < 4; ++i)
      gload_lds16(A + agb[i] + k0, (char*)As + aldso[i]);
    #pragma unroll
    for (int i = 0; i < NB; ++i)
      gload_lds16(Bw + bgb[i] + k0, (char*)Bs + bldso[i]);
    __syncthreads();

    #pragma unroll
    for (int ks = 0; ks < 2; ++ks) {
      short8 aF[4], bF[FN];
      #pragma unroll
      for (int mi = 0; mi < 4; ++mi)
        aF[mi] = *(const short8*)&As[(wm*64 + mi*16 + l15) * 64 + (((quad + 4*ks) ^ sw) * 8)];
      #pragma unroll
      for (int ni = 0; ni < FN; ++ni)
        bF[ni] = *(const short8*)&Bs[(wn*(BN/2) + ni*16 + l15) * 64 + (((quad + 4*ks) ^ sw) * 8)];
      #pragma unroll
      for (int mi = 0; mi < 4; ++mi)
        #pragma unroll
        for (int ni = 0; ni < FN; ++ni)
          acc[mi][ni] = __builtin_amdgcn_mfma_f32_16x16x32_bf16(aF[mi], bF[ni], acc[mi][ni], 0, 0, 0);
    }
    __syncthreads();
  }

  const int obf = (out_mode == 2) ? inbf : (out_mode == 0);
  #pragma unroll
  for (int ni = 0; ni < FN; ++ni) {
    int colg = col0 + wn*(BN/2) + ni*16 + l15;
    if (colg >= Nn) continue;
    float bv = bias ? ldf(bias, colg, inbf) : 0.f;
    #pragma unroll
    for (int mi = 0; mi < 4; ++mi) {
      #pragma unroll
      for (int r = 0; r < 4; ++r) {
        int rowg = row0 + wm*64 + mi*16 + quad*4 + r;
        int orow = rowg;
        if (omap) { int b = rowg >> 10, l = rowg & 1023; orow = (b << 10) + omap[l]; }
        float v = acc[mi][ni][r] + bv;
        if (out2 && colg < 64)
          out2[(size_t)orow * 64 + colg] = f2bf(colg < DR_ ? v : 0.f);
        if (act == 1)      v = (v > 20.f) ? v : log1pf(__expf(v));                  // softplus
        else if (act == 2) v = 0.5f * v * (1.f + erff(v * 0.70710678118654752f));   // gelu
        if (resid) v += ldf(resid, (size_t)orow * ldr + colg, inbf);
        size_t oi = (size_t)orow * ldo + colg;
        if (obf) ((ushort_t*)Out)[oi] = f2bf(v);
        else     ((float*)Out)[oi]    = v;
      }
    }
  }
}

// ---------------------------------------------------------------- conv(K=4)+silu
__global__ __launch_bounds__(256) void conv_silu_k(
    const ushort_t* __restrict__ u,
    const void* __restrict__ cw0, const void* __restrict__ cw1,
    const void* __restrict__ cb0, const void* __restrict__ cb1,
    ushort_t* __restrict__ uc, const int* __restrict__ flagp)
{
  const int inbf = *flagp;
  int g = blockIdx.x * 256 + threadIdx.x;
  int c = g % C_;
  int row = g / C_;
  int l = row & 1023;
  const void* cw = (row >> 12) ? cw1 : cw0;
  const void* cb = (row >> 12) ? cb1 : cb0;
  float w0 = ldf(cw, c*4+0, inbf), w1 = ldf(cw, c*4+1, inbf);
  float w2 = ldf(cw, c*4+2, inbf), w3 = ldf(cw, c*4+3, inbf);
  const ushort_t* up = u + (size_t)(row - l) * C_ + c;
  float s = ldf(cb, c, inbf);
  if (l >= 3) s += w0 * bf2f(up[(size_t)(l-3) * C_]);
  if (l >= 2) s += w1 * bf2f(up[(size_t)(l-2) * C_]);
  if (l >= 1) s += w2 * bf2f(up[(size_t)(l-1) * C_]);
  s += w3 * bf2f(up[(size_t)l * C_]);
  s = s / (1.f + __expf(-s));
  uc[g] = f2bf(s);
}

// ---------------------------------------------------------------- segmented scan
__global__ __launch_bounds__(256) void scan_pass1(
    const ushort_t* __restrict__ dt, const ushort_t* __restrict__ uc,
    const float* __restrict__ dbl,
    const void* __restrict__ Alog_cw, const void* __restrict__ Alog_ccw,
    ushort_t* __restrict__ P, ushort_t* __restrict__ Q,
    const int* __restrict__ flagp)
{
  const int inbf = *flagp;
  const int db = blockIdx.z, d = db >> 2;
  const int s = blockIdx.y;
  const int tid = threadIdx.x;
  const int c = blockIdx.x * 256 + tid;
  const int l0 = s * SEG_;

  __shared__ __align__(16) float Bs[SEG_][32];
  {
    const float* src = dbl + ((size_t)db * L_ + l0) * 80 + DR_;
    #pragma unroll
    for (int i = 0; i < 2; ++i) {
      int idx = tid * 4 + i * 1024;
      int st = idx >> 5, col = idx & 31;
      *(f32x4*)&Bs[st][col] = *(const f32x4*)(src + (size_t)st * 80 + col);
    }
  }
  __syncthreads();

  const void* Alog = d ? Alog_ccw : Alog_cw;
  float a[16];
  #pragma unroll
  for (int n = 0; n < 16; ++n) a[n] = -__expf(ldf(Alog, c * N_ + n, inbf));

  const size_t rbase = ((size_t)db * L_ + l0) * C_ + c;
  const ushort_t* dtp = dt + rbase;
  const ushort_t* ucp = uc + rbase;

  float h[16];
  #pragma unroll
  for (int n = 0; n < 16; ++n) h[n] = 0.f;
  float S = 0.f;

  #pragma unroll 4
  for (int l = 0; l < SEG_; ++l) {
    float dtv = bf2f(dtp[(size_t)l * C_]);
    float ucv = bf2f(ucp[(size_t)l * C_]);
    float dtu = dtv * ucv;
    S += dtv;
    f32x4 bq0 = *(const f32x4*)&Bs[l][0];
    f32x4 bq1 = *(const f32x4*)&Bs[l][4];
    f32x4 bq2 = *(const f32x4*)&Bs[l][8];
    f32x4 bq3 = *(const f32x4*)&Bs[l][12];
    #pragma unroll
    for (int j = 0; j < 4; ++j) { float dA = __expf(dtv*a[j]);    h[j]    = h[j]   *dA + dtu*bq0[j]; }
    #pragma unroll
    for (int j = 0; j < 4; ++j) { float dA = __expf(dtv*a[4+j]);  h[4+j]  = h[4+j] *dA + dtu*bq1[j]; }
    #pragma unroll
    for (int j = 0; j < 4; ++j) { float dA = __expf(dtv*a[8+j]);  h[8+j]  = h[8+j] *dA + dtu*bq2[j]; }
    #pragma unroll
    for (int j = 0; j < 4; ++j) { float dA = __expf(dtv*a[12+j]); h[12+j] = h[12+j]*dA + dtu*bq3[j]; }
  }
  size_t idx = (((size_t)db * NSEG_ + s) * C_ + c) * N_;
  #pragma unroll
  for (int n = 0; n < 16; ++n) {
    P[idx + n] = f2bf(__expf(a[n] * S));
    Q[idx + n] = f2bf(h[n]);
  }
}

__global__ __launch_bounds__(256) void scan_pass2(
    ushort_t* __restrict__ P, ushort_t* __restrict__ Q)
{
  size_t g = (size_t)blockIdx.x * 256 + threadIdx.x;
  size_t db = g / (C_ * N_);
  size_t cn = g % (C_ * N_);
  float h = 0.f;
  #pragma unroll
  for (int s = 0; s < NSEG_; ++s) {
    size_t off = (db * NSEG_ + s) * (C_ * N_) + cn;
    float p = bf2f(P[off]), q = bf2f(Q[off]);
    Q[off] = f2bf(h);
    h = h * p + q;
  }
}

__global__ __launch_bounds__(256) void scan_pass3(
    const ushort_t* __restrict__ dt, const ushort_t* __restrict__ uc,
    const float* __restrict__ dbl, const ushort_t* __restrict__ z,
    const void* __restrict__ Alog_cw, const void* __restrict__ Alog_ccw,
    const void* __restrict__ D_cw, const void* __restrict__ D_ccw,
    const ushort_t* __restrict__ Q, ushort_t* __restrict__ y,
    const int* __restrict__ flagp)
{
  const int inbf = *flagp;
  const int db = blockIdx.z, d = db >> 2;
  const int s = blockIdx.y;
  const int tid = threadIdx.x;
  const int c = blockIdx.x * 256 + tid;
  const int l0 = s * SEG_;

  __shared__ __align__(16) float Bs[SEG_][32];   // cols 0..15 = B, 16..31 = C
  {
    const float* src = dbl + ((size_t)db * L_ + l0) * 80 + DR_;
    #pragma unroll
    for (int i = 0; i < 2; ++i) {
      int idx = tid * 4 + i * 1024;
      int st = idx >> 5, col = idx & 31;
      *(f32x4*)&Bs[st][col] = *(const f32x4*)(src + (size_t)st * 80 + col);
    }
  }
  __syncthreads();

  const void* Alog = d ? Alog_ccw : Alog_cw;
  const void* Dp   = d ? D_ccw   : D_cw;
  float a[16];
  #pragma unroll
  for (int n = 0; n < 16; ++n) a[n] = -__expf(ldf(Alog, c * N_ + n, inbf));
  const float dvc = ldf(Dp, c, inbf);

  const size_t rbase = ((size_t)db * L_ + l0) * C_ + c;
  const ushort_t* dtp = dt + rbase;
  const ushort_t* ucp = uc + rbase;
  const ushort_t* zp  = z  + rbase;
  ushort_t* yp = y + rbase;

  size_t idx = (((size_t)db * NSEG_ + s) * C_ + c) * N_;
  float h[16];
  #pragma unroll
  for (int n = 0; n < 16; ++n) h[n] = bf2f(Q[idx + n]);

  #pragma unroll 2
  for (int l = 0; l < SEG_; ++l) {
    float dtv = bf2f(dtp[(size_t)l * C_]);
    float ucv = bf2f(ucp[(size_t)l * C_]);
    float zv  = bf2f(zp[(size_t)l * C_]);
    float dtu = dtv * ucv;
    f32x4 bq0 = *(const f32x4*)&Bs[l][0];
    f32x4 bq1 = *(const f32x4*)&Bs[l][4];
    f32x4 bq2 = *(const f32x4*)&Bs[l][8];
    f32x4 bq3 = *(const f32x4*)&Bs[l][12];
    f32x4 cq0 = *(const f32x4*)&Bs[l][16];
    f32x4 cq1 = *(const f32x4*)&Bs[l][20];
    f32x4 cq2 = *(const f32x4*)&Bs[l][24];
    f32x4 cq3 = *(const f32x4*)&Bs[l][28];
    float yv = dvc * ucv;
    #pragma unroll
    for (int j = 0; j < 4; ++j) { float dA = __expf(dtv*a[j]);    h[j]    = h[j]   *dA + dtu*bq0[j]; yv += h[j]   *cq0[j]; }
    #pragma unroll
    for (int j = 0; j < 4; ++j) { float dA = __expf(dtv*a[4+j]);  h[4+j]  = h[4+j] *dA + dtu*bq1[j]; yv += h[4+j] *cq1[j]; }
    #pragma unroll
    for (int j = 0; j < 4; ++j) { float dA = __expf(dtv*a[8+j]);  h[8+j]  = h[8+j] *dA + dtu*bq2[j]; yv += h[8+j] *cq2[j]; }
    #pragma unroll
    for (int j = 0; j < 4; ++j) { float dA = __expf(dtv*a[12+j]); h[12+j] = h[12+j]*dA + dtu*bq3[j]; yv += h[12+j]*cq3[j]; }
    yv *= zv / (1.f + __expf(-zv));   // * silu(z)
    yp[(size_t)l * C_] = f2bf(yv);
  }
}

// ---------------------------------------------------------------- launch
extern "C" void kernel_launch(void* const* d_in, const int* in_sizes, int n_in,
                              void* d_out, int out_size, void* d_ws, size_t ws_size,
                              hipStream_t stream)
{
  const void* x      = d_in[0];
  const void* norm_w = d_in[1];
  const void* norm_b = d_in[2];
  const void* in_w[2]    = { d_in[3],  d_in[12] };
  const void* conv_w[2]  = { d_in[4],  d_in[13] };
  const void* conv_b[2]  = { d_in[5],  d_in[14] };
  const void* xproj_w[2] = { d_in[6],  d_in[15] };
  const void* dtp_w[2]   = { d_in[7],  d_in[16] };
  const void* dtp_b[2]   = { d_in[8],  d_in[17] };
  const void* A_log[2]   = { d_in[9],  d_in[18] };
  const void* Dvec[2]    = { d_in[10], d_in[19] };
  const void* out_w[2]   = { d_in[11], d_in[20] };
  const void* fus_w1 = d_in[21];
  const void* fus_b1 = d_in[22];
  const void* fus_w2 = d_in[23];
  const void* fus_b2 = d_in[24];

  char* base = (char*)d_ws;
  int*      IDX  = (int*)base;
  int*      FLAG = (int*)(base + 8192);
  ushort_t* XN   = (ushort_t*)(base + 8448);
  ushort_t* U    = (ushort_t*)(base + 6299904);
  ushort_t* Z    = (ushort_t*)(base + 18882816);
  ushort_t* UC   = (ushort_t*)(base + 31465728);
  float*    DBL  = (float*)(base + 44048640);
  ushort_t* Y    = (ushort_t*)(base + 46670080);
  // lifetime aliases
  ushort_t* DT    = U;                                  // S5 out, scan in
  ushort_t* FUSED = Z;                                  // S7 out, S8 in
  ushort_t* HBUF  = XN;                                 // S8 out, S9 in
  ushort_t* SP = (ushort_t*)(base + 8448);              // scan only (bf16)
  ushort_t* SQ = SP + (size_t)2 * 4 * NSEG_ * C_ * N_;
  ushort_t* DTC = XN;                                   // S4 out2, S5 in
  ushort_t* INWT = UC;                                  // [2][1536][768], S2
  ushort_t* uout = (ushort_t*)d_out;
  ushort_t* XPJT = uout;                                // [2][128][768], S4
  ushort_t* DTPT = uout + 196608;                       // [2][768][64],  S5
  ushort_t* OWT  = uout + 294912;                       // [2][768][768], S7
  ushort_t* FW1T = U;                                   // [768][1536], S8
  ushort_t* FW2T = U + (size_t)768 * 1536;              // [768][768],  S9

  const size_t SD = (size_t)M_ * C_;

  hipLaunchKernelGGL(setup_k, dim3(1), dim3(64), 0, stream, x, IDX, IDX + L_, FLAG);

  // ---- batched transposes #1 (weights needed S2..S7)
  {
    TJ tj; tj.njobs = 8; int o = 0;
    for (int d = 0; d < 2; ++d) {
      int j = d;
      tj.src[j]=in_w[d]; tj.dst[j]=INWT+(size_t)d*1536*768;
      tj.R[j]=768; tj.Cc[j]=1536; tj.RD[j]=1536; tj.ldD[j]=768;
    }
    for (int d = 0; d < 2; ++d) {
      int j = 2+d;
      tj.src[j]=xproj_w[d]; tj.dst[j]=XPJT+(size_t)d*128*768;
      tj.R[j]=768; tj.Cc[j]=80; tj.RD[j]=128; tj.ldD[j]=768;
    }
    for (int d = 0; d < 2; ++d) {
      int j = 4+d;
      tj.src[j]=dtp_w[d]; tj.dst[j]=DTPT+(size_t)d*768*64;
      tj.R[j]=48; tj.Cc[j]=768; tj.RD[j]=768; tj.ldD[j]=64;
    }
    for (int d = 0; d < 2; ++d) {
      int j = 6+d;
      tj.src[j]=out_w[d]; tj.dst[j]=OWT+(size_t)d*768*768;
      tj.R[j]=768; tj.Cc[j]=768; tj.RD[j]=768; tj.ldD[j]=768;
    }
    tj.off[0] = 0;
    for (int j = 0; j < 8; ++j) {
      int cspan = tj.Cc[j] > tj.RD[j] ? tj.Cc[j] : tj.RD[j];
      int rspan = tj.R[j] > tj.ldD[j] ? tj.R[j] : tj.ldD[j];
      tj.off[j+1] = tj.off[j] + ((cspan+31)>>5) * ((rspan+31)>>5);
      o = tj.off[j+1];
    }
    hipLaunchKernelGGL(tbatch_k, dim3(o), dim3(256), 0, stream, tj, FLAG);
  }

  hipLaunchKernelGGL(layernorm_k, dim3(M_), dim3(256), 0, stream, x, norm_w, norm_b, XN, FLAG);

  GB gb;
  for (int i = 0; i < 4; ++i) { gb.out2[i] = nullptr; gb.omap[i] = nullptr; gb.amap[i] = nullptr; gb.bias[i] = nullptr; }

  // ---- S2: in_proj, z = (d, u/z half), BN=128, grid 6x32x4 -> 768
  for (int zz = 0; zz < 4; ++zz) {
    int d = zz >> 1, half = zz & 1;
    gb.A[zz] = XN; gb.amap[zz] = IDX + d * L_;
    gb.WT[zz] = INWT + (size_t)d*1536*768 + (size_t)half*768*768;
    gb.bias[zz] = nullptr;
    gb.out[zz] = (void*)((half ? Z : U) + d * SD); gb.out2[zz] = nullptr; gb.omap[zz] = nullptr;
  }
  hipLaunchKernelGGL(mgemm_k<128>, dim3(768), dim3(256), 0, stream,
      gb, C_, C_, C_, C_, C_, 0, 0, (const void*)nullptr, 0, 6, 4, FLAG);

  // ---- S3: conv + silu (both dirs, one dispatch)
  hipLaunchKernelGGL(conv_silu_k, dim3(2*M_*C_/256), dim3(256), 0, stream,
      U, conv_w[0], conv_w[1], conv_b[0], conv_b[1], UC, FLAG);

  // ---- S4: xproj -> DBL fp32 (+fused dtc), BN=64, Nn=80, grid 2x32x2 -> 128
  for (int zz = 0; zz < 2; ++zz) {
    gb.A[zz] = UC + zz * SD; gb.amap[zz] = nullptr;
    gb.WT[zz] = XPJT + (size_t)zz*128*768;
    gb.bias[zz] = nullptr;
    gb.out[zz] = (void*)(DBL + (size_t)zz * M_ * 80);
    gb.out2[zz] = DTC + (size_t)zz * M_ * 64;
    gb.omap[zz] = nullptr;
  }
  hipLaunchKernelGGL(mgemm_k<64>, dim3(128), dim3(256), 0, stream,
      gb, C_, C_, 80, C_, 80, 0, 1, (const void*)nullptr, 0, 2, 2, FLAG);

  // ---- S5: dt = softplus(dtc @ dtp_w + dtp_b), K=64, BN=64, grid 12x32x2 -> 768
  for (int zz = 0; zz < 2; ++zz) {
    gb.A[zz] = DTC + (size_t)zz * M_ * 64; gb.amap[zz] = nullptr;
    gb.WT[zz] = DTPT + (size_t)zz*768*64;
    gb.bias[zz] = dtp_b[zz];
    gb.out[zz] = (void*)(DT + zz * SD); gb.out2[zz] = nullptr; gb.omap[zz] = nullptr;
  }
  hipLaunchKernelGGL(mgemm_k<64>, dim3(768), dim3(256), 0, stream,
      gb, 64, 64, C_, 64, C_, 1, 0, (const void*)nullptr, 0, 12, 2, FLAG);

  // ---- S6: segmented selective scan
  hipLaunchKernelGGL(scan_pass1, dim3(3, NSEG_, 8), dim3(256), 0, stream,
      DT, UC, DBL, A_log[0], A_log[1], SP, SQ, FLAG);
  hipLaunchKernelGGL(scan_pass2, dim3(8 * C_ * N_ / 256), dim3(256), 0, stream, SP, SQ);
  hipLaunchKernelGGL(scan_pass3, dim3(3, NSEG_, 8), dim3(256), 0, stream,
      DT, UC, DBL, Z, A_log[0], A_log[1], Dvec[0], Dvec[1], SQ, Y, FLAG);

  // ---- batched transposes #2 (fus weights; U region free after scan)
  {
    TJ tj; tj.njobs = 2;
    tj.src[0]=fus_w1; tj.dst[0]=FW1T; tj.R[0]=1536; tj.Cc[0]=768; tj.RD[0]=768; tj.ldD[0]=1536;
    tj.src[1]=fus_w2; tj.dst[1]=FW2T; tj.R[1]=768;  tj.Cc[1]=768; tj.RD[1]=768; tj.ldD[1]=768;
    tj.off[0] = 0;
    for (int j = 0; j < 2; ++j) {
      int cspan = tj.Cc[j] > tj.RD[j] ? tj.Cc[j] : tj.RD[j];
      int rspan = tj.R[j] > tj.ldD[j] ? tj.R[j] : tj.ldD[j];
      tj.off[j+1] = tj.off[j] + ((cspan+31)>>5) * ((rspan+31)>>5);
    }
    hipLaunchKernelGGL(tbatch_k, dim3(tj.off[2]), dim3(256), 0, stream, tj, FLAG);
  }

  // ---- S7: out_proj with spiral-inverse scatter, BN=128, grid 6x32x2 -> 384
  for (int zz = 0; zz < 2; ++zz) {
    gb.A[zz] = Y + zz * SD; gb.amap[zz] = nullptr;
    gb.WT[zz] = OWT + (size_t)zz*768*768;
    gb.bias[zz] = nullptr;
    gb.out[zz] = (void*)(FUSED + zz * C_); gb.out2[zz] = nullptr; gb.omap[zz] = IDX + zz * L_;
  }
  hipLaunchKernelGGL(mgemm_k<128>, dim3(384), dim3(256), 0, stream,
      gb, C_, C_, C_, C_, 2*C_, 0, 0, (const void*)nullptr, 0, 6, 2, FLAG);

  // ---- S8: h = gelu(fused @ fus_w1 + fus_b1), K=1536, BN=64, grid 12x32x1 -> 384
  gb.A[0] = FUSED; gb.amap[0] = nullptr;
  gb.WT[0] = FW1T; gb.bias[0] = fus_b1;
  gb.out[0] = (void*)HBUF; gb.out2[0] = nullptr; gb.omap[0] = nullptr;
  hipLaunchKernelGGL(mgemm_k<64>, dim3(384), dim3(256), 0, stream,
      gb, 2*C_, 2*C_, C_, 2*C_, C_, 2, 0, (const void*)nullptr, 0, 12, 1, FLAG);

  // ---- S9: out = h @ fus_w2 + fus_b2 + x, BN=64, grid 12x32x1 -> 384
  gb.A[0] = HBUF; gb.amap[0] = nullptr;
  gb.WT[0] = FW2T; gb.bias[0] = fus_b2;
  gb.out[0] = d_out; gb.out2[0] = nullptr; gb.omap[0] = nullptr;
  hipLaunchKernelGGL(mgemm_k<64>, dim3(384), dim3(256), 0, stream,
      gb, C_, C_, C_, C_, C_, 0, 2, x, C_, 12, 1, FLAG);
}

// Round 10
// 468.651 us; speedup vs baseline: 3.7361x; 1.0854x over previous
//
#include <hip/hip_runtime.h>

typedef unsigned short ushort_t;
typedef __attribute__((ext_vector_type(8))) short short8;
typedef __attribute__((ext_vector_type(4))) float f32x4;

#define B_ 4
#define L_ 1024
#define C_ 768
#define N_ 16
#define DR_ 48
#define HW_ 32
#define M_ (B_*L_)   // 4096 rows
#define SEG_ 64      // scan segment length
#define NSEG_ 16     // L_/SEG_

// Workspace layout (byte offsets), total 59,252,992 B:
//   0        IDX   (2*1024 int)
//   8192     FLAG
//   8448     XN region: XN -> DTC -> {SP,SQ bf16} -> HBUF
//   6299904  U region: U -> DT -> {fus_w1^T, fus_w2^T}
//   18882816 Z region: Z -> FUSED
//   31465728 UC region: in_w^T -> UC
//   44048640 DBL 2*M*80 f32
//   46670080 Y 2*M*C u16
// d_out doubles as scratch for {xproj^T, dtp^T, out_w^T} until S7 (dead til S9).

__device__ __forceinline__ float bf2f(ushort_t u) {
  union { unsigned int i; float f; } v; v.i = ((unsigned int)u) << 16; return v.f;
}
__device__ __forceinline__ ushort_t f2bf(float f) {
  union { float f; unsigned int i; } v; v.f = f;
  unsigned int x = v.i;
  return (ushort_t)((x + 0x7fffu + ((x >> 16) & 1u)) >> 16);
}
__device__ __forceinline__ float ldf(const void* p, size_t i, int bf) {
  return bf ? bf2f(((const ushort_t*)p)[i]) : ((const float*)p)[i];
}
// async global->LDS, 16 B per lane; lds dest = wave-uniform base + lane*16
__device__ __forceinline__ void gload_lds16(const void* g, void* lds) {
  __builtin_amdgcn_global_load_lds(
      (const __attribute__((address_space(1))) unsigned int*)g,
      (__attribute__((address_space(3))) unsigned int*)lds, 16, 0, 0);
}

// ------------------------------------------------- spiral idx + dtype detect
__global__ void setup_k(const void* x, int* idx_cw, int* idx_ccw, int* flag) {
  int t = threadIdx.x;
  if (t == 0) {
    int top = 0, bottom = HW_-1, left = 0, right = HW_-1, p = 0;
    while (top <= bottom && left <= right) {
      for (int j = left; j <= right; j++) idx_cw[p++] = top*HW_ + j;
      top++;
      for (int i = top; i <= bottom; i++) idx_cw[p++] = i*HW_ + right;
      right--;
      if (top <= bottom) { for (int j = right; j >= left; j--) idx_cw[p++] = bottom*HW_ + j; bottom--; }
      if (left <= right) { for (int i = bottom; i >= top; i--) idx_cw[p++] = i*HW_ + left; left++; }
    }
  } else if (t == 1) {
    int top = 0, bottom = HW_-1, left = 0, right = HW_-1, p = 0;
    while (top <= bottom && left <= right) {
      for (int j = right; j >= left; j--) idx_ccw[p++] = top*HW_ + j;
      top++;
      for (int i = top; i <= bottom; i++) idx_ccw[p++] = i*HW_ + left;
      left++;
      if (top <= bottom) { for (int j = left; j <= right; j++) idx_ccw[p++] = bottom*HW_ + j; bottom--; }
      if (left <= right) { for (int i = bottom; i >= top; i--) idx_ccw[p++] = i*HW_ + right; right--; }
    }
  } else if (t == 2) {
    const ushort_t* u = (const ushort_t*)x;
    int bf = 1;
    for (int i = 0; i < 256; i++) {
      int e = (u[i] >> 7) & 0xFF;
      if (e < 90 || e > 141) { bf = 0; break; }
    }
    *flag = bf;
  }
}

// ---------------------------------------------------------------- layernorm
__global__ __launch_bounds__(256) void layernorm_k(
    const void* __restrict__ x, const void* __restrict__ w,
    const void* __restrict__ bb, ushort_t* __restrict__ xn,
    const int* __restrict__ flagp)
{
  const int inbf = *flagp;
  int row = blockIdx.x;
  int tid = threadIdx.x;
  size_t o0 = (size_t)row * C_;
  float v0 = ldf(x, o0 + tid,       inbf);
  float v1 = ldf(x, o0 + tid + 256, inbf);
  float v2 = ldf(x, o0 + tid + 512, inbf);
  float s = v0 + v1 + v2, s2 = v0*v0 + v1*v1 + v2*v2;
  for (int o = 32; o > 0; o >>= 1) { s += __shfl_down(s, o); s2 += __shfl_down(s2, o); }
  __shared__ float ss[4], ss2[4];
  if ((tid & 63) == 0) { ss[tid >> 6] = s; ss2[tid >> 6] = s2; }
  __syncthreads();
  s  = ss[0] + ss[1] + ss[2] + ss[3];
  s2 = ss2[0] + ss2[1] + ss2[2] + ss2[3];
  float mean = s * (1.f / C_);
  float var  = s2 * (1.f / C_) - mean * mean;
  float inv  = rsqrtf(var + 1e-6f);
  xn[o0 + tid]       = f2bf((v0 - mean) * inv * ldf(w, tid,     inbf) + ldf(bb, tid,     inbf));
  xn[o0 + tid + 256] = f2bf((v1 - mean) * inv * ldf(w, tid+256, inbf) + ldf(bb, tid+256, inbf));
  xn[o0 + tid + 512] = f2bf((v2 - mean) * inv * ldf(w, tid+512, inbf) + ldf(bb, tid+512, inbf));
}

// ---------------------------------------------------------------- batched transpose
struct TJ {
  const void* src[8]; ushort_t* dst[8];
  int R[8], Cc[8], RD[8], ldD[8];
  int off[9]; int njobs;
};

__global__ __launch_bounds__(256) void tbatch_k(TJ tj, const int* __restrict__ flagp) {
  const int inbf = *flagp;
  int bid = blockIdx.x;
  int j = 0;
  while (bid >= tj.off[j+1]) ++j;
  const void* src = tj.src[j];
  ushort_t* dst = tj.dst[j];
  const int R = tj.R[j], Cc = tj.Cc[j], RD = tj.RD[j], ldD = tj.ldD[j];
  int cb_span = (Cc > RD ? Cc : RD);
  int txt = (cb_span + 31) >> 5;
  int t = bid - tj.off[j];
  int bx = (t % txt) * 32;             // src col / dst row
  int by = (t / txt) * 32;             // src row / dst col
  __shared__ ushort_t tile[32][33];
  int tx = threadIdx.x & 31, ty = threadIdx.x >> 5;
  #pragma unroll
  for (int i = 0; i < 4; ++i) {
    int r = by + ty + i*8, c = bx + tx;
    ushort_t v = 0;
    if (r < R && c < Cc) v = f2bf(ldf(src, (size_t)r * Cc + c, inbf));
    tile[ty + i*8][tx] = v;
  }
  __syncthreads();
  #pragma unroll
  for (int i = 0; i < 4; ++i) {
    int dr = bx + ty + i*8, dc = by + tx;
    if (dr < RD && dc < ldD)
      dst[(size_t)dr * ldD + dc] = tile[tx][ty + i*8];
  }
}

// ---------------------------------------------------------------- MFMA GEMM
// Out[M, Nn] = act(A[M,K] @ WT[N,K]^T + bias) (+resid). Tile BM x BN x BK64,
// 256 thr / 4 waves. BM=128: waves 2x2 (wave 64m x BN/2). BM=64: waves 1x4
// (wave 64m x BN/4). Staging: global_load_lds w=16, LDS [row][k] 128 B rows,
// XOR chunk swizzle c' = c ^ (r&7) (measured 0 conflicts, round 6).
struct GB {
  const ushort_t* A[4]; const int* amap[4];
  const ushort_t* WT[4];
  const void* bias[4];
  void* out[4]; ushort_t* out2[4]; const int* omap[4];
};

template<int BM, int BN>
__global__ __launch_bounds__(256) void mgemm_k(
    GB gb, int lda, int ldb, int Nn, int K, int ldo,
    int act, int out_mode, const void* resid, int ldr, const int* __restrict__ flagp)
{
  constexpr int NA = BM / 32;          // A staging chunks per thread
  constexpr int NB = BN / 32;          // B staging chunks per thread
  constexpr int WN = (BM == 128) ? 2 : 4;   // waves along n
  constexpr int NSPAN = BN / WN;       // n-span per wave
  constexpr int FN = NSPAN / 16;       // n-frags per wave
  const int inbf = *flagp;
  const int z = blockIdx.z;

  const ushort_t* A  = gb.A[z];
  const int* amap    = gb.amap[z];
  const ushort_t* Bw = gb.WT[z];
  const void* bias   = gb.bias[z];
  void* Out          = gb.out[z];
  ushort_t* out2     = gb.out2[z];
  const int* omap    = gb.omap[z];

  __shared__ __align__(16) ushort_t As[BM * 64];
  __shared__ __align__(16) ushort_t Bs[BN * 64];

  const int tid  = threadIdx.x;
  const int w    = tid >> 6;
  const int lane = tid & 63;
  const int quad = lane >> 4;
  const int l15  = lane & 15;
  const int wm     = (BM == 128) ? (w >> 1) * 64 : 0;       // wave m offset
  const int wn_off = ((BM == 128) ? (w & 1) : w) * NSPAN;   // wave n offset
  const int row0 = blockIdx.y * BM;
  const int col0 = blockIdx.x * BN;

  int agb[NA], bgb[NB], aldso[NA], bldso[NB];
  #pragma unroll
  for (int i = 0; i < NA; ++i) {
    int t = i*256 + tid;                // chunk id
    int r = t >> 3;
    int c = (t & 7) ^ (r & 7);          // swizzle involution
    int grow = row0 + r;
    if (amap) { int b = grow >> 10, l = grow & 1023; grow = (b << 10) + amap[l]; }
    agb[i] = grow * lda + c * 8;
    aldso[i] = (i*256 + w*64) * 16;
  }
  #pragma unroll
  for (int i = 0; i < NB; ++i) {
    int t = i*256 + tid;
    int r = t >> 3;
    int c = (t & 7) ^ (r & 7);
    bgb[i] = (col0 + r) * ldb + c * 8;
    bldso[i] = (i*256 + w*64) * 16;
  }

  f32x4 acc[4][FN];
  #pragma unroll
  for (int mi = 0; mi < 4; ++mi)
    #pragma unroll
    for (int ni = 0; ni < FN; ++ni)
      acc[mi][ni] = (f32x4){0.f, 0.f, 0.f, 0.f};

  const int sw = l15 & 7;

  for (int k0 = 0; k0 < K; k0 += 64) {
    #pragma unroll
    for (int i = 0; i < NA; ++i)
      gload_lds16(A + agb[i] + k0, (char*)As + aldso[i]);
    #pragma unroll
    for (int i = 0; i < NB; ++i)
      gload_lds16(Bw + bgb[i] + k0, (char*)Bs + bldso[i]);
    __syncthreads();

    #pragma unroll
    for (int ks = 0; ks < 2; ++ks) {
      short8 aF[4], bF[FN];
      #pragma unroll
      for (int mi = 0; mi < 4; ++mi)
        aF[mi] = *(const short8*)&As[(wm + mi*16 + l15) * 64 + (((quad + 4*ks) ^ sw) * 8)];
      #pragma unroll
      for (int ni = 0; ni < FN; ++ni)
        bF[ni] = *(const short8*)&Bs[(wn_off + ni*16 + l15) * 64 + (((quad + 4*ks) ^ sw) * 8)];
      #pragma unroll
      for (int mi = 0; mi < 4; ++mi)
        #pragma unroll
        for (int ni = 0; ni < FN; ++ni)
          acc[mi][ni] = __builtin_amdgcn_mfma_f32_16x16x32_bf16(aF[mi], bF[ni], acc[mi][ni], 0, 0, 0);
    }
    __syncthreads();
  }

  const int obf = (out_mode == 2) ? inbf : (out_mode == 0);
  #pragma unroll
  for (int ni = 0; ni < FN; ++ni) {
    int colg = col0 + wn_off + ni*16 + l15;
    if (colg >= Nn) continue;
    float bv = bias ? ldf(bias, colg, inbf) : 0.f;
    #pragma unroll
    for (int mi = 0; mi < 4; ++mi) {
      #pragma unroll
      for (int r = 0; r < 4; ++r) {
        int rowg = row0 + wm + mi*16 + quad*4 + r;
        int orow = rowg;
        if (omap) { int b = rowg >> 10, l = rowg & 1023; orow = (b << 10) + omap[l]; }
        float v = acc[mi][ni][r] + bv;
        if (out2 && colg < 64)
          out2[(size_t)orow * 64 + colg] = f2bf(colg < DR_ ? v : 0.f);
        if (act == 1)      v = (v > 20.f) ? v : log1pf(__expf(v));                  // softplus
        else if (act == 2) v = 0.5f * v * (1.f + erff(v * 0.70710678118654752f));   // gelu
        if (resid) v += ldf(resid, (size_t)orow * ldr + colg, inbf);
        size_t oi = (size_t)orow * ldo + colg;
        if (obf) ((ushort_t*)Out)[oi] = f2bf(v);
        else     ((float*)Out)[oi]    = v;
      }
    }
  }
}

// ---------------------------------------------------------------- conv(K=4)+silu
__global__ __launch_bounds__(256) void conv_silu_k(
    const ushort_t* __restrict__ u,
    const void* __restrict__ cw0, const void* __restrict__ cw1,
    const void* __restrict__ cb0, const void* __restrict__ cb1,
    ushort_t* __restrict__ uc, const int* __restrict__ flagp)
{
  const int inbf = *flagp;
  int g = blockIdx.x * 256 + threadIdx.x;
  int c = g % C_;
  int row = g / C_;
  int l = row & 1023;
  const void* cw = (row >> 12) ? cw1 : cw0;
  const void* cb = (row >> 12) ? cb1 : cb0;
  float w0 = ldf(cw, c*4+0, inbf), w1 = ldf(cw, c*4+1, inbf);
  float w2 = ldf(cw, c*4+2, inbf), w3 = ldf(cw, c*4+3, inbf);
  const ushort_t* up = u + (size_t)(row - l) * C_ + c;
  float s = ldf(cb, c, inbf);
  if (l >= 3) s += w0 * bf2f(up[(size_t)(l-3) * C_]);
  if (l >= 2) s += w1 * bf2f(up[(size_t)(l-2) * C_]);
  if (l >= 1) s += w2 * bf2f(up[(size_t)(l-1) * C_]);
  s += w3 * bf2f(up[(size_t)l * C_]);
  s = s / (1.f + __expf(-s));
  uc[g] = f2bf(s);
}

// ---------------------------------------------------------------- segmented scan
__global__ __launch_bounds__(256) void scan_pass1(
    const ushort_t* __restrict__ dt, const ushort_t* __restrict__ uc,
    const float* __restrict__ dbl,
    const void* __restrict__ Alog_cw, const void* __restrict__ Alog_ccw,
    ushort_t* __restrict__ P, ushort_t* __restrict__ Q,
    const int* __restrict__ flagp)
{
  const int inbf = *flagp;
  const int db = blockIdx.z, d = db >> 2;
  const int s = blockIdx.y;
  const int tid = threadIdx.x;
  const int c = blockIdx.x * 256 + tid;
  const int l0 = s * SEG_;

  __shared__ __align__(16) float Bs[SEG_][32];
  {
    const float* src = dbl + ((size_t)db * L_ + l0) * 80 + DR_;
    #pragma unroll
    for (int i = 0; i < 2; ++i) {
      int idx = tid * 4 + i * 1024;
      int st = idx >> 5, col = idx & 31;
      *(f32x4*)&Bs[st][col] = *(const f32x4*)(src + (size_t)st * 80 + col);
    }
  }
  __syncthreads();

  const void* Alog = d ? Alog_ccw : Alog_cw;
  float a[16];
  #pragma unroll
  for (int n = 0; n < 16; ++n) a[n] = -__expf(ldf(Alog, c * N_ + n, inbf));

  const size_t rbase = ((size_t)db * L_ + l0) * C_ + c;
  const ushort_t* dtp = dt + rbase;
  const ushort_t* ucp = uc + rbase;

  float h[16];
  #pragma unroll
  for (int n = 0; n < 16; ++n) h[n] = 0.f;
  float S = 0.f;

  #pragma unroll 4
  for (int l = 0; l < SEG_; ++l) {
    float dtv = bf2f(dtp[(size_t)l * C_]);
    float ucv = bf2f(ucp[(size_t)l * C_]);
    float dtu = dtv * ucv;
    S += dtv;
    f32x4 bq0 = *(const f32x4*)&Bs[l][0];
    f32x4 bq1 = *(const f32x4*)&Bs[l][4];
    f32x4 bq2 = *(const f32x4*)&Bs[l][8];
    f32x4 bq3 = *(const f32x4*)&Bs[l][12];
    #pragma unroll
    for (int j = 0; j < 4; ++j) { float dA = __expf(dtv*a[j]);    h[j]    = h[j]   *dA + dtu*bq0[j]; }
    #pragma unroll
    for (int j = 0; j < 4; ++j) { float dA = __expf(dtv*a[4+j]);  h[4+j]  = h[4+j] *dA + dtu*bq1[j]; }
    #pragma unroll
    for (int j = 0; j < 4; ++j) { float dA = __expf(dtv*a[8+j]);  h[8+j]  = h[8+j] *dA + dtu*bq2[j]; }
    #pragma unroll
    for (int j = 0; j < 4; ++j) { float dA = __expf(dtv*a[12+j]); h[12+j] = h[12+j]*dA + dtu*bq3[j]; }
  }
  size_t idx = (((size_t)db * NSEG_ + s) * C_ + c) * N_;
  #pragma unroll
  for (int n = 0; n < 16; ++n) {
    P[idx + n] = f2bf(__expf(a[n] * S));
    Q[idx + n] = f2bf(h[n]);
  }
}

__global__ __launch_bounds__(256) void scan_pass2(
    ushort_t* __restrict__ P, ushort_t* __restrict__ Q)
{
  size_t g = (size_t)blockIdx.x * 256 + threadIdx.x;
  size_t db = g / (C_ * N_);
  size_t cn = g % (C_ * N_);
  float h = 0.f;
  #pragma unroll
  for (int s = 0; s < NSEG_; ++s) {
    size_t off = (db * NSEG_ + s) * (C_ * N_) + cn;
    float p = bf2f(P[off]), q = bf2f(Q[off]);
    Q[off] = f2bf(h);
    h = h * p + q;
  }
}

__global__ __launch_bounds__(256) void scan_pass3(
    const ushort_t* __restrict__ dt, const ushort_t* __restrict__ uc,
    const float* __restrict__ dbl, const ushort_t* __restrict__ z,
    const void* __restrict__ Alog_cw, const void* __restrict__ Alog_ccw,
    const void* __restrict__ D_cw, const void* __restrict__ D_ccw,
    const ushort_t* __restrict__ Q, ushort_t* __restrict__ y,
    const int* __restrict__ flagp)
{
  const int inbf = *flagp;
  const int db = blockIdx.z, d = db >> 2;
  const int s = blockIdx.y;
  const int tid = threadIdx.x;
  const int c = blockIdx.x * 256 + tid;
  const int l0 = s * SEG_;

  __shared__ __align__(16) float Bs[SEG_][32];   // cols 0..15 = B, 16..31 = C
  {
    const float* src = dbl + ((size_t)db * L_ + l0) * 80 + DR_;
    #pragma unroll
    for (int i = 0; i < 2; ++i) {
      int idx = tid * 4 + i * 1024;
      int st = idx >> 5, col = idx & 31;
      *(f32x4*)&Bs[st][col] = *(const f32x4*)(src + (size_t)st * 80 + col);
    }
  }
  __syncthreads();

  const void* Alog = d ? Alog_ccw : Alog_cw;
  const void* Dp   = d ? D_ccw   : D_cw;
  float a[16];
  #pragma unroll
  for (int n = 0; n < 16; ++n) a[n] = -__expf(ldf(Alog, c * N_ + n, inbf));
  const float dvc = ldf(Dp, c, inbf);

  const size_t rbase = ((size_t)db * L_ + l0) * C_ + c;
  const ushort_t* dtp = dt + rbase;
  const ushort_t* ucp = uc + rbase;
  const ushort_t* zp  = z  + rbase;
  ushort_t* yp = y + rbase;

  size_t idx = (((size_t)db * NSEG_ + s) * C_ + c) * N_;
  float h[16];
  #pragma unroll
  for (int n = 0; n < 16; ++n) h[n] = bf2f(Q[idx + n]);

  #pragma unroll 2
  for (int l = 0; l < SEG_; ++l) {
    float dtv = bf2f(dtp[(size_t)l * C_]);
    float ucv = bf2f(ucp[(size_t)l * C_]);
    float zv  = bf2f(zp[(size_t)l * C_]);
    float dtu = dtv * ucv;
    f32x4 bq0 = *(const f32x4*)&Bs[l][0];
    f32x4 bq1 = *(const f32x4*)&Bs[l][4];
    f32x4 bq2 = *(const f32x4*)&Bs[l][8];
    f32x4 bq3 = *(const f32x4*)&Bs[l][12];
    f32x4 cq0 = *(const f32x4*)&Bs[l][16];
    f32x4 cq1 = *(const f32x4*)&Bs[l][20];
    f32x4 cq2 = *(const f32x4*)&Bs[l][24];
    f32x4 cq3 = *(const f32x4*)&Bs[l][28];
    float yv = dvc * ucv;
    #pragma unroll
    for (int j = 0; j < 4; ++j) { float dA = __expf(dtv*a[j]);    h[j]    = h[j]   *dA + dtu*bq0[j]; yv += h[j]   *cq0[j]; }
    #pragma unroll
    for (int j = 0; j < 4; ++j) { float dA = __expf(dtv*a[4+j]);  h[4+j]  = h[4+j] *dA + dtu*bq1[j]; yv += h[4+j] *cq1[j]; }
    #pragma unroll
    for (int j = 0; j < 4; ++j) { float dA = __expf(dtv*a[8+j]);  h[8+j]  = h[8+j] *dA + dtu*bq2[j]; yv += h[8+j] *cq2[j]; }
    #pragma unroll
    for (int j = 0; j < 4; ++j) { float dA = __expf(dtv*a[12+j]); h[12+j] = h[12+j]*dA + dtu*bq3[j]; yv += h[12+j]*cq3[j]; }
    yv *= zv / (1.f + __expf(-zv));   // * silu(z)
    yp[(size_t)l * C_] = f2bf(yv);
  }
}

// ---------------------------------------------------------------- launch
extern "C" void kernel_launch(void* const* d_in, const int* in_sizes, int n_in,
                              void* d_out, int out_size, void* d_ws, size_t ws_size,
                              hipStream_t stream)
{
  const void* x      = d_in[0];
  const void* norm_w = d_in[1];
  const void* norm_b = d_in[2];
  const void* in_w[2]    = { d_in[3],  d_in[12] };
  const void* conv_w[2]  = { d_in[4],  d_in[13] };
  const void* conv_b[2]  = { d_in[5],  d_in[14] };
  const void* xproj_w[2] = { d_in[6],  d_in[15] };
  const void* dtp_w[2]   = { d_in[7],  d_in[16] };
  const void* dtp_b[2]   = { d_in[8],  d_in[17] };
  const void* A_log[2]   = { d_in[9],  d_in[18] };
  const void* Dvec[2]    = { d_in[10], d_in[19] };
  const void* out_w[2]   = { d_in[11], d_in[20] };
  const void* fus_w1 = d_in[21];
  const void* fus_b1 = d_in[22];
  const void* fus_w2 = d_in[23];
  const void* fus_b2 = d_in[24];

  char* base = (char*)d_ws;
  int*      IDX  = (int*)base;
  int*      FLAG = (int*)(base + 8192);
  ushort_t* XN   = (ushort_t*)(base + 8448);
  ushort_t* U    = (ushort_t*)(base + 6299904);
  ushort_t* Z    = (ushort_t*)(base + 18882816);
  ushort_t* UC   = (ushort_t*)(base + 31465728);
  float*    DBL  = (float*)(base + 44048640);
  ushort_t* Y    = (ushort_t*)(base + 46670080);
  // lifetime aliases
  ushort_t* DT    = U;                                  // S5 out, scan in
  ushort_t* FUSED = Z;                                  // S7 out, S8 in
  ushort_t* HBUF  = XN;                                 // S8 out, S9 in
  ushort_t* SP = (ushort_t*)(base + 8448);              // scan only (bf16)
  ushort_t* SQ = SP + (size_t)2 * 4 * NSEG_ * C_ * N_;
  ushort_t* DTC = XN;                                   // S4 out2, S5 in
  ushort_t* INWT = UC;                                  // [2][1536][768], S2
  ushort_t* uout = (ushort_t*)d_out;
  ushort_t* XPJT = uout;                                // [2][128][768], S4
  ushort_t* DTPT = uout + 196608;                       // [2][768][64],  S5
  ushort_t* OWT  = uout + 294912;                       // [2][768][768], S7
  ushort_t* FW1T = U;                                   // [768][1536], S8
  ushort_t* FW2T = U + (size_t)768 * 1536;              // [768][768],  S9

  const size_t SD = (size_t)M_ * C_;

  hipLaunchKernelGGL(setup_k, dim3(1), dim3(64), 0, stream, x, IDX, IDX + L_, FLAG);

  // ---- batched transposes #1 (weights needed S2..S7)
  {
    TJ tj; tj.njobs = 8; int o = 0;
    for (int d = 0; d < 2; ++d) {
      int j = d;
      tj.src[j]=in_w[d]; tj.dst[j]=INWT+(size_t)d*1536*768;
      tj.R[j]=768; tj.Cc[j]=1536; tj.RD[j]=1536; tj.ldD[j]=768;
    }
    for (int d = 0; d < 2; ++d) {
      int j = 2+d;
      tj.src[j]=xproj_w[d]; tj.dst[j]=XPJT+(size_t)d*128*768;
      tj.R[j]=768; tj.Cc[j]=80; tj.RD[j]=128; tj.ldD[j]=768;
    }
    for (int d = 0; d < 2; ++d) {
      int j = 4+d;
      tj.src[j]=dtp_w[d]; tj.dst[j]=DTPT+(size_t)d*768*64;
      tj.R[j]=48; tj.Cc[j]=768; tj.RD[j]=768; tj.ldD[j]=64;
    }
    for (int d = 0; d < 2; ++d) {
      int j = 6+d;
      tj.src[j]=out_w[d]; tj.dst[j]=OWT+(size_t)d*768*768;
      tj.R[j]=768; tj.Cc[j]=768; tj.RD[j]=768; tj.ldD[j]=768;
    }
    tj.off[0] = 0;
    for (int j = 0; j < 8; ++j) {
      int cspan = tj.Cc[j] > tj.RD[j] ? tj.Cc[j] : tj.RD[j];
      int rspan = tj.R[j] > tj.ldD[j] ? tj.R[j] : tj.ldD[j];
      tj.off[j+1] = tj.off[j] + ((cspan+31)>>5) * ((rspan+31)>>5);
      o = tj.off[j+1];
    }
    hipLaunchKernelGGL(tbatch_k, dim3(o), dim3(256), 0, stream, tj, FLAG);
  }

  hipLaunchKernelGGL(layernorm_k, dim3(M_), dim3(256), 0, stream, x, norm_w, norm_b, XN, FLAG);

  GB gb;
  for (int i = 0; i < 4; ++i) { gb.out2[i] = nullptr; gb.omap[i] = nullptr; gb.amap[i] = nullptr; gb.bias[i] = nullptr; }

  // ---- S2: in_proj, z = (d, u/z half), BM=64 BN=128, grid 6x64x4 = 1536
  for (int zz = 0; zz < 4; ++zz) {
    int d = zz >> 1, half = zz & 1;
    gb.A[zz] = XN; gb.amap[zz] = IDX + d * L_;
    gb.WT[zz] = INWT + (size_t)d*1536*768 + (size_t)half*768*768;
    gb.bias[zz] = nullptr;
    gb.out[zz] = (void*)((half ? Z : U) + d * SD); gb.out2[zz] = nullptr; gb.omap[zz] = nullptr;
  }
  hipLaunchKernelGGL((mgemm_k<64,128>), dim3(6, 64, 4), dim3(256), 0, stream,
      gb, C_, C_, C_, C_, C_, 0, 0, (const void*)nullptr, 0, FLAG);

  // ---- S3: conv + silu (both dirs, one dispatch)
  hipLaunchKernelGGL(conv_silu_k, dim3(2*M_*C_/256), dim3(256), 0, stream,
      U, conv_w[0], conv_w[1], conv_b[0], conv_b[1], UC, FLAG);

  // ---- S4: xproj -> DBL fp32 (+fused dtc), BM=64 BN=128, Nn=80, grid 1x64x2
  for (int zz = 0; zz < 2; ++zz) {
    gb.A[zz] = UC + zz * SD; gb.amap[zz] = nullptr;
    gb.WT[zz] = XPJT + (size_t)zz*128*768;
    gb.bias[zz] = nullptr;
    gb.out[zz] = (void*)(DBL + (size_t)zz * M_ * 80);
    gb.out2[zz] = DTC + (size_t)zz * M_ * 64;
    gb.omap[zz] = nullptr;
  }
  hipLaunchKernelGGL((mgemm_k<64,128>), dim3(1, 64, 2), dim3(256), 0, stream,
      gb, C_, C_, 80, C_, 80, 0, 1, (const void*)nullptr, 0, FLAG);

  // ---- S5: dt = softplus(dtc @ dtp_w + dtp_b), K=64, BM=64 BN=64, grid 12x64x2
  for (int zz = 0; zz < 2; ++zz) {
    gb.A[zz] = DTC + (size_t)zz * M_ * 64; gb.amap[zz] = nullptr;
    gb.WT[zz] = DTPT + (size_t)zz*768*64;
    gb.bias[zz] = dtp_b[zz];
    gb.out[zz] = (void*)(DT + zz * SD); gb.out2[zz] = nullptr; gb.omap[zz] = nullptr;
  }
  hipLaunchKernelGGL((mgemm_k<64,64>), dim3(12, 64, 2), dim3(256), 0, stream,
      gb, 64, 64, C_, 64, C_, 1, 0, (const void*)nullptr, 0, FLAG);

  // ---- S6: segmented selective scan
  hipLaunchKernelGGL(scan_pass1, dim3(3, NSEG_, 8), dim3(256), 0, stream,
      DT, UC, DBL, A_log[0], A_log[1], SP, SQ, FLAG);
  hipLaunchKernelGGL(scan_pass2, dim3(8 * C_ * N_ / 256), dim3(256), 0, stream, SP, SQ);
  hipLaunchKernelGGL(scan_pass3, dim3(3, NSEG_, 8), dim3(256), 0, stream,
      DT, UC, DBL, Z, A_log[0], A_log[1], Dvec[0], Dvec[1], SQ, Y, FLAG);

  // ---- batched transposes #2 (fus weights; U region free after scan)
  {
    TJ tj; tj.njobs = 2;
    tj.src[0]=fus_w1; tj.dst[0]=FW1T; tj.R[0]=1536; tj.Cc[0]=768; tj.RD[0]=768; tj.ldD[0]=1536;
    tj.src[1]=fus_w2; tj.dst[1]=FW2T; tj.R[1]=768;  tj.Cc[1]=768; tj.RD[1]=768; tj.ldD[1]=768;
    tj.off[0] = 0;
    for (int j = 0; j < 2; ++j) {
      int cspan = tj.Cc[j] > tj.RD[j] ? tj.Cc[j] : tj.RD[j];
      int rspan = tj.R[j] > tj.ldD[j] ? tj.R[j] : tj.ldD[j];
      tj.off[j+1] = tj.off[j] + ((cspan+31)>>5) * ((rspan+31)>>5);
    }
    hipLaunchKernelGGL(tbatch_k, dim3(tj.off[2]), dim3(256), 0, stream, tj, FLAG);
  }

  // ---- S7: out_proj with spiral-inverse scatter, BM=64 BN=128, grid 6x64x2
  for (int zz = 0; zz < 2; ++zz) {
    gb.A[zz] = Y + zz * SD; gb.amap[zz] = nullptr;
    gb.WT[zz] = OWT + (size_t)zz*768*768;
    gb.bias[zz] = nullptr;
    gb.out[zz] = (void*)(FUSED + zz * C_); gb.out2[zz] = nullptr; gb.omap[zz] = IDX + zz * L_;
  }
  hipLaunchKernelGGL((mgemm_k<64,128>), dim3(6, 64, 2), dim3(256), 0, stream,
      gb, C_, C_, C_, C_, 2*C_, 0, 0, (const void*)nullptr, 0, FLAG);

  // ---- S8: h = gelu(fused @ fus_w1 + fus_b1), K=1536, BM=64 BN=64, grid 12x64x1
  gb.A[0] = FUSED; gb.amap[0] = nullptr;
  gb.WT[0] = FW1T; gb.bias[0] = fus_b1;
  gb.out[0] = (void*)HBUF; gb.out2[0] = nullptr; gb.omap[0] = nullptr;
  hipLaunchKernelGGL((mgemm_k<64,64>), dim3(12, 64, 1), dim3(256), 0, stream,
      gb, 2*C_, 2*C_, C_, 2*C_, C_, 2, 0, (const void*)nullptr, 0, FLAG);

  // ---- S9: out = h @ fus_w2 + fus_b2 + x, BM=64 BN=64, grid 12x64x1
  gb.A[0] = HBUF; gb.amap[0] = nullptr;
  gb.WT[0] = FW2T; gb.bias[0] = fus_b2;
  gb.out[0] = d_out; gb.out2[0] = nullptr; gb.omap[0] = nullptr;
  hipLaunchKernelGGL((mgemm_k<64,64>), dim3(12, 64, 1), dim3(256), 0, stream,
      gb, C_, C_, C_, C_, C_, 0, 2, x, C_, FLAG);
}

// Round 11
// 446.109 us; speedup vs baseline: 3.9249x; 1.0505x over previous
//
#include <hip/hip_runtime.h>

typedef unsigned short ushort_t;
typedef __attribute__((ext_vector_type(8))) short short8;
typedef __attribute__((ext_vector_type(4))) float f32x4;

#define B_ 4
#define L_ 1024
#define C_ 768
#define N_ 16
#define DR_ 48
#define HW_ 32
#define M_ (B_*L_)   // 4096 rows
#define SEG_ 64      // scan segment length
#define NSEG_ 16     // L_/SEG_

// Workspace layout (byte offsets), total 59,252,992 B:
//   0        IDX   (2*1024 int)
//   8192     FLAG
//   8448     XN region: XN -> DTC -> {SP,SQ bf16} -> HBUF
//   6299904  U region: U -> DT -> {fus_w1^T, fus_w2^T}
//   18882816 Z region: Z -> FUSED
//   31465728 UC region: in_w^T -> UC
//   44048640 DBL 2*M*80 f32
//   46670080 Y 2*M*C u16
// d_out doubles as scratch for {xproj^T, dtp^T, out_w^T} until S7 (dead til S9).

__device__ __forceinline__ float bf2f(ushort_t u) {
  union { unsigned int i; float f; } v; v.i = ((unsigned int)u) << 16; return v.f;
}
__device__ __forceinline__ ushort_t f2bf(float f) {
  union { float f; unsigned int i; } v; v.f = f;
  unsigned int x = v.i;
  return (ushort_t)((x + 0x7fffu + ((x >> 16) & 1u)) >> 16);
}
__device__ __forceinline__ float ldf(const void* p, size_t i, int bf) {
  return bf ? bf2f(((const ushort_t*)p)[i]) : ((const float*)p)[i];
}
// bf16-vs-fp32 detect on x's first 256 words (L2-hot; used inside prep_k to
// avoid a FLAG dependency within the merged dispatch)
__device__ __forceinline__ int detect_bf(const void* x) {
  const ushort_t* u = (const ushort_t*)x;
  int bf = 1;
  for (int i = 0; i < 256; i++) {
    int e = (u[i] >> 7) & 0xFF;
    if (e < 90 || e > 141) { bf = 0; break; }
  }
  return bf;
}
// async global->LDS, 16 B per lane; lds dest = wave-uniform base + lane*16
__device__ __forceinline__ void gload_lds16(const void* g, void* lds) {
  __builtin_amdgcn_global_load_lds(
      (const __attribute__((address_space(1))) unsigned int*)g,
      (__attribute__((address_space(3))) unsigned int*)lds, 16, 0, 0);
}

// ---------------------------------------------------------------- prep kernel
// One dispatch: blocks [0,oT) weight transposes, [oT,oT+4096) layernorm rows,
// block oT+4096 spiral-idx + FLAG write. All independent.
struct TJ {
  const void* src[8]; ushort_t* dst[8];
  int R[8], Cc[8], RD[8], ldD[8];
  int off[9]; int njobs;
};

__global__ __launch_bounds__(256) void prep_k(
    TJ tj, const void* __restrict__ x, const void* __restrict__ nw,
    const void* __restrict__ nb, ushort_t* __restrict__ xn,
    int* idx_cw, int* idx_ccw, int* flag)
{
  const int oT = tj.off[tj.njobs];
  int bid = blockIdx.x;

  if (bid < oT) {                       // ---- transpose job
    const int inbf = detect_bf(x);
    int j = 0;
    while (bid >= tj.off[j+1]) ++j;
    const void* src = tj.src[j];
    ushort_t* dst = tj.dst[j];
    const int R = tj.R[j], Cc = tj.Cc[j], RD = tj.RD[j], ldD = tj.ldD[j];
    int cb_span = (Cc > RD ? Cc : RD);
    int txt = (cb_span + 31) >> 5;
    int t = bid - tj.off[j];
    int bx = (t % txt) * 32;
    int by = (t / txt) * 32;
    __shared__ ushort_t tile[32][33];
    int tx = threadIdx.x & 31, ty = threadIdx.x >> 5;
    #pragma unroll
    for (int i = 0; i < 4; ++i) {
      int r = by + ty + i*8, c = bx + tx;
      ushort_t v = 0;
      if (r < R && c < Cc) v = f2bf(ldf(src, (size_t)r * Cc + c, inbf));
      tile[ty + i*8][tx] = v;
    }
    __syncthreads();
    #pragma unroll
    for (int i = 0; i < 4; ++i) {
      int dr = bx + ty + i*8, dc = by + tx;
      if (dr < RD && dc < ldD)
        dst[(size_t)dr * ldD + dc] = tile[tx][ty + i*8];
    }
    return;
  }
  bid -= oT;
  if (bid < M_) {                       // ---- layernorm row
    const int inbf = detect_bf(x);
    int tid = threadIdx.x;
    size_t o0 = (size_t)bid * C_;
    float v0 = ldf(x, o0 + tid,       inbf);
    float v1 = ldf(x, o0 + tid + 256, inbf);
    float v2 = ldf(x, o0 + tid + 512, inbf);
    float s = v0 + v1 + v2, s2 = v0*v0 + v1*v1 + v2*v2;
    for (int o = 32; o > 0; o >>= 1) { s += __shfl_down(s, o); s2 += __shfl_down(s2, o); }
    __shared__ float ss[4], ss2[4];
    if ((tid & 63) == 0) { ss[tid >> 6] = s; ss2[tid >> 6] = s2; }
    __syncthreads();
    s  = ss[0] + ss[1] + ss[2] + ss[3];
    s2 = ss2[0] + ss2[1] + ss2[2] + ss2[3];
    float mean = s * (1.f / C_);
    float var  = s2 * (1.f / C_) - mean * mean;
    float inv  = rsqrtf(var + 1e-6f);
    xn[o0 + tid]       = f2bf((v0 - mean) * inv * ldf(nw, tid,     inbf) + ldf(nb, tid,     inbf));
    xn[o0 + tid + 256] = f2bf((v1 - mean) * inv * ldf(nw, tid+256, inbf) + ldf(nb, tid+256, inbf));
    xn[o0 + tid + 512] = f2bf((v2 - mean) * inv * ldf(nw, tid+512, inbf) + ldf(nb, tid+512, inbf));
    return;
  }
  // ---- setup block
  int t = threadIdx.x;
  if (t == 0) {
    int top = 0, bottom = HW_-1, left = 0, right = HW_-1, p = 0;
    while (top <= bottom && left <= right) {
      for (int j = left; j <= right; j++) idx_cw[p++] = top*HW_ + j;
      top++;
      for (int i = top; i <= bottom; i++) idx_cw[p++] = i*HW_ + right;
      right--;
      if (top <= bottom) { for (int j = right; j >= left; j--) idx_cw[p++] = bottom*HW_ + j; bottom--; }
      if (left <= right) { for (int i = bottom; i >= top; i--) idx_cw[p++] = i*HW_ + left; left++; }
    }
  } else if (t == 1) {
    int top = 0, bottom = HW_-1, left = 0, right = HW_-1, p = 0;
    while (top <= bottom && left <= right) {
      for (int j = right; j >= left; j--) idx_ccw[p++] = top*HW_ + j;
      top++;
      for (int i = top; i <= bottom; i++) idx_ccw[p++] = i*HW_ + left;
      left++;
      if (top <= bottom) { for (int j = left; j <= right; j++) idx_ccw[p++] = bottom*HW_ + j; bottom--; }
      if (left <= right) { for (int i = bottom; i >= top; i--) idx_ccw[p++] = i*HW_ + right; right--; }
    }
  } else if (t == 2) {
    *flag = detect_bf(x);
  }
}

// ---------------------------------------------------------------- batched transpose
__global__ __launch_bounds__(256) void tbatch_k(TJ tj, const int* __restrict__ flagp) {
  const int inbf = *flagp;
  int bid = blockIdx.x;
  int j = 0;
  while (bid >= tj.off[j+1]) ++j;
  const void* src = tj.src[j];
  ushort_t* dst = tj.dst[j];
  const int R = tj.R[j], Cc = tj.Cc[j], RD = tj.RD[j], ldD = tj.ldD[j];
  int cb_span = (Cc > RD ? Cc : RD);
  int txt = (cb_span + 31) >> 5;
  int t = bid - tj.off[j];
  int bx = (t % txt) * 32;
  int by = (t / txt) * 32;
  __shared__ ushort_t tile[32][33];
  int tx = threadIdx.x & 31, ty = threadIdx.x >> 5;
  #pragma unroll
  for (int i = 0; i < 4; ++i) {
    int r = by + ty + i*8, c = bx + tx;
    ushort_t v = 0;
    if (r < R && c < Cc) v = f2bf(ldf(src, (size_t)r * Cc + c, inbf));
    tile[ty + i*8][tx] = v;
  }
  __syncthreads();
  #pragma unroll
  for (int i = 0; i < 4; ++i) {
    int dr = bx + ty + i*8, dc = by + tx;
    if (dr < RD && dc < ldD)
      dst[(size_t)dr * ldD + dc] = tile[tx][ty + i*8];
  }
}

// ---------------------------------------------------------------- MFMA GEMM
// Out[M, Nn] = act(A[M,K] @ WT[N,K]^T + bias) (+resid). Tile BM x BN x BK64,
// 256 thr / 4 waves. BM=128: waves 2x2. BM=64: waves 1x4 (wave 64m x BN/4).
// Staging: global_load_lds w=16, LDS [row][k] 128 B rows, XOR chunk swizzle
// c' = c ^ (r&7) (measured 0 conflicts).
struct GB {
  const ushort_t* A[4]; const int* amap[4];
  const ushort_t* WT[4];
  const void* bias[4];
  void* out[4]; ushort_t* out2[4]; const int* omap[4];
};

template<int BM, int BN>
__global__ __launch_bounds__(256) void mgemm_k(
    GB gb, int lda, int ldb, int Nn, int K, int ldo,
    int act, int out_mode, const void* resid, int ldr, const int* __restrict__ flagp)
{
  constexpr int NA = BM / 32;          // A staging chunks per thread
  constexpr int NB = BN / 32;          // B staging chunks per thread
  constexpr int WN = (BM == 128) ? 2 : 4;   // waves along n
  constexpr int NSPAN = BN / WN;       // n-span per wave
  constexpr int FN = NSPAN / 16;       // n-frags per wave
  const int inbf = *flagp;
  const int z = blockIdx.z;

  const ushort_t* A  = gb.A[z];
  const int* amap    = gb.amap[z];
  const ushort_t* Bw = gb.WT[z];
  const void* bias   = gb.bias[z];
  void* Out          = gb.out[z];
  ushort_t* out2     = gb.out2[z];
  const int* omap    = gb.omap[z];

  __shared__ __align__(16) ushort_t As[BM * 64];
  __shared__ __align__(16) ushort_t Bs[BN * 64];

  const int tid  = threadIdx.x;
  const int w    = tid >> 6;
  const int lane = tid & 63;
  const int quad = lane >> 4;
  const int l15  = lane & 15;
  const int wm     = (BM == 128) ? (w >> 1) * 64 : 0;       // wave m offset
  const int wn_off = ((BM == 128) ? (w & 1) : w) * NSPAN;   // wave n offset
  const int row0 = blockIdx.y * BM;
  const int col0 = blockIdx.x * BN;

  int agb[NA], bgb[NB], aldso[NA], bldso[NB];
  #pragma unroll
  for (int i = 0; i < NA; ++i) {
    int t = i*256 + tid;                // chunk id
    int r = t >> 3;
    int c = (t & 7) ^ (r & 7);          // swizzle involution
    int grow = row0 + r;
    if (amap) { int b = grow >> 10, l = grow & 1023; grow = (b << 10) + amap[l]; }
    agb[i] = grow * lda + c * 8;
    aldso[i] = (i*256 + w*64) * 16;
  }
  #pragma unroll
  for (int i = 0; i < NB; ++i) {
    int t = i*256 + tid;
    int r = t >> 3;
    int c = (t & 7) ^ (r & 7);
    bgb[i] = (col0 + r) * ldb + c * 8;
    bldso[i] = (i*256 + w*64) * 16;
  }

  f32x4 acc[4][FN];
  #pragma unroll
  for (int mi = 0; mi < 4; ++mi)
    #pragma unroll
    for (int ni = 0; ni < FN; ++ni)
      acc[mi][ni] = (f32x4){0.f, 0.f, 0.f, 0.f};

  const int sw = l15 & 7;

  for (int k0 = 0; k0 < K; k0 += 64) {
    #pragma unroll
    for (int i = 0; i < NA; ++i)
      gload_lds16(A + agb[i] + k0, (char*)As + aldso[i]);
    #pragma unroll
    for (int i = 0; i < NB; ++i)
      gload_lds16(Bw + bgb[i] + k0, (char*)Bs + bldso[i]);
    __syncthreads();

    #pragma unroll
    for (int ks = 0; ks < 2; ++ks) {
      short8 aF[4], bF[FN];
      #pragma unroll
      for (int mi = 0; mi < 4; ++mi)
        aF[mi] = *(const short8*)&As[(wm + mi*16 + l15) * 64 + (((quad + 4*ks) ^ sw) * 8)];
      #pragma unroll
      for (int ni = 0; ni < FN; ++ni)
        bF[ni] = *(const short8*)&Bs[(wn_off + ni*16 + l15) * 64 + (((quad + 4*ks) ^ sw) * 8)];
      #pragma unroll
      for (int mi = 0; mi < 4; ++mi)
        #pragma unroll
        for (int ni = 0; ni < FN; ++ni)
          acc[mi][ni] = __builtin_amdgcn_mfma_f32_16x16x32_bf16(aF[mi], bF[ni], acc[mi][ni], 0, 0, 0);
    }
    __syncthreads();
  }

  const int obf = (out_mode == 2) ? inbf : (out_mode == 0);
  #pragma unroll
  for (int ni = 0; ni < FN; ++ni) {
    int colg = col0 + wn_off + ni*16 + l15;
    if (colg >= Nn) continue;
    float bv = bias ? ldf(bias, colg, inbf) : 0.f;
    #pragma unroll
    for (int mi = 0; mi < 4; ++mi) {
      #pragma unroll
      for (int r = 0; r < 4; ++r) {
        int rowg = row0 + wm + mi*16 + quad*4 + r;
        int orow = rowg;
        if (omap) { int b = rowg >> 10, l = rowg & 1023; orow = (b << 10) + omap[l]; }
        float v = acc[mi][ni][r] + bv;
        if (out2 && colg < 64)
          out2[(size_t)orow * 64 + colg] = f2bf(colg < DR_ ? v : 0.f);
        if (act == 1)      v = (v > 20.f) ? v : log1pf(__expf(v));                  // softplus
        else if (act == 2) v = 0.5f * v * (1.f + erff(v * 0.70710678118654752f));   // gelu
        if (resid) v += ldf(resid, (size_t)orow * ldr + colg, inbf);
        size_t oi = (size_t)orow * ldo + colg;
        if (obf) ((ushort_t*)Out)[oi] = f2bf(v);
        else     ((float*)Out)[oi]    = v;
      }
    }
  }
}

// ---------------------------------------------------------------- conv(K=4)+silu
__global__ __launch_bounds__(256) void conv_silu_k(
    const ushort_t* __restrict__ u,
    const void* __restrict__ cw0, const void* __restrict__ cw1,
    const void* __restrict__ cb0, const void* __restrict__ cb1,
    ushort_t* __restrict__ uc, const int* __restrict__ flagp)
{
  const int inbf = *flagp;
  int g = blockIdx.x * 256 + threadIdx.x;
  int c = g % C_;
  int row = g / C_;
  int l = row & 1023;
  const void* cw = (row >> 12) ? cw1 : cw0;
  const void* cb = (row >> 12) ? cb1 : cb0;
  float w0 = ldf(cw, c*4+0, inbf), w1 = ldf(cw, c*4+1, inbf);
  float w2 = ldf(cw, c*4+2, inbf), w3 = ldf(cw, c*4+3, inbf);
  const ushort_t* up = u + (size_t)(row - l) * C_ + c;
  float s = ldf(cb, c, inbf);
  if (l >= 3) s += w0 * bf2f(up[(size_t)(l-3) * C_]);
  if (l >= 2) s += w1 * bf2f(up[(size_t)(l-2) * C_]);
  if (l >= 1) s += w2 * bf2f(up[(size_t)(l-1) * C_]);
  s += w3 * bf2f(up[(size_t)l * C_]);
  s = s / (1.f + __expf(-s));
  uc[g] = f2bf(s);
}

// ---------------------------------------------------------------- segmented scan
__global__ __launch_bounds__(256) void scan_pass1(
    const ushort_t* __restrict__ dt, const ushort_t* __restrict__ uc,
    const float* __restrict__ dbl,
    const void* __restrict__ Alog_cw, const void* __restrict__ Alog_ccw,
    ushort_t* __restrict__ P, ushort_t* __restrict__ Q,
    const int* __restrict__ flagp)
{
  const int inbf = *flagp;
  const int db = blockIdx.z, d = db >> 2;
  const int s = blockIdx.y;
  const int tid = threadIdx.x;
  const int c = blockIdx.x * 256 + tid;
  const int l0 = s * SEG_;

  __shared__ __align__(16) float Bs[SEG_][32];
  {
    const float* src = dbl + ((size_t)db * L_ + l0) * 80 + DR_;
    #pragma unroll
    for (int i = 0; i < 2; ++i) {
      int idx = tid * 4 + i * 1024;
      int st = idx >> 5, col = idx & 31;
      *(f32x4*)&Bs[st][col] = *(const f32x4*)(src + (size_t)st * 80 + col);
    }
  }
  __syncthreads();

  const void* Alog = d ? Alog_ccw : Alog_cw;
  float a[16];
  #pragma unroll
  for (int n = 0; n < 16; ++n) a[n] = -__expf(ldf(Alog, c * N_ + n, inbf));

  const size_t rbase = ((size_t)db * L_ + l0) * C_ + c;
  const ushort_t* dtp = dt + rbase;
  const ushort_t* ucp = uc + rbase;

  float h[16];
  #pragma unroll
  for (int n = 0; n < 16; ++n) h[n] = 0.f;
  float S = 0.f;

  #pragma unroll 4
  for (int l = 0; l < SEG_; ++l) {
    float dtv = bf2f(dtp[(size_t)l * C_]);
    float ucv = bf2f(ucp[(size_t)l * C_]);
    float dtu = dtv * ucv;
    S += dtv;
    f32x4 bq0 = *(const f32x4*)&Bs[l][0];
    f32x4 bq1 = *(const f32x4*)&Bs[l][4];
    f32x4 bq2 = *(const f32x4*)&Bs[l][8];
    f32x4 bq3 = *(const f32x4*)&Bs[l][12];
    #pragma unroll
    for (int j = 0; j < 4; ++j) { float dA = __expf(dtv*a[j]);    h[j]    = h[j]   *dA + dtu*bq0[j]; }
    #pragma unroll
    for (int j = 0; j < 4; ++j) { float dA = __expf(dtv*a[4+j]);  h[4+j]  = h[4+j] *dA + dtu*bq1[j]; }
    #pragma unroll
    for (int j = 0; j < 4; ++j) { float dA = __expf(dtv*a[8+j]);  h[8+j]  = h[8+j] *dA + dtu*bq2[j]; }
    #pragma unroll
    for (int j = 0; j < 4; ++j) { float dA = __expf(dtv*a[12+j]); h[12+j] = h[12+j]*dA + dtu*bq3[j]; }
  }
  size_t idx = (((size_t)db * NSEG_ + s) * C_ + c) * N_;
  #pragma unroll
  for (int n = 0; n < 16; ++n) {
    P[idx + n] = f2bf(__expf(a[n] * S));
    Q[idx + n] = f2bf(h[n]);
  }
}

__global__ __launch_bounds__(256) void scan_pass2(
    ushort_t* __restrict__ P, ushort_t* __restrict__ Q)
{
  size_t g = (size_t)blockIdx.x * 256 + threadIdx.x;
  size_t db = g / (C_ * N_);
  size_t cn = g % (C_ * N_);
  float h = 0.f;
  #pragma unroll
  for (int s = 0; s < NSEG_; ++s) {
    size_t off = (db * NSEG_ + s) * (C_ * N_) + cn;
    float p = bf2f(P[off]), q = bf2f(Q[off]);
    Q[off] = f2bf(h);
    h = h * p + q;
  }
}

__global__ __launch_bounds__(256) void scan_pass3(
    const ushort_t* __restrict__ dt, const ushort_t* __restrict__ uc,
    const float* __restrict__ dbl, const ushort_t* __restrict__ z,
    const void* __restrict__ Alog_cw, const void* __restrict__ Alog_ccw,
    const void* __restrict__ D_cw, const void* __restrict__ D_ccw,
    const ushort_t* __restrict__ Q, ushort_t* __restrict__ y,
    const int* __restrict__ flagp)
{
  const int inbf = *flagp;
  const int db = blockIdx.z, d = db >> 2;
  const int s = blockIdx.y;
  const int tid = threadIdx.x;
  const int c = blockIdx.x * 256 + tid;
  const int l0 = s * SEG_;

  __shared__ __align__(16) float Bs[SEG_][32];   // cols 0..15 = B, 16..31 = C
  {
    const float* src = dbl + ((size_t)db * L_ + l0) * 80 + DR_;
    #pragma unroll
    for (int i = 0; i < 2; ++i) {
      int idx = tid * 4 + i * 1024;
      int st = idx >> 5, col = idx & 31;
      *(f32x4*)&Bs[st][col] = *(const f32x4*)(src + (size_t)st * 80 + col);
    }
  }
  __syncthreads();

  const void* Alog = d ? Alog_ccw : Alog_cw;
  const void* Dp   = d ? D_ccw   : D_cw;
  float a[16];
  #pragma unroll
  for (int n = 0; n < 16; ++n) a[n] = -__expf(ldf(Alog, c * N_ + n, inbf));
  const float dvc = ldf(Dp, c, inbf);

  const size_t rbase = ((size_t)db * L_ + l0) * C_ + c;
  const ushort_t* dtp = dt + rbase;
  const ushort_t* ucp = uc + rbase;
  const ushort_t* zp  = z  + rbase;
  ushort_t* yp = y + rbase;

  size_t idx = (((size_t)db * NSEG_ + s) * C_ + c) * N_;
  float h[16];
  #pragma unroll
  for (int n = 0; n < 16; ++n) h[n] = bf2f(Q[idx + n]);

  #pragma unroll 2
  for (int l = 0; l < SEG_; ++l) {
    float dtv = bf2f(dtp[(size_t)l * C_]);
    float ucv = bf2f(ucp[(size_t)l * C_]);
    float zv  = bf2f(zp[(size_t)l * C_]);
    float dtu = dtv * ucv;
    f32x4 bq0 = *(const f32x4*)&Bs[l][0];
    f32x4 bq1 = *(const f32x4*)&Bs[l][4];
    f32x4 bq2 = *(const f32x4*)&Bs[l][8];
    f32x4 bq3 = *(const f32x4*)&Bs[l][12];
    f32x4 cq0 = *(const f32x4*)&Bs[l][16];
    f32x4 cq1 = *(const f32x4*)&Bs[l][20];
    f32x4 cq2 = *(const f32x4*)&Bs[l][24];
    f32x4 cq3 = *(const f32x4*)&Bs[l][28];
    float yv = dvc * ucv;
    #pragma unroll
    for (int j = 0; j < 4; ++j) { float dA = __expf(dtv*a[j]);    h[j]    = h[j]   *dA + dtu*bq0[j]; yv += h[j]   *cq0[j]; }
    #pragma unroll
    for (int j = 0; j < 4; ++j) { float dA = __expf(dtv*a[4+j]);  h[4+j]  = h[4+j] *dA + dtu*bq1[j]; yv += h[4+j] *cq1[j]; }
    #pragma unroll
    for (int j = 0; j < 4; ++j) { float dA = __expf(dtv*a[8+j]);  h[8+j]  = h[8+j] *dA + dtu*bq2[j]; yv += h[8+j] *cq2[j]; }
    #pragma unroll
    for (int j = 0; j < 4; ++j) { float dA = __expf(dtv*a[12+j]); h[12+j] = h[12+j]*dA + dtu*bq3[j]; yv += h[12+j]*cq3[j]; }
    yv *= zv / (1.f + __expf(-zv));   // * silu(z)
    yp[(size_t)l * C_] = f2bf(yv);
  }
}

// ---------------------------------------------------------------- launch
extern "C" void kernel_launch(void* const* d_in, const int* in_sizes, int n_in,
                              void* d_out, int out_size, void* d_ws, size_t ws_size,
                              hipStream_t stream)
{
  const void* x      = d_in[0];
  const void* norm_w = d_in[1];
  const void* norm_b = d_in[2];
  const void* in_w[2]    = { d_in[3],  d_in[12] };
  const void* conv_w[2]  = { d_in[4],  d_in[13] };
  const void* conv_b[2]  = { d_in[5],  d_in[14] };
  const void* xproj_w[2] = { d_in[6],  d_in[15] };
  const void* dtp_w[2]   = { d_in[7],  d_in[16] };
  const void* dtp_b[2]   = { d_in[8],  d_in[17] };
  const void* A_log[2]   = { d_in[9],  d_in[18] };
  const void* Dvec[2]    = { d_in[10], d_in[19] };
  const void* out_w[2]   = { d_in[11], d_in[20] };
  const void* fus_w1 = d_in[21];
  const void* fus_b1 = d_in[22];
  const void* fus_w2 = d_in[23];
  const void* fus_b2 = d_in[24];

  char* base = (char*)d_ws;
  int*      IDX  = (int*)base;
  int*      FLAG = (int*)(base + 8192);
  ushort_t* XN   = (ushort_t*)(base + 8448);
  ushort_t* U    = (ushort_t*)(base + 6299904);
  ushort_t* Z    = (ushort_t*)(base + 18882816);
  ushort_t* UC   = (ushort_t*)(base + 31465728);
  float*    DBL  = (float*)(base + 44048640);
  ushort_t* Y    = (ushort_t*)(base + 46670080);
  // lifetime aliases
  ushort_t* DT    = U;                                  // S5 out, scan in
  ushort_t* FUSED = Z;                                  // S7 out, S8 in
  ushort_t* HBUF  = XN;                                 // S8 out, S9 in
  ushort_t* SP = (ushort_t*)(base + 8448);              // scan only (bf16)
  ushort_t* SQ = SP + (size_t)2 * 4 * NSEG_ * C_ * N_;
  ushort_t* DTC = XN;                                   // S4 out2, S5 in
  ushort_t* INWT = UC;                                  // [2][1536][768], S2
  ushort_t* uout = (ushort_t*)d_out;
  ushort_t* XPJT = uout;                                // [2][128][768], S4
  ushort_t* DTPT = uout + 196608;                       // [2][768][64],  S5
  ushort_t* OWT  = uout + 294912;                       // [2][768][768], S7
  ushort_t* FW1T = U;                                   // [768][1536], S8
  ushort_t* FW2T = U + (size_t)768 * 1536;              // [768][768],  S9

  const size_t SD = (size_t)M_ * C_;

  // ---- prep: weight transposes + layernorm + spiral idx + FLAG, one dispatch
  {
    TJ tj; tj.njobs = 8;
    for (int d = 0; d < 2; ++d) {
      int j = d;
      tj.src[j]=in_w[d]; tj.dst[j]=INWT+(size_t)d*1536*768;
      tj.R[j]=768; tj.Cc[j]=1536; tj.RD[j]=1536; tj.ldD[j]=768;
    }
    for (int d = 0; d < 2; ++d) {
      int j = 2+d;
      tj.src[j]=xproj_w[d]; tj.dst[j]=XPJT+(size_t)d*128*768;
      tj.R[j]=768; tj.Cc[j]=80; tj.RD[j]=128; tj.ldD[j]=768;
    }
    for (int d = 0; d < 2; ++d) {
      int j = 4+d;
      tj.src[j]=dtp_w[d]; tj.dst[j]=DTPT+(size_t)d*768*64;
      tj.R[j]=48; tj.Cc[j]=768; tj.RD[j]=768; tj.ldD[j]=64;
    }
    for (int d = 0; d < 2; ++d) {
      int j = 6+d;
      tj.src[j]=out_w[d]; tj.dst[j]=OWT+(size_t)d*768*768;
      tj.R[j]=768; tj.Cc[j]=768; tj.RD[j]=768; tj.ldD[j]=768;
    }
    tj.off[0] = 0;
    for (int j = 0; j < 8; ++j) {
      int cspan = tj.Cc[j] > tj.RD[j] ? tj.Cc[j] : tj.RD[j];
      int rspan = tj.R[j] > tj.ldD[j] ? tj.R[j] : tj.ldD[j];
      tj.off[j+1] = tj.off[j] + ((cspan+31)>>5) * ((rspan+31)>>5);
    }
    int nblk = tj.off[8] + M_ + 1;
    hipLaunchKernelGGL(prep_k, dim3(nblk), dim3(256), 0, stream,
        tj, x, norm_w, norm_b, XN, IDX, IDX + L_, FLAG);
  }

  GB gb;
  for (int i = 0; i < 4; ++i) { gb.out2[i] = nullptr; gb.omap[i] = nullptr; gb.amap[i] = nullptr; gb.bias[i] = nullptr; }

  // ---- S2: in_proj, z = (d, u/z half), BM=64 BN=64, grid 12x64x4 = 3072
  for (int zz = 0; zz < 4; ++zz) {
    int d = zz >> 1, half = zz & 1;
    gb.A[zz] = XN; gb.amap[zz] = IDX + d * L_;
    gb.WT[zz] = INWT + (size_t)d*1536*768 + (size_t)half*768*768;
    gb.bias[zz] = nullptr;
    gb.out[zz] = (void*)((half ? Z : U) + d * SD); gb.out2[zz] = nullptr; gb.omap[zz] = nullptr;
  }
  hipLaunchKernelGGL((mgemm_k<64,64>), dim3(12, 64, 4), dim3(256), 0, stream,
      gb, C_, C_, C_, C_, C_, 0, 0, (const void*)nullptr, 0, FLAG);

  // ---- S3: conv + silu (both dirs, one dispatch)
  hipLaunchKernelGGL(conv_silu_k, dim3(2*M_*C_/256), dim3(256), 0, stream,
      U, conv_w[0], conv_w[1], conv_b[0], conv_b[1], UC, FLAG);

  // ---- S4: xproj -> DBL fp32 (+fused dtc), BM=64 BN=64, Nn=80, grid 2x64x2
  for (int zz = 0; zz < 2; ++zz) {
    gb.A[zz] = UC + zz * SD; gb.amap[zz] = nullptr;
    gb.WT[zz] = XPJT + (size_t)zz*128*768;
    gb.bias[zz] = nullptr;
    gb.out[zz] = (void*)(DBL + (size_t)zz * M_ * 80);
    gb.out2[zz] = DTC + (size_t)zz * M_ * 64;
    gb.omap[zz] = nullptr;
  }
  hipLaunchKernelGGL((mgemm_k<64,64>), dim3(2, 64, 2), dim3(256), 0, stream,
      gb, C_, C_, 80, C_, 80, 0, 1, (const void*)nullptr, 0, FLAG);

  // ---- S5: dt = softplus(dtc @ dtp_w + dtp_b), K=64, BM=64 BN=64, grid 12x64x2
  for (int zz = 0; zz < 2; ++zz) {
    gb.A[zz] = DTC + (size_t)zz * M_ * 64; gb.amap[zz] = nullptr;
    gb.WT[zz] = DTPT + (size_t)zz*768*64;
    gb.bias[zz] = dtp_b[zz];
    gb.out[zz] = (void*)(DT + zz * SD); gb.out2[zz] = nullptr; gb.omap[zz] = nullptr;
  }
  hipLaunchKernelGGL((mgemm_k<64,64>), dim3(12, 64, 2), dim3(256), 0, stream,
      gb, 64, 64, C_, 64, C_, 1, 0, (const void*)nullptr, 0, FLAG);

  // ---- S6: segmented selective scan
  hipLaunchKernelGGL(scan_pass1, dim3(3, NSEG_, 8), dim3(256), 0, stream,
      DT, UC, DBL, A_log[0], A_log[1], SP, SQ, FLAG);
  hipLaunchKernelGGL(scan_pass2, dim3(8 * C_ * N_ / 256), dim3(256), 0, stream, SP, SQ);
  hipLaunchKernelGGL(scan_pass3, dim3(3, NSEG_, 8), dim3(256), 0, stream,
      DT, UC, DBL, Z, A_log[0], A_log[1], Dvec[0], Dvec[1], SQ, Y, FLAG);

  // ---- batched transposes #2 (fus weights; U region free after scan)
  {
    TJ tj; tj.njobs = 2;
    tj.src[0]=fus_w1; tj.dst[0]=FW1T; tj.R[0]=1536; tj.Cc[0]=768; tj.RD[0]=768; tj.ldD[0]=1536;
    tj.src[1]=fus_w2; tj.dst[1]=FW2T; tj.R[1]=768;  tj.Cc[1]=768; tj.RD[1]=768; tj.ldD[1]=768;
    tj.off[0] = 0;
    for (int j = 0; j < 2; ++j) {
      int cspan = tj.Cc[j] > tj.RD[j] ? tj.Cc[j] : tj.RD[j];
      int rspan = tj.R[j] > tj.ldD[j] ? tj.R[j] : tj.ldD[j];
      tj.off[j+1] = tj.off[j] + ((cspan+31)>>5) * ((rspan+31)>>5);
    }
    hipLaunchKernelGGL(tbatch_k, dim3(tj.off[2]), dim3(256), 0, stream, tj, FLAG);
  }

  // ---- S7: out_proj with spiral-inverse scatter, BM=64 BN=64, grid 12x64x2
  for (int zz = 0; zz < 2; ++zz) {
    gb.A[zz] = Y + zz * SD; gb.amap[zz] = nullptr;
    gb.WT[zz] = OWT + (size_t)zz*768*768;
    gb.bias[zz] = nullptr;
    gb.out[zz] = (void*)(FUSED + zz * C_); gb.out2[zz] = nullptr; gb.omap[zz] = IDX + zz * L_;
  }
  hipLaunchKernelGGL((mgemm_k<64,64>), dim3(12, 64, 2), dim3(256), 0, stream,
      gb, C_, C_, C_, C_, 2*C_, 0, 0, (const void*)nullptr, 0, FLAG);

  // ---- S8: h = gelu(fused @ fus_w1 + fus_b1), K=1536, BM=64 BN=64, grid 12x64x1
  gb.A[0] = FUSED; gb.amap[0] = nullptr;
  gb.WT[0] = FW1T; gb.bias[0] = fus_b1;
  gb.out[0] = (void*)HBUF; gb.out2[0] = nullptr; gb.omap[0] = nullptr;
  hipLaunchKernelGGL((mgemm_k<64,64>), dim3(12, 64, 1), dim3(256), 0, stream,
      gb, 2*C_, 2*C_, C_, 2*C_, C_, 2, 0, (const void*)nullptr, 0, FLAG);

  // ---- S9: out = h @ fus_w2 + fus_b2 + x, BM=64 BN=64, grid 12x64x1
  gb.A[0] = HBUF; gb.amap[0] = nullptr;
  gb.WT[0] = FW2T; gb.bias[0] = fus_b2;
  gb.out[0] = d_out; gb.out2[0] = nullptr; gb.omap[0] = nullptr;
  hipLaunchKernelGGL((mgemm_k<64,64>), dim3(12, 64, 1), dim3(256), 0, stream,
      gb, C_, C_, C_, C_, C_, 0, 2, x, C_, FLAG);
}